// Round 2
// baseline (499.686 us; speedup 1.0000x reference)
//
#include <hip/hip_runtime.h>
#include <hip/hip_bf16.h>
#include <math.h>

typedef __hip_bfloat16 bf16;

__device__ __forceinline__ float b2f(bf16 v) { return __bfloat162float(v); }
__device__ __forceinline__ bf16 f2b(float v) { return __float2bfloat16(v); }
__device__ __forceinline__ float gelu_exact(float x) {
    return 0.5f * x * (1.0f + erff(x * 0.70710678118654752440f));
}
__device__ __forceinline__ float sigmoidf_(float x) {
    return 1.0f / (1.0f + __expf(-x));
}
// dtype-flexible input load: isbf ? bf16[i] : f32[i]
__device__ __forceinline__ float ldin(const void* p, int i, bool isbf) {
    return isbf ? __bfloat162float(((const bf16*)p)[i]) : ((const float*)p)[i];
}

// fp32 params block layout (offsets in floats)
#define P_DWK    0
#define P_DWB    2304
#define P_DWG    2560
#define P_DWBT   2816
#define P_DWM    3072
#define P_DWV    3328
#define P_CIW1   3584
#define P_CIB1   11776
#define P_CIG    11808
#define P_CIBT   11840
#define P_CIM    11872
#define P_CIV    11904
#define P_CIW2   11936
#define P_CIB2   20128
#define P_SIW1   20384
#define P_SIB1   24480
#define P_SIG    24496
#define P_SIBT   24512
#define P_SIM    24528
#define P_SIV    24544
#define P_SIW2   24560
#define P_SIB2   24576
#define P_TEMP   24577
#define P_BPROJ  24585
// total 24841 floats

// ---------------------------------------------------------------------------
// K0: dtype sniffer. If data is bf16-packed, the LOW 16 bits of each u32 are a
// bf16 value of N(0,1)-ish magnitude (exponent field in a narrow window). If
// data is fp32, low 16 bits are random mantissa bits (~14% in-window).
// ---------------------------------------------------------------------------
__global__ __launch_bounds__(256) void k_sniff(const unsigned* __restrict__ x,
                                               unsigned* __restrict__ flag) {
    int cnt = 0;
    for (int i = threadIdx.x; i < 4096; i += 256) {
        unsigned lo = x[i] & 0xFFFFu;
        unsigned e = (lo >> 7) & 0xFFu;
        cnt += (e >= 0x66u && e <= 0x8Au) ? 1 : 0;
    }
    __shared__ int red[256];
    red[threadIdx.x] = cnt;
    __syncthreads();
    for (int o = 128; o > 0; o >>= 1) {
        if (threadIdx.x < o) red[threadIdx.x] += red[threadIdx.x + o];
        __syncthreads();
    }
    if (threadIdx.x == 0) *flag = (red[0] > 2048) ? 1u : 0u;
}

// ---------------------------------------------------------------------------
// K0b: convert all small params to fp32 block.
// ---------------------------------------------------------------------------
struct CvtArgs { const void* src[24]; int dst[24]; int cnt[24]; };

__global__ __launch_bounds__(256) void k_cvt(CvtArgs a, float* __restrict__ prm,
                                             const unsigned* __restrict__ flag) {
    const bool isbf = (*flag != 0u);
    const int e = blockIdx.x;
    const void* s = a.src[e];
    float* d = prm + a.dst[e];
    const int n = a.cnt[e];
    for (int i = threadIdx.x; i < n; i += 256) d[i] = ldin(s, i, isbf);
}

// ---------------------------------------------------------------------------
// K1: qkv GEMM.  Y[b,j,n] = sum_c w_qkv[c,j] * x[b,c,n], j in [0,768)
// j<256 -> q, j<512 -> k, else v. All outputs fp32.
// ---------------------------------------------------------------------------
__global__ __launch_bounds__(256) void k_qkv(const void* __restrict__ x,
                                             const void* __restrict__ w,
                                             const unsigned* __restrict__ flag,
                                             float* __restrict__ qf,
                                             float* __restrict__ kf,
                                             float* __restrict__ vb) {
    __shared__ float Xs[64][64];
    __shared__ float Ws[64][64];
    const bool isbf = (*flag != 0u);
    const int b = blockIdx.z;
    const int j0 = blockIdx.y * 64;
    const int n0 = blockIdx.x * 64;
    const int tid = threadIdx.x;
    const int tx = tid & 15, ty = tid >> 4;
    float acc[4][4] = {};
    for (int k0 = 0; k0 < 256; k0 += 64) {
        __syncthreads();
        for (int i = tid; i < 4096; i += 256) {
            int c = i >> 6, n = i & 63;
            Xs[c][n] = ldin(x, ((b * 256 + k0 + c) << 12) + n0 + n, isbf);
            Ws[c][n] = ldin(w, (k0 + c) * 768 + j0 + n, isbf);
        }
        __syncthreads();
#pragma unroll 8
        for (int kk = 0; kk < 64; ++kk) {
            float xv[4], wv[4];
#pragma unroll
            for (int u = 0; u < 4; ++u) xv[u] = Xs[kk][tx * 4 + u];
#pragma unroll
            for (int u = 0; u < 4; ++u) wv[u] = Ws[kk][ty * 4 + u];
#pragma unroll
            for (int jj = 0; jj < 4; ++jj)
#pragma unroll
                for (int nn = 0; nn < 4; ++nn)
                    acc[jj][nn] = fmaf(wv[jj], xv[nn], acc[jj][nn]);
        }
    }
#pragma unroll
    for (int jj = 0; jj < 4; ++jj) {
        int j = j0 + ty * 4 + jj;
#pragma unroll
        for (int nn = 0; nn < 4; ++nn) {
            int n = n0 + tx * 4 + nn;
            float val = acc[jj][nn];
            if (j < 256)
                qf[(((b << 8) + j) << 12) + n] = val;
            else if (j < 512)
                kf[(((b << 8) + (j - 256)) << 12) + n] = val;
            else
                vb[(((b << 8) + (j - 512)) << 12) + n] = val;
        }
    }
}

// ---------------------------------------------------------------------------
// K2: l2-norm scale factors: qs/ks[b,ch] = rsqrt(max(sum_n val^2, 1e-12))
// ---------------------------------------------------------------------------
__global__ __launch_bounds__(256) void k_norms(const float* __restrict__ qf,
                                               const float* __restrict__ kf,
                                               float* __restrict__ qs,
                                               float* __restrict__ ks) {
    const int row = blockIdx.x;  // 0..511
    const int b = blockIdx.y;
    const int ch = row & 255;
    const float* p = ((row < 256) ? qf : kf) + (((b << 8) + ch) << 12);
    float s = 0.f;
    for (int i = threadIdx.x; i < 4096; i += 256) {
        float v = p[i];
        s = fmaf(v, v, s);
    }
    __shared__ float red[256];
    red[threadIdx.x] = s;
    __syncthreads();
    for (int off = 128; off > 0; off >>= 1) {
        if (threadIdx.x < off) red[threadIdx.x] += red[threadIdx.x + off];
        __syncthreads();
    }
    if (threadIdx.x == 0) {
        float r = rsqrtf(fmaxf(red[0], 1e-12f));
        (row < 256 ? qs : ks)[(b << 8) + ch] = r;
    }
}

// ---------------------------------------------------------------------------
// K3: attn_raw[b,h,c,d] += sum_{n chunk} q[b,hc,n]*k[b,hd,n]  (atomic)
// ---------------------------------------------------------------------------
__global__ __launch_bounds__(256) void k_attn_qk(const float* __restrict__ qf,
                                                 const float* __restrict__ kf,
                                                 float* __restrict__ attn_raw) {
    __shared__ float Qs[128][36];
    __shared__ float Ks[128][36];
    const int b = blockIdx.z, h = blockIdx.y, chunk = blockIdx.x;
    const int tid = threadIdx.x;
    const int nsub = tid >> 6;
    const int combo = tid & 63;
    const int c0 = (combo >> 3) * 4, d0 = (combo & 7) * 4;
    const int base_q = ((b * 256 + h * 32) << 12);
    float acc[4][4] = {};
    for (int cc = 0; cc < 4; ++cc) {
        const int nb = chunk * 512 + cc * 128;
        __syncthreads();
        for (int i = tid; i < 4096; i += 256) {
            int r = i >> 7, n = i & 127;
            Qs[n][r] = qf[base_q + (r << 12) + nb + n];
            Ks[n][r] = kf[base_q + (r << 12) + nb + n];
        }
        __syncthreads();
        for (int n = nsub * 32; n < nsub * 32 + 32; ++n) {
            float qv[4], kv[4];
#pragma unroll
            for (int u = 0; u < 4; ++u) qv[u] = Qs[n][c0 + u];
#pragma unroll
            for (int u = 0; u < 4; ++u) kv[u] = Ks[n][d0 + u];
#pragma unroll
            for (int ci = 0; ci < 4; ++ci)
#pragma unroll
                for (int dj = 0; dj < 4; ++dj)
                    acc[ci][dj] = fmaf(qv[ci], kv[dj], acc[ci][dj]);
        }
    }
    __syncthreads();
    float* red = &Qs[0][0];  // 256*16 floats = 4096 < 128*36 = 4608
#pragma unroll
    for (int ci = 0; ci < 4; ++ci)
#pragma unroll
        for (int dj = 0; dj < 4; ++dj) red[tid * 16 + ci * 4 + dj] = acc[ci][dj];
    __syncthreads();
    if (nsub == 0) {
#pragma unroll
        for (int i = 0; i < 16; ++i) {
            float s = red[combo * 16 + i] + red[(64 + combo) * 16 + i] +
                      red[(128 + combo) * 16 + i] + red[(192 + combo) * 16 + i];
            int c = c0 + (i >> 2), d = d0 + (i & 3);
            atomicAdd(&attn_raw[(((b * 8 + h) << 5) + c) * 32 + d], s);
        }
    }
}

// ---------------------------------------------------------------------------
// K3b: scales + temperature, softmax over d.
// ---------------------------------------------------------------------------
__global__ __launch_bounds__(64) void k_softmax(float* __restrict__ attn,
                                                const float* __restrict__ qs,
                                                const float* __restrict__ ks,
                                                const float* __restrict__ prm) {
    const int h = blockIdx.x, b = blockIdx.y;
    const int tid = threadIdx.x;
    __shared__ float A[32][32];
    const float t = prm[P_TEMP + h];
    float* base = attn + ((b * 8 + h) << 10);
    for (int i = tid; i < 1024; i += 64) {
        int c = i >> 5, d = i & 31;
        A[c][d] = base[i] * qs[(b << 8) + h * 32 + c] * ks[(b << 8) + h * 32 + d] * t;
    }
    __syncthreads();
    if (tid < 32) {
        const int c = tid;
        float m = -1e30f;
#pragma unroll
        for (int d = 0; d < 32; ++d) m = fmaxf(m, A[c][d]);
        float s = 0.f;
#pragma unroll
        for (int d = 0; d < 32; ++d) {
            float e = __expf(A[c][d] - m);
            A[c][d] = e;
            s += e;
        }
        float inv = 1.0f / s;
#pragma unroll
        for (int d = 0; d < 32; ++d) base[c * 32 + d] = A[c][d] * inv;
    }
}

// ---------------------------------------------------------------------------
// K4: att[b, h*32+c, n] = sum_d attn[b,h,c,d] * v[b, h*32+d, n]
// ---------------------------------------------------------------------------
__global__ __launch_bounds__(256) void k_attv(const float* __restrict__ attn,
                                              const float* __restrict__ vb,
                                              float* __restrict__ att) {
    const int b = blockIdx.z, h = blockIdx.y;
    const int n = blockIdx.x * 256 + threadIdx.x;
    __shared__ float A[32][32];
    for (int i = threadIdx.x; i < 1024; i += 256) A[i >> 5][i & 31] = attn[((b * 8 + h) << 10) + i];
    __syncthreads();
    const int base = ((b * 256 + h * 32) << 12) + n;
    float vv[32];
#pragma unroll
    for (int d = 0; d < 32; ++d) vv[d] = vb[base + (d << 12)];
#pragma unroll
    for (int c = 0; c < 32; ++c) {
        float s = 0.f;
#pragma unroll
        for (int d = 0; d < 32; ++d) s = fmaf(A[c][d], vv[d], s);
        att[base + (c << 12)] = s;
    }
}

// ---------------------------------------------------------------------------
// K5: gap[b,ch] = mean_n att[b,ch,n]
// ---------------------------------------------------------------------------
__global__ __launch_bounds__(256) void k_gap(const float* __restrict__ att,
                                             float* __restrict__ gap) {
    const int row = blockIdx.x;
    const float* p = att + ((long)row << 12);
    float s = 0.f;
    for (int i = threadIdx.x; i < 4096; i += 256) s += p[i];
    __shared__ float red[256];
    red[threadIdx.x] = s;
    __syncthreads();
    for (int off = 128; off > 0; off >>= 1) {
        if (threadIdx.x < off) red[threadIdx.x] += red[threadIdx.x + off];
        __syncthreads();
    }
    if (threadIdx.x == 0) gap[row] = red[0] * (1.0f / 4096.0f);
}

// ---------------------------------------------------------------------------
// K6: channel gate
// ---------------------------------------------------------------------------
__global__ __launch_bounds__(256) void k_cm(const float* __restrict__ gap,
                                            const float* __restrict__ prm,
                                            float* __restrict__ sigcm) {
    const int b = blockIdx.x;
    const int tid = threadIdx.x;
    __shared__ float gl[256];
    __shared__ float t1[32];
    gl[tid] = gap[(b << 8) + tid];
    __syncthreads();
    if (tid < 32) {
        float s = prm[P_CIB1 + tid];
        for (int c = 0; c < 256; ++c) s = fmaf(gl[c], prm[P_CIW1 + c * 32 + tid], s);
        s = (s - prm[P_CIM + tid]) * rsqrtf(prm[P_CIV + tid] + 1e-3f) * prm[P_CIG + tid] + prm[P_CIBT + tid];
        t1[tid] = gelu_exact(s);
    }
    __syncthreads();
    float s = prm[P_CIB2 + tid];
#pragma unroll
    for (int o = 0; o < 32; ++o) s = fmaf(t1[o], prm[P_CIW2 + o * 256 + tid], s);
    sigcm[(b << 8) + tid] = sigmoidf_(s);
}

// ---------------------------------------------------------------------------
// K7: depthwise 3x3 SAME + bias + BN + GELU on v
// ---------------------------------------------------------------------------
__global__ __launch_bounds__(256) void k_dwconv(const float* __restrict__ vb,
                                                const float* __restrict__ prm,
                                                float* __restrict__ conv) {
    const int b = blockIdx.z, c = blockIdx.y;
    const int tid = threadIdx.x;
    const int y = blockIdx.x * 4 + (tid >> 6);
    const int xp = tid & 63;
    float w[9];
#pragma unroll
    for (int i = 0; i < 9; ++i) w[i] = prm[P_DWK + c * 9 + i];
    const float* src = vb + (((b << 8) + c) << 12);
    float acc = 0.f;
#pragma unroll
    for (int ky = 0; ky < 3; ++ky) {
        int yy = y + ky - 1;
        if (yy < 0 || yy > 63) continue;
#pragma unroll
        for (int kx = 0; kx < 3; ++kx) {
            int xx = xp + kx - 1;
            if (xx < 0 || xx > 63) continue;
            acc = fmaf(src[yy * 64 + xx], w[ky * 3 + kx], acc);
        }
    }
    acc += prm[P_DWB + c];
    acc = (acc - prm[P_DWM + c]) * rsqrtf(prm[P_DWV + c] + 1e-3f) * prm[P_DWG + c] + prm[P_DWBT + c];
    conv[(((b << 8) + c) << 12) + y * 64 + xp] = gelu_exact(acc);
}

// ---------------------------------------------------------------------------
// K8: spatial gate
// ---------------------------------------------------------------------------
__global__ __launch_bounds__(256) void k_sm(const float* __restrict__ conv,
                                            const float* __restrict__ prm,
                                            float* __restrict__ sigsm) {
    const int b = blockIdx.y;
    const int tid = threadIdx.x;
    const int n = blockIdx.x * 256 + tid;
    __shared__ float W1[256][16];
    for (int i = tid; i < 4096; i += 256) W1[i >> 4][i & 15] = prm[P_SIW1 + i];
    __syncthreads();
    float acc[16] = {};
    const float* src = conv + ((long)(b << 8) << 12) + n;
    for (int c = 0; c < 256; ++c) {
        float v = src[c << 12];
#pragma unroll
        for (int o = 0; o < 16; ++o) acc[o] = fmaf(v, W1[c][o], acc[o]);
    }
    float sm = prm[P_SIB2];
#pragma unroll
    for (int o = 0; o < 16; ++o) {
        float t = acc[o] + prm[P_SIB1 + o];
        t = (t - prm[P_SIM + o]) * rsqrtf(prm[P_SIV + o] + 1e-3f) * prm[P_SIG + o] + prm[P_SIBT + o];
        sm = fmaf(gelu_exact(t), prm[P_SIW2 + o], sm);
    }
    sigsm[(b << 12) + n] = sigmoidf_(sm);
}

// ---------------------------------------------------------------------------
// K9: final projection with fused gates; dtype-flexible output store.
// ---------------------------------------------------------------------------
__global__ __launch_bounds__(256) void k_proj(const float* __restrict__ att,
                                              const float* __restrict__ conv,
                                              const float* __restrict__ sigsm,
                                              const float* __restrict__ sigcm,
                                              const void* __restrict__ wproj,
                                              const float* __restrict__ prm,
                                              const unsigned* __restrict__ flag,
                                              void* __restrict__ out) {
    __shared__ float Zs[64][64];
    __shared__ float Ws[64][64];
    const bool isbf = (*flag != 0u);
    const int b = blockIdx.z;
    const int j0 = blockIdx.y * 64;
    const int n0 = blockIdx.x * 64;
    const int tid = threadIdx.x;
    const int tx = tid & 15, ty = tid >> 4;
    float acc[4][4] = {};
    for (int k0 = 0; k0 < 256; k0 += 64) {
        __syncthreads();
        for (int i = tid; i < 4096; i += 256) {
            int c = i >> 6, n = i & 63;
            int gc = k0 + c, gn = n0 + n;
            int idx = (((b << 8) + gc) << 12) + gn;
            Zs[c][n] = att[idx] * sigsm[(b << 12) + gn] + conv[idx] * sigcm[(b << 8) + gc];
            Ws[c][n] = ldin(wproj, gc * 256 + j0 + n, isbf);
        }
        __syncthreads();
#pragma unroll 8
        for (int kk = 0; kk < 64; ++kk) {
            float xv[4], wv[4];
#pragma unroll
            for (int u = 0; u < 4; ++u) xv[u] = Zs[kk][tx * 4 + u];
#pragma unroll
            for (int u = 0; u < 4; ++u) wv[u] = Ws[kk][ty * 4 + u];
#pragma unroll
            for (int jj = 0; jj < 4; ++jj)
#pragma unroll
                for (int nn = 0; nn < 4; ++nn)
                    acc[jj][nn] = fmaf(wv[jj], xv[nn], acc[jj][nn]);
        }
    }
#pragma unroll
    for (int jj = 0; jj < 4; ++jj) {
        int j = j0 + ty * 4 + jj;
        float bp = prm[P_BPROJ + j];
#pragma unroll
        for (int nn = 0; nn < 4; ++nn) {
            int n = n0 + tx * 4 + nn;
            int idx = (((b << 8) + j) << 12) + n;
            float val = acc[jj][nn] + bp;
            if (isbf) ((bf16*)out)[idx] = f2b(val);
            else ((float*)out)[idx] = val;
        }
    }
}

// ---------------------------------------------------------------------------
extern "C" void kernel_launch(void* const* d_in, const int* in_sizes, int n_in,
                              void* d_out, int out_size, void* d_ws, size_t ws_size,
                              hipStream_t stream) {
    char* ws = (char*)d_ws;
    // fp32 ws layout (bytes):
    //   vb    @ 0          (32M)  v
    //   qf    @ 32M        (32M)
    //   kf    @ 64M        (32M)   -- att aliases kf after k_attn_qk is done
    //   conv  @ 96M        (32M)
    //   attn  @ 128M       (256K)
    //   qs/ks/gap/sigcm    (8K each), sigsm (128K), params (~100K), flag (4B)
    float* vb    = (float*)(ws);
    float* qf    = (float*)(ws + 33554432);
    float* kf    = (float*)(ws + 67108864);
    float* att   = (float*)(ws + 67108864);   // alias kf (kf dead after k_attn_qk)
    float* conv  = (float*)(ws + 100663296);
    float* attn  = (float*)(ws + 134217728);
    float* qs    = (float*)(ws + 134217728 + 262144);
    float* ksn   = qs + 2048;
    float* gap   = ksn + 2048;
    float* sigcm = gap + 2048;
    float* sigsm = sigcm + 2048;              // 32768 floats
    float* prm   = sigsm + 32768;             // 24841 floats
    unsigned* flag = (unsigned*)(prm + 25088);

    k_sniff<<<1, 256, 0, stream>>>((const unsigned*)d_in[0], flag);

    CvtArgs a;
    const int map_src[24] = {3, 4, 5, 6, 7, 8, 9, 10, 11, 12, 13, 14, 15, 16, 17,
                             18, 19, 20, 21, 22, 23, 24, 25, 26};
    const int map_dst[24] = {P_BPROJ, P_DWK, P_DWB, P_DWG, P_DWBT, P_DWM, P_DWV,
                             P_CIG, P_CIBT, P_CIM, P_CIV, P_SIG, P_SIBT, P_SIM, P_SIV,
                             P_CIW1, P_CIB1, P_CIW2, P_CIB2, P_SIW1, P_SIB1, P_SIW2,
                             P_SIB2, P_TEMP};
    for (int i = 0; i < 24; ++i) {
        a.src[i] = d_in[map_src[i]];
        a.dst[i] = map_dst[i];
        a.cnt[i] = in_sizes[map_src[i]];
    }
    k_cvt<<<24, 256, 0, stream>>>(a, prm, flag);

    hipMemsetAsync(attn, 0, 8 * 8 * 32 * 32 * sizeof(float), stream);

    k_qkv<<<dim3(64, 12, 8), 256, 0, stream>>>(d_in[0], d_in[1], flag, qf, kf, vb);
    k_norms<<<dim3(512, 8), 256, 0, stream>>>(qf, kf, qs, ksn);
    k_attn_qk<<<dim3(8, 8, 8), 256, 0, stream>>>(qf, kf, attn);
    k_softmax<<<dim3(8, 8), 64, 0, stream>>>(attn, qs, ksn, prm);
    k_attv<<<dim3(16, 8, 8), 256, 0, stream>>>(attn, vb, att);
    k_dwconv<<<dim3(16, 256, 8), 256, 0, stream>>>(vb, prm, conv);
    k_gap<<<2048, 256, 0, stream>>>(att, gap);
    k_cm<<<8, 256, 0, stream>>>(gap, prm, sigcm);
    k_sm<<<dim3(16, 8), 256, 0, stream>>>(conv, prm, sigsm);
    k_proj<<<dim3(64, 4, 8), 256, 0, stream>>>(att, conv, sigsm, sigcm,
                                               d_in[2], prm, flag, d_out);
}

// Round 3
// 374.721 us; speedup vs baseline: 1.3335x; 1.3335x over previous
//
#include <hip/hip_runtime.h>
#include <hip/hip_bf16.h>
#include <math.h>

typedef __hip_bfloat16 bf16;
typedef __attribute__((ext_vector_type(8))) short short8;
typedef __attribute__((ext_vector_type(4))) short short4v;
typedef __attribute__((ext_vector_type(4))) float floatx4;

__device__ __forceinline__ float b2f(bf16 v) { return __bfloat162float(v); }
__device__ __forceinline__ bf16 f2b(float v) { return __float2bfloat16(v); }
__device__ __forceinline__ short f2s(float v) {
    bf16 h = __float2bfloat16(v);
    return *reinterpret_cast<short*>(&h);
}
__device__ __forceinline__ float gelu_exact(float x) {
    return 0.5f * x * (1.0f + erff(x * 0.70710678118654752440f));
}
__device__ __forceinline__ float sigmoidf_(float x) {
    return 1.0f / (1.0f + __expf(-x));
}
// dtype-flexible input load: isbf ? bf16[i] : f32[i]
__device__ __forceinline__ float ldin(const void* p, int i, bool isbf) {
    return isbf ? __bfloat162float(((const bf16*)p)[i]) : ((const float*)p)[i];
}

// fp32 params block layout (offsets in floats)
#define P_DWK    0
#define P_DWB    2304
#define P_DWG    2560
#define P_DWBT   2816
#define P_DWM    3072
#define P_DWV    3328
#define P_CIW1   3584
#define P_CIB1   11776
#define P_CIG    11808
#define P_CIBT   11840
#define P_CIM    11872
#define P_CIV    11904
#define P_CIW2   11936
#define P_CIB2   20128
#define P_SIW1   20384
#define P_SIB1   24480
#define P_SIG    24496
#define P_SIBT   24512
#define P_SIM    24528
#define P_SIV    24544
#define P_SIW2   24560
#define P_SIB2   24576
#define P_TEMP   24577
#define P_BPROJ  24585

// ---------------------------------------------------------------------------
// K0: dtype sniffer (bf16-packed vs fp32 input buffers).
// ---------------------------------------------------------------------------
__global__ __launch_bounds__(256) void k_sniff(const unsigned* __restrict__ x,
                                               unsigned* __restrict__ flag) {
    int cnt = 0;
    for (int i = threadIdx.x; i < 4096; i += 256) {
        unsigned lo = x[i] & 0xFFFFu;
        unsigned e = (lo >> 7) & 0xFFu;
        cnt += (e >= 0x66u && e <= 0x8Au) ? 1 : 0;
    }
    __shared__ int red[256];
    red[threadIdx.x] = cnt;
    __syncthreads();
    for (int o = 128; o > 0; o >>= 1) {
        if (threadIdx.x < o) red[threadIdx.x] += red[threadIdx.x + o];
        __syncthreads();
    }
    if (threadIdx.x == 0) *flag = (red[0] > 2048) ? 1u : 0u;
}

// ---------------------------------------------------------------------------
// K0b: convert all small params to fp32 block.
// ---------------------------------------------------------------------------
struct CvtArgs { const void* src[24]; int dst[24]; int cnt[24]; };

__global__ __launch_bounds__(256) void k_cvt(CvtArgs a, float* __restrict__ prm,
                                             const unsigned* __restrict__ flag) {
    const bool isbf = (*flag != 0u);
    const int e = blockIdx.x;
    const void* s = a.src[e];
    float* d = prm + a.dst[e];
    const int n = a.cnt[e];
    for (int i = threadIdx.x; i < n; i += 256) d[i] = ldin(s, i, isbf);
}

// ---------------------------------------------------------------------------
// K1 (MFMA): qkv GEMM.  Y[b,j,n] = sum_c w_qkv[c,j] * x[b,c,n], j in [0,768)
// Block tile 64(j) x 128(n), BK=64, 4 waves; 16x16x32 bf16 MFMA.
// blockIdx.y: 0-3 -> q, 4-7 -> k, 8-11 -> v.
// ---------------------------------------------------------------------------
__global__ __launch_bounds__(256) void k_qkv_m(const void* __restrict__ x,
                                               const void* __restrict__ w,
                                               const unsigned* __restrict__ flag,
                                               float* __restrict__ qf,
                                               float* __restrict__ kf,
                                               float* __restrict__ vb) {
    __shared__ short As[64][72];   // A[j][k] = w[k][j]  (bf16 bits)
    __shared__ short Bs[128][72];  // B[n][k] = x[k][n]
    const bool isbf = (*flag != 0u);
    const int b = blockIdx.z;
    const int j0 = blockIdx.y * 64;     // global j of tile
    const int n0 = blockIdx.x * 128;
    const int tid = threadIdx.x;
    const int wid = tid >> 6, l = tid & 63;
    const int lm = l & 15, lk = (l >> 4) * 8;
    // staging thread maps
    const int sn = tid & 127, skg = tid >> 7;   // B: n, k-group(0..1)
    const int sj = tid & 63, skg4 = tid >> 6;   // A: j, k-group(0..3)

    floatx4 acc[8];
#pragma unroll
    for (int i = 0; i < 8; ++i) acc[i] = (floatx4){0.f, 0.f, 0.f, 0.f};

    for (int k0 = 0; k0 < 256; k0 += 64) {
        __syncthreads();
        // stage B: x[k0+k][n0+n] -> Bs[n][k], pack 4 k per write
#pragma unroll
        for (int it = 0; it < 8; ++it) {
            int kk = skg * 4 + it * 8;
            short4v p;
#pragma unroll
            for (int u = 0; u < 4; ++u)
                p[u] = f2s(ldin(x, ((b * 256 + k0 + kk + u) << 12) + n0 + sn, isbf));
            *(short4v*)&Bs[sn][kk] = p;
        }
        // stage A: w[k0+k][j0+j] -> As[j][k]
#pragma unroll
        for (int it = 0; it < 4; ++it) {
            int kk = skg4 * 4 + it * 16;
            short4v p;
#pragma unroll
            for (int u = 0; u < 4; ++u)
                p[u] = f2s(ldin(w, (k0 + kk + u) * 768 + j0 + sj, isbf));
            *(short4v*)&As[sj][kk] = p;
        }
        __syncthreads();
#pragma unroll
        for (int h = 0; h < 2; ++h) {
            short8 af = *(const short8*)&As[wid * 16 + lm][h * 32 + lk];
#pragma unroll
            for (int nt = 0; nt < 8; ++nt) {
                short8 bfr = *(const short8*)&Bs[nt * 16 + lm][h * 32 + lk];
                acc[nt] = __builtin_amdgcn_mfma_f32_16x16x32_bf16(af, bfr, acc[nt], 0, 0, 0);
            }
        }
    }
    // epilogue: D[row=(l>>4)*4+r][col=lm]; whole block lands in exactly one of q/k/v
    float* dst = (blockIdx.y < 4) ? qf : (blockIdx.y < 8 ? kf : vb);
    const int jloc = (blockIdx.y & 3) * 64 + wid * 16 + (l >> 4) * 4;
#pragma unroll
    for (int nt = 0; nt < 8; ++nt) {
        int n = n0 + nt * 16 + lm;
#pragma unroll
        for (int r = 0; r < 4; ++r)
            dst[(((b << 8) + jloc + r) << 12) + n] = acc[nt][r];
    }
}

// ---------------------------------------------------------------------------
// K2: l2-norm scale factors
// ---------------------------------------------------------------------------
__global__ __launch_bounds__(256) void k_norms(const float* __restrict__ qf,
                                               const float* __restrict__ kf,
                                               float* __restrict__ qs,
                                               float* __restrict__ ks) {
    const int row = blockIdx.x;  // 0..511
    const int b = blockIdx.y;
    const int ch = row & 255;
    const float* p = ((row < 256) ? qf : kf) + (((b << 8) + ch) << 12);
    float s = 0.f;
    for (int i = threadIdx.x; i < 4096; i += 256) {
        float v = p[i];
        s = fmaf(v, v, s);
    }
    __shared__ float red[256];
    red[threadIdx.x] = s;
    __syncthreads();
    for (int off = 128; off > 0; off >>= 1) {
        if (threadIdx.x < off) red[threadIdx.x] += red[threadIdx.x + off];
        __syncthreads();
    }
    if (threadIdx.x == 0) {
        float r = rsqrtf(fmaxf(red[0], 1e-12f));
        (row < 256 ? qs : ks)[(b << 8) + ch] = r;
    }
}

// ---------------------------------------------------------------------------
// K3: attn_raw[b,h,c,d] += sum_{n chunk} q[b,hc,n]*k[b,hd,n]  (atomic)
// ---------------------------------------------------------------------------
__global__ __launch_bounds__(256) void k_attn_qk(const float* __restrict__ qf,
                                                 const float* __restrict__ kf,
                                                 float* __restrict__ attn_raw) {
    __shared__ float Qs[128][36];
    __shared__ float Ks[128][36];
    const int b = blockIdx.z, h = blockIdx.y, chunk = blockIdx.x;
    const int tid = threadIdx.x;
    const int nsub = tid >> 6;
    const int combo = tid & 63;
    const int c0 = (combo >> 3) * 4, d0 = (combo & 7) * 4;
    const int base_q = ((b * 256 + h * 32) << 12);
    float acc[4][4] = {};
    for (int cc = 0; cc < 4; ++cc) {
        const int nb = chunk * 512 + cc * 128;
        __syncthreads();
        for (int i = tid; i < 4096; i += 256) {
            int r = i >> 7, n = i & 127;
            Qs[n][r] = qf[base_q + (r << 12) + nb + n];
            Ks[n][r] = kf[base_q + (r << 12) + nb + n];
        }
        __syncthreads();
        for (int n = nsub * 32; n < nsub * 32 + 32; ++n) {
            float qv[4], kv[4];
#pragma unroll
            for (int u = 0; u < 4; ++u) qv[u] = Qs[n][c0 + u];
#pragma unroll
            for (int u = 0; u < 4; ++u) kv[u] = Ks[n][d0 + u];
#pragma unroll
            for (int ci = 0; ci < 4; ++ci)
#pragma unroll
                for (int dj = 0; dj < 4; ++dj)
                    acc[ci][dj] = fmaf(qv[ci], kv[dj], acc[ci][dj]);
        }
    }
    __syncthreads();
    float* red = &Qs[0][0];
#pragma unroll
    for (int ci = 0; ci < 4; ++ci)
#pragma unroll
        for (int dj = 0; dj < 4; ++dj) red[tid * 16 + ci * 4 + dj] = acc[ci][dj];
    __syncthreads();
    if (nsub == 0) {
#pragma unroll
        for (int i = 0; i < 16; ++i) {
            float s = red[combo * 16 + i] + red[(64 + combo) * 16 + i] +
                      red[(128 + combo) * 16 + i] + red[(192 + combo) * 16 + i];
            int c = c0 + (i >> 2), d = d0 + (i & 3);
            atomicAdd(&attn_raw[(((b * 8 + h) << 5) + c) * 32 + d], s);
        }
    }
}

// ---------------------------------------------------------------------------
// K3b: scales + temperature, softmax over d.
// ---------------------------------------------------------------------------
__global__ __launch_bounds__(64) void k_softmax(float* __restrict__ attn,
                                                const float* __restrict__ qs,
                                                const float* __restrict__ ks,
                                                const float* __restrict__ prm) {
    const int h = blockIdx.x, b = blockIdx.y;
    const int tid = threadIdx.x;
    __shared__ float A[32][32];
    const float t = prm[P_TEMP + h];
    float* base = attn + ((b * 8 + h) << 10);
    for (int i = tid; i < 1024; i += 64) {
        int c = i >> 5, d = i & 31;
        A[c][d] = base[i] * qs[(b << 8) + h * 32 + c] * ks[(b << 8) + h * 32 + d] * t;
    }
    __syncthreads();
    if (tid < 32) {
        const int c = tid;
        float m = -1e30f;
#pragma unroll
        for (int d = 0; d < 32; ++d) m = fmaxf(m, A[c][d]);
        float s = 0.f;
#pragma unroll
        for (int d = 0; d < 32; ++d) {
            float e = __expf(A[c][d] - m);
            A[c][d] = e;
            s += e;
        }
        float inv = 1.0f / s;
#pragma unroll
        for (int d = 0; d < 32; ++d) base[c * 32 + d] = A[c][d] * inv;
    }
}

// ---------------------------------------------------------------------------
// K4: att[b, h*32+c, n] = sum_d attn[b,h,c,d] * v[b, h*32+d, n]
// ---------------------------------------------------------------------------
__global__ __launch_bounds__(256) void k_attv(const float* __restrict__ attn,
                                              const float* __restrict__ vb,
                                              float* __restrict__ att) {
    const int b = blockIdx.z, h = blockIdx.y;
    const int n = blockIdx.x * 256 + threadIdx.x;
    __shared__ float A[32][32];
    for (int i = threadIdx.x; i < 1024; i += 256) A[i >> 5][i & 31] = attn[((b * 8 + h) << 10) + i];
    __syncthreads();
    const int base = ((b * 256 + h * 32) << 12) + n;
    float vv[32];
#pragma unroll
    for (int d = 0; d < 32; ++d) vv[d] = vb[base + (d << 12)];
#pragma unroll
    for (int c = 0; c < 32; ++c) {
        float s = 0.f;
#pragma unroll
        for (int d = 0; d < 32; ++d) s = fmaf(A[c][d], vv[d], s);
        att[base + (c << 12)] = s;
    }
}

// ---------------------------------------------------------------------------
// K5: gap[b,ch] = mean_n att[b,ch,n]
// ---------------------------------------------------------------------------
__global__ __launch_bounds__(256) void k_gap(const float* __restrict__ att,
                                             float* __restrict__ gap) {
    const int row = blockIdx.x;
    const float* p = att + ((long)row << 12);
    float s = 0.f;
    for (int i = threadIdx.x; i < 4096; i += 256) s += p[i];
    __shared__ float red[256];
    red[threadIdx.x] = s;
    __syncthreads();
    for (int off = 128; off > 0; off >>= 1) {
        if (threadIdx.x < off) red[threadIdx.x] += red[threadIdx.x + off];
        __syncthreads();
    }
    if (threadIdx.x == 0) gap[row] = red[0] * (1.0f / 4096.0f);
}

// ---------------------------------------------------------------------------
// K6: channel gate
// ---------------------------------------------------------------------------
__global__ __launch_bounds__(256) void k_cm(const float* __restrict__ gap,
                                            const float* __restrict__ prm,
                                            float* __restrict__ sigcm) {
    const int b = blockIdx.x;
    const int tid = threadIdx.x;
    __shared__ float gl[256];
    __shared__ float t1[32];
    gl[tid] = gap[(b << 8) + tid];
    __syncthreads();
    if (tid < 32) {
        float s = prm[P_CIB1 + tid];
        for (int c = 0; c < 256; ++c) s = fmaf(gl[c], prm[P_CIW1 + c * 32 + tid], s);
        s = (s - prm[P_CIM + tid]) * rsqrtf(prm[P_CIV + tid] + 1e-3f) * prm[P_CIG + tid] + prm[P_CIBT + tid];
        t1[tid] = gelu_exact(s);
    }
    __syncthreads();
    float s = prm[P_CIB2 + tid];
#pragma unroll
    for (int o = 0; o < 32; ++o) s = fmaf(t1[o], prm[P_CIW2 + o * 256 + tid], s);
    sigcm[(b << 8) + tid] = sigmoidf_(s);
}

// ---------------------------------------------------------------------------
// K7: depthwise 3x3 SAME + bias + BN + GELU on v
// ---------------------------------------------------------------------------
__global__ __launch_bounds__(256) void k_dwconv(const float* __restrict__ vb,
                                                const float* __restrict__ prm,
                                                float* __restrict__ conv) {
    const int b = blockIdx.z, c = blockIdx.y;
    const int tid = threadIdx.x;
    const int y = blockIdx.x * 4 + (tid >> 6);
    const int xp = tid & 63;
    float w[9];
#pragma unroll
    for (int i = 0; i < 9; ++i) w[i] = prm[P_DWK + c * 9 + i];
    const float* src = vb + (((b << 8) + c) << 12);
    float acc = 0.f;
#pragma unroll
    for (int ky = 0; ky < 3; ++ky) {
        int yy = y + ky - 1;
        if (yy < 0 || yy > 63) continue;
#pragma unroll
        for (int kx = 0; kx < 3; ++kx) {
            int xx = xp + kx - 1;
            if (xx < 0 || xx > 63) continue;
            acc = fmaf(src[yy * 64 + xx], w[ky * 3 + kx], acc);
        }
    }
    acc += prm[P_DWB + c];
    acc = (acc - prm[P_DWM + c]) * rsqrtf(prm[P_DWV + c] + 1e-3f) * prm[P_DWG + c] + prm[P_DWBT + c];
    conv[(((b << 8) + c) << 12) + y * 64 + xp] = gelu_exact(acc);
}

// ---------------------------------------------------------------------------
// K8: spatial gate
// ---------------------------------------------------------------------------
__global__ __launch_bounds__(256) void k_sm(const float* __restrict__ conv,
                                            const float* __restrict__ prm,
                                            float* __restrict__ sigsm) {
    const int b = blockIdx.y;
    const int tid = threadIdx.x;
    const int n = blockIdx.x * 256 + tid;
    __shared__ float W1[256][16];
    for (int i = tid; i < 4096; i += 256) W1[i >> 4][i & 15] = prm[P_SIW1 + i];
    __syncthreads();
    float acc[16] = {};
    const float* src = conv + ((long)(b << 8) << 12) + n;
    for (int c = 0; c < 256; ++c) {
        float v = src[c << 12];
#pragma unroll
        for (int o = 0; o < 16; ++o) acc[o] = fmaf(v, W1[c][o], acc[o]);
    }
    float sm = prm[P_SIB2];
#pragma unroll
    for (int o = 0; o < 16; ++o) {
        float t = acc[o] + prm[P_SIB1 + o];
        t = (t - prm[P_SIM + o]) * rsqrtf(prm[P_SIV + o] + 1e-3f) * prm[P_SIG + o] + prm[P_SIBT + o];
        sm = fmaf(gelu_exact(t), prm[P_SIW2 + o], sm);
    }
    sigsm[(b << 12) + n] = sigmoidf_(sm);
}

// ---------------------------------------------------------------------------
// K9 (MFMA): final projection with fused gates.
// Z[c][n] = att*sigsm + conv*sigcm;  out[j][n] = sum_c wp[c][j] Z[c][n] + bp[j]
// Block tile 64(j) x 128(n), BK=64, 4 waves.
// ---------------------------------------------------------------------------
__global__ __launch_bounds__(256) void k_proj_m(const float* __restrict__ att,
                                                const float* __restrict__ conv,
                                                const float* __restrict__ sigsm,
                                                const float* __restrict__ sigcm,
                                                const void* __restrict__ wproj,
                                                const float* __restrict__ prm,
                                                const unsigned* __restrict__ flag,
                                                void* __restrict__ out) {
    __shared__ short As[64][72];   // A[j][c] = wp[c][j]
    __shared__ short Bs[128][72];  // B[n][c] = Z[c][n]
    const bool isbf = (*flag != 0u);
    const int b = blockIdx.z;
    const int j0 = blockIdx.y * 64;
    const int n0 = blockIdx.x * 128;
    const int tid = threadIdx.x;
    const int wid = tid >> 6, l = tid & 63;
    const int lm = l & 15, lk = (l >> 4) * 8;
    const int sn = tid & 127, skg = tid >> 7;
    const int sj = tid & 63, skg4 = tid >> 6;
    const float sv = sigsm[(b << 12) + n0 + sn];   // fixed n per thread

    floatx4 acc[8];
#pragma unroll
    for (int i = 0; i < 8; ++i) acc[i] = (floatx4){0.f, 0.f, 0.f, 0.f};

    for (int k0 = 0; k0 < 256; k0 += 64) {
        __syncthreads();
#pragma unroll
        for (int it = 0; it < 8; ++it) {
            int kk = skg * 4 + it * 8;
            short4v p;
#pragma unroll
            for (int u = 0; u < 4; ++u) {
                int c = k0 + kk + u;
                int idx = (((b << 8) + c) << 12) + n0 + sn;
                p[u] = f2s(att[idx] * sv + conv[idx] * sigcm[(b << 8) + c]);
            }
            *(short4v*)&Bs[sn][kk] = p;
        }
#pragma unroll
        for (int it = 0; it < 4; ++it) {
            int kk = skg4 * 4 + it * 16;
            short4v p;
#pragma unroll
            for (int u = 0; u < 4; ++u)
                p[u] = f2s(ldin(wproj, (k0 + kk + u) * 256 + j0 + sj, isbf));
            *(short4v*)&As[sj][kk] = p;
        }
        __syncthreads();
#pragma unroll
        for (int h = 0; h < 2; ++h) {
            short8 af = *(const short8*)&As[wid * 16 + lm][h * 32 + lk];
#pragma unroll
            for (int nt = 0; nt < 8; ++nt) {
                short8 bfr = *(const short8*)&Bs[nt * 16 + lm][h * 32 + lk];
                acc[nt] = __builtin_amdgcn_mfma_f32_16x16x32_bf16(af, bfr, acc[nt], 0, 0, 0);
            }
        }
    }
    const int jb = j0 + wid * 16 + (l >> 4) * 4;
    float bp[4];
#pragma unroll
    for (int r = 0; r < 4; ++r) bp[r] = prm[P_BPROJ + jb + r];
#pragma unroll
    for (int nt = 0; nt < 8; ++nt) {
        int n = n0 + nt * 16 + lm;
#pragma unroll
        for (int r = 0; r < 4; ++r) {
            int idx = (((b << 8) + jb + r) << 12) + n;
            float val = acc[nt][r] + bp[r];
            if (isbf) ((bf16*)out)[idx] = f2b(val);
            else ((float*)out)[idx] = val;
        }
    }
}

// ---------------------------------------------------------------------------
extern "C" void kernel_launch(void* const* d_in, const int* in_sizes, int n_in,
                              void* d_out, int out_size, void* d_ws, size_t ws_size,
                              hipStream_t stream) {
    char* ws = (char*)d_ws;
    float* vb    = (float*)(ws);
    float* qf    = (float*)(ws + 33554432);
    float* kf    = (float*)(ws + 67108864);
    float* att   = (float*)(ws + 67108864);   // alias kf (kf dead after k_attn_qk)
    float* conv  = (float*)(ws + 100663296);
    float* attn  = (float*)(ws + 134217728);
    float* qs    = (float*)(ws + 134217728 + 262144);
    float* ksn   = qs + 2048;
    float* gap   = ksn + 2048;
    float* sigcm = gap + 2048;
    float* sigsm = sigcm + 2048;              // 32768 floats
    float* prm   = sigsm + 32768;             // 24841 floats
    unsigned* flag = (unsigned*)(prm + 25088);

    k_sniff<<<1, 256, 0, stream>>>((const unsigned*)d_in[0], flag);

    CvtArgs a;
    const int map_src[24] = {3, 4, 5, 6, 7, 8, 9, 10, 11, 12, 13, 14, 15, 16, 17,
                             18, 19, 20, 21, 22, 23, 24, 25, 26};
    const int map_dst[24] = {P_BPROJ, P_DWK, P_DWB, P_DWG, P_DWBT, P_DWM, P_DWV,
                             P_CIG, P_CIBT, P_CIM, P_CIV, P_SIG, P_SIBT, P_SIM, P_SIV,
                             P_CIW1, P_CIB1, P_CIW2, P_CIB2, P_SIW1, P_SIB1, P_SIW2,
                             P_SIB2, P_TEMP};
    for (int i = 0; i < 24; ++i) {
        a.src[i] = d_in[map_src[i]];
        a.dst[i] = map_dst[i];
        a.cnt[i] = in_sizes[map_src[i]];
    }
    k_cvt<<<24, 256, 0, stream>>>(a, prm, flag);

    hipMemsetAsync(attn, 0, 8 * 8 * 32 * 32 * sizeof(float), stream);

    k_qkv_m<<<dim3(32, 12, 8), 256, 0, stream>>>(d_in[0], d_in[1], flag, qf, kf, vb);
    k_norms<<<dim3(512, 8), 256, 0, stream>>>(qf, kf, qs, ksn);
    k_attn_qk<<<dim3(8, 8, 8), 256, 0, stream>>>(qf, kf, attn);
    k_softmax<<<dim3(8, 8), 64, 0, stream>>>(attn, qs, ksn, prm);
    k_attv<<<dim3(16, 8, 8), 256, 0, stream>>>(attn, vb, att);
    k_dwconv<<<dim3(16, 256, 8), 256, 0, stream>>>(vb, prm, conv);
    k_gap<<<2048, 256, 0, stream>>>(att, gap);
    k_cm<<<8, 256, 0, stream>>>(gap, prm, sigcm);
    k_sm<<<dim3(16, 8), 256, 0, stream>>>(conv, prm, sigsm);
    k_proj_m<<<dim3(32, 4, 8), 256, 0, stream>>>(att, conv, sigsm, sigcm,
                                                 d_in[2], prm, flag, d_out);
}

// Round 4
// 222.194 us; speedup vs baseline: 2.2489x; 1.6865x over previous
//
#include <hip/hip_runtime.h>
#include <hip/hip_bf16.h>
#include <math.h>

typedef __hip_bfloat16 bf16;
typedef __attribute__((ext_vector_type(8))) short short8;
typedef __attribute__((ext_vector_type(4))) float floatx4;

__device__ __forceinline__ bf16 f2b(float v) { return __float2bfloat16(v); }
__device__ __forceinline__ short f2s(float v) {
    bf16 h = __float2bfloat16(v);
    return *reinterpret_cast<short*>(&h);
}
__device__ __forceinline__ float s2f(short s) {
    union { unsigned u; float f; } t;
    t.u = ((unsigned)(unsigned short)s) << 16;
    return t.f;
}
__device__ __forceinline__ float gelu_exact(float x) {
    return 0.5f * x * (1.0f + erff(x * 0.70710678118654752440f));
}
__device__ __forceinline__ float sigmoidf_(float x) {
    return 1.0f / (1.0f + __expf(-x));
}
__device__ __forceinline__ float ldin(const void* p, int i, bool isbf) {
    return isbf ? s2f(((const short*)p)[i]) : ((const float*)p)[i];
}
#define MFMA16(a, b, c) __builtin_amdgcn_mfma_f32_16x16x32_bf16(a, b, c, 0, 0, 0)

// fp32 params block layout (offsets in floats)
#define P_DWK    0
#define P_DWB    2304
#define P_DWG    2560
#define P_DWBT   2816
#define P_DWM    3072
#define P_DWV    3328
#define P_CIW1   3584
#define P_CIB1   11776
#define P_CIG    11808
#define P_CIBT   11840
#define P_CIM    11872
#define P_CIV    11904
#define P_CIW2   11936
#define P_CIB2   20128
#define P_SIW1   20384
#define P_SIB1   24480
#define P_SIG    24496
#define P_SIBT   24512
#define P_SIM    24528
#define P_SIV    24544
#define P_SIW2   24560
#define P_SIB2   24576
#define P_TEMP   24577
#define P_BPROJ  24585

// ---------------------------------------------------------------------------
// K0: dtype sniffer (bf16-packed vs fp32 input buffers).
// ---------------------------------------------------------------------------
__global__ __launch_bounds__(256) void k_sniff(const unsigned* __restrict__ x,
                                               unsigned* __restrict__ flag) {
    int cnt = 0;
    for (int i = threadIdx.x; i < 4096; i += 256) {
        unsigned lo = x[i] & 0xFFFFu;
        unsigned e = (lo >> 7) & 0xFFu;
        cnt += (e >= 0x66u && e <= 0x8Au) ? 1 : 0;
    }
    __shared__ int red[256];
    red[threadIdx.x] = cnt;
    __syncthreads();
    for (int o = 128; o > 0; o >>= 1) {
        if (threadIdx.x < o) red[threadIdx.x] += red[threadIdx.x + o];
        __syncthreads();
    }
    if (threadIdx.x == 0) *flag = (red[0] > 2048) ? 1u : 0u;
}

// ---------------------------------------------------------------------------
// K0b: convert all small params to fp32 block.
// ---------------------------------------------------------------------------
struct CvtArgs { const void* src[24]; int dst[24]; int cnt[24]; };

__global__ __launch_bounds__(256) void k_cvt(CvtArgs a, float* __restrict__ prm,
                                             const unsigned* __restrict__ flag) {
    const bool isbf = (*flag != 0u);
    const int e = blockIdx.x;
    const void* s = a.src[e];
    float* d = prm + a.dst[e];
    const int n = a.cnt[e];
    for (int i = threadIdx.x; i < n; i += 256) d[i] = ldin(s, i, isbf);
}

// ---------------------------------------------------------------------------
// K_xt: x [b][c][n] (fp32 or bf16) -> xT bf16 [b][n][c]. 64x64 LDS tiles.
// ---------------------------------------------------------------------------
__global__ __launch_bounds__(256) void k_xt(const void* __restrict__ x,
                                            const unsigned* __restrict__ flag,
                                            bf16* __restrict__ xT) {
    __shared__ short T[64][72];
    const bool isbf = (*flag != 0u);
    const int b = blockIdx.z, c0 = blockIdx.y * 64, n0 = blockIdx.x * 64;
    const int tid = threadIdx.x;
    const int nn = tid & 63, cc0 = tid >> 6;
#pragma unroll
    for (int i = 0; i < 16; ++i) {
        int cc = cc0 + i * 4;
        T[nn][cc] = f2s(ldin(x, ((b * 256 + c0 + cc) << 12) + n0 + nn, isbf));
    }
    __syncthreads();
    const int rn = tid >> 3, oct = tid & 7;
#pragma unroll
    for (int i = 0; i < 2; ++i) {
        int n = rn + i * 32;
        *(short8*)&xT[(((b << 12) + n0 + n) << 8) + c0 + oct * 8] =
            *(const short8*)&T[n][oct * 8];
    }
}

// ---------------------------------------------------------------------------
// K_wt: w [c][j] (256 x ncols) -> wT bf16 [j][c].
// ---------------------------------------------------------------------------
__global__ __launch_bounds__(256) void k_wt(const void* __restrict__ src,
                                            const unsigned* __restrict__ flag,
                                            bf16* __restrict__ dst, int ncols) {
    __shared__ short T[64][72];
    const bool isbf = (*flag != 0u);
    const int j0 = blockIdx.x * 64, c0 = blockIdx.y * 64;
    const int tid = threadIdx.x;
    const int jj = tid & 63, cc0 = tid >> 6;
#pragma unroll
    for (int i = 0; i < 16; ++i) {
        int cc = cc0 + i * 4;
        T[jj][cc] = f2s(ldin(src, (c0 + cc) * ncols + j0 + jj, isbf));
    }
    __syncthreads();
    const int rj = tid >> 3, oct = tid & 7;
#pragma unroll
    for (int i = 0; i < 2; ++i) {
        int j = rj + i * 32;
        *(short8*)&dst[((j0 + j) << 8) + c0 + oct * 8] = *(const short8*)&T[j][oct * 8];
    }
}

// ---------------------------------------------------------------------------
// K1: qkv GEMM (MFMA, vectorized staging).
// Y[b,j,n] = sum_c wqkvT[j][c] * xT[n][c].  Tile 64j x 128n, BK=64, 4 waves.
// y<4 -> q bf16, y<8 -> k bf16 (+ fused sum-of-squares atomics), else v fp32.
// ---------------------------------------------------------------------------
__global__ __launch_bounds__(256) void k_qkv_m2(const bf16* __restrict__ xT,
                                                const bf16* __restrict__ wT,
                                                bf16* __restrict__ qb,
                                                bf16* __restrict__ kb,
                                                float* __restrict__ vb,
                                                float* __restrict__ qss,
                                                float* __restrict__ kss) {
    __shared__ short As[64][72];
    __shared__ short Bs[128][72];
    const int b = blockIdx.z, j0 = blockIdx.y * 64, n0 = blockIdx.x * 128;
    const int tid = threadIdx.x;
    const int wid = tid >> 6, l = tid & 63;
    const int lm = l & 15, lk = (l >> 4) * 8;
    const int srow = tid >> 3, soct = tid & 7;
    floatx4 acc[8];
#pragma unroll
    for (int i = 0; i < 8; ++i) acc[i] = (floatx4){0.f, 0.f, 0.f, 0.f};

    for (int k0 = 0; k0 < 256; k0 += 64) {
        __syncthreads();
#pragma unroll
        for (int i = 0; i < 2; ++i) {
            int j = srow + i * 32;
            *(short8*)&As[j][soct * 8] =
                *(const short8*)&wT[((j0 + j) << 8) + k0 + soct * 8];
        }
#pragma unroll
        for (int i = 0; i < 4; ++i) {
            int n = srow + i * 32;
            *(short8*)&Bs[n][soct * 8] =
                *(const short8*)&xT[(((b << 12) + n0 + n) << 8) + k0 + soct * 8];
        }
        __syncthreads();
#pragma unroll
        for (int h = 0; h < 2; ++h) {
            short8 af = *(const short8*)&As[wid * 16 + lm][h * 32 + lk];
#pragma unroll
            for (int nt = 0; nt < 8; ++nt) {
                short8 bfr = *(const short8*)&Bs[nt * 16 + lm][h * 32 + lk];
                acc[nt] = MFMA16(af, bfr, acc[nt]);
            }
        }
    }
    const int y = blockIdx.y;
    const int jloc = (y & 3) * 64 + wid * 16 + (l >> 4) * 4;
    float sq[4] = {0.f, 0.f, 0.f, 0.f};
    if (y < 4) {
#pragma unroll
        for (int nt = 0; nt < 8; ++nt) {
            int n = n0 + nt * 16 + lm;
#pragma unroll
            for (int r = 0; r < 4; ++r) {
                float vf = acc[nt][r];
                qb[(((b << 8) + jloc + r) << 12) + n] = f2b(vf);
                sq[r] = fmaf(vf, vf, sq[r]);
            }
        }
    } else if (y < 8) {
#pragma unroll
        for (int nt = 0; nt < 8; ++nt) {
            int n = n0 + nt * 16 + lm;
#pragma unroll
            for (int r = 0; r < 4; ++r) {
                float vf = acc[nt][r];
                kb[(((b << 8) + jloc + r) << 12) + n] = f2b(vf);
                sq[r] = fmaf(vf, vf, sq[r]);
            }
        }
    } else {
#pragma unroll
        for (int nt = 0; nt < 8; ++nt) {
            int n = n0 + nt * 16 + lm;
#pragma unroll
            for (int r = 0; r < 4; ++r)
                vb[(((b << 8) + jloc + r) << 12) + n] = acc[nt][r];
        }
    }
    if (y < 8) {   // block-uniform branch: barriers safe
        __syncthreads();
        float* red = (float*)&As[0][0];   // 64 rows x 16 lanes = 4 KB
        const int rbase = wid * 16 + (l >> 4) * 4;
#pragma unroll
        for (int r = 0; r < 4; ++r) red[(rbase + r) * 16 + lm] = sq[r];
        __syncthreads();
        if (tid < 64) {
            float s = 0.f;
#pragma unroll
            for (int i = 0; i < 16; ++i) s += red[tid * 16 + i];
            float* dst = (y < 4) ? qss : kss;
            atomicAdd(&dst[(b << 8) + (y & 3) * 64 + tid], s);
        }
    }
}

// ---------------------------------------------------------------------------
// K2: qss/kss (sum of squares) -> rsqrt(max(.,1e-12)) in place.
// ---------------------------------------------------------------------------
__global__ __launch_bounds__(256) void k_rsqrt(float* __restrict__ qss,
                                               float* __restrict__ kss) {
    int i = blockIdx.x * 256 + threadIdx.x;  // 0..4095
    float* p = (i < 2048) ? qss : kss;
    int j = i & 2047;
    p[j] = rsqrtf(fmaxf(p[j], 1e-12f));
}

// ---------------------------------------------------------------------------
// K3: fused QK^T (MFMA over n) + l2 scales + temperature + softmax.
// One block per (h,b); 4 waves split K=4096 into 1024-chunks; LDS reduce.
// ---------------------------------------------------------------------------
__global__ __launch_bounds__(256) void k_qk2(const bf16* __restrict__ qb,
                                             const bf16* __restrict__ kb,
                                             const float* __restrict__ qss,
                                             const float* __restrict__ kss,
                                             const float* __restrict__ prm,
                                             float* __restrict__ attn) {
    __shared__ float AS[32][32];
    const int h = blockIdx.x, b = blockIdx.y;
    const int tid = threadIdx.x;
    const int wid = tid >> 6, l = tid & 63;
    const int lm = l & 15, lk = (l >> 4) * 8;
    floatx4 acc[2][2];
#pragma unroll
    for (int i = 0; i < 2; ++i)
#pragma unroll
        for (int j = 0; j < 2; ++j) acc[i][j] = (floatx4){0.f, 0.f, 0.f, 0.f};
    const int cbase = (b << 8) + h * 32;
    for (int it = 0; it < 32; ++it) {
        int n = wid * 1024 + it * 32 + lk;
        short8 a0 = *(const short8*)&qb[((cbase + lm) << 12) + n];
        short8 a1 = *(const short8*)&qb[((cbase + 16 + lm) << 12) + n];
        short8 b0 = *(const short8*)&kb[((cbase + lm) << 12) + n];
        short8 b1 = *(const short8*)&kb[((cbase + 16 + lm) << 12) + n];
        acc[0][0] = MFMA16(a0, b0, acc[0][0]);
        acc[0][1] = MFMA16(a0, b1, acc[0][1]);
        acc[1][0] = MFMA16(a1, b0, acc[1][0]);
        acc[1][1] = MFMA16(a1, b1, acc[1][1]);
    }
    for (int i = tid; i < 1024; i += 256) ((float*)AS)[i] = 0.f;
    __syncthreads();
#pragma unroll
    for (int mt = 0; mt < 2; ++mt)
#pragma unroll
        for (int nt = 0; nt < 2; ++nt)
#pragma unroll
            for (int r = 0; r < 4; ++r)
                atomicAdd(&AS[mt * 16 + (l >> 4) * 4 + r][nt * 16 + lm], acc[mt][nt][r]);
    __syncthreads();
    if (tid < 32) {
        const int c = tid;
        float qsc = qss[cbase + c] * prm[P_TEMP + h];
        float row[32];
        float m = -1e30f;
#pragma unroll
        for (int d = 0; d < 32; ++d) {
            row[d] = AS[c][d] * qsc * kss[cbase + d];
            m = fmaxf(m, row[d]);
        }
        float s = 0.f;
#pragma unroll
        for (int d = 0; d < 32; ++d) {
            row[d] = __expf(row[d] - m);
            s += row[d];
        }
        float inv = 1.0f / s;
        float* dst = attn + ((b * 8 + h) << 10) + c * 32;
#pragma unroll
        for (int d = 0; d < 32; ++d) dst[d] = row[d] * inv;
    }
}

// ---------------------------------------------------------------------------
// K4: att = attn @ v; writes attT bf16 [b][n][c]; fused gap (sum) atomics.
// ---------------------------------------------------------------------------
__global__ __launch_bounds__(256) void k_attv2(const float* __restrict__ attn,
                                               const float* __restrict__ vb,
                                               bf16* __restrict__ attT,
                                               float* __restrict__ gap) {
    __shared__ float A[32][32];
    __shared__ float G[256][32];
    const int b = blockIdx.z, h = blockIdx.y;
    const int tid = threadIdx.x;
    const int n = blockIdx.x * 256 + tid;
    for (int i = tid; i < 1024; i += 256) ((float*)A)[i] = attn[((b * 8 + h) << 10) + i];
    __syncthreads();
    const int base = ((b * 256 + h * 32) << 12) + n;
    float vv[32];
#pragma unroll
    for (int d = 0; d < 32; ++d) vv[d] = vb[base + (d << 12)];
    float av[32];
#pragma unroll
    for (int c = 0; c < 32; ++c) {
        float s = 0.f;
#pragma unroll
        for (int d = 0; d < 32; ++d) s = fmaf(A[c][d], vv[d], s);
        av[c] = s;
        G[tid][c] = s;
    }
    const int obase = (((b << 12) + n) << 8) + h * 32;
#pragma unroll
    for (int g = 0; g < 4; ++g) {
        short8 p;
#pragma unroll
        for (int u = 0; u < 8; ++u) p[u] = f2s(av[g * 8 + u]);
        *(short8*)&attT[obase + g * 8] = p;
    }
    __syncthreads();
    if (tid < 32) {
        float s = 0.f;
        for (int t = 0; t < 256; ++t) s += G[t][tid];   // bank-conflict-free (stride 32)
        atomicAdd(&gap[(b << 8) + h * 32 + tid], s);
    }
}

// ---------------------------------------------------------------------------
// K5: depthwise 3x3 SAME + bias + BN + GELU on v (fp32 in/out).
// ---------------------------------------------------------------------------
__global__ __launch_bounds__(256) void k_dwconv(const float* __restrict__ vb,
                                                const float* __restrict__ prm,
                                                float* __restrict__ conv) {
    const int b = blockIdx.z, c = blockIdx.y;
    const int tid = threadIdx.x;
    const int y = blockIdx.x * 4 + (tid >> 6);
    const int xp = tid & 63;
    float w[9];
#pragma unroll
    for (int i = 0; i < 9; ++i) w[i] = prm[P_DWK + c * 9 + i];
    const float* src = vb + (((b << 8) + c) << 12);
    float acc = 0.f;
#pragma unroll
    for (int ky = 0; ky < 3; ++ky) {
        int yy = y + ky - 1;
        if (yy < 0 || yy > 63) continue;
#pragma unroll
        for (int kx = 0; kx < 3; ++kx) {
            int xx = xp + kx - 1;
            if (xx < 0 || xx > 63) continue;
            acc = fmaf(src[yy * 64 + xx], w[ky * 3 + kx], acc);
        }
    }
    acc += prm[P_DWB + c];
    acc = (acc - prm[P_DWM + c]) * rsqrtf(prm[P_DWV + c] + 1e-3f) * prm[P_DWG + c] + prm[P_DWBT + c];
    conv[(((b << 8) + c) << 12) + y * 64 + xp] = gelu_exact(acc);
}

// ---------------------------------------------------------------------------
// K6: conv fp32 [c][n] -> convT bf16 [n][c].
// ---------------------------------------------------------------------------
__global__ __launch_bounds__(256) void k_tr(const float* __restrict__ conv,
                                            bf16* __restrict__ convT) {
    __shared__ short T[64][72];
    const int b = blockIdx.z, c0 = blockIdx.y * 64, n0 = blockIdx.x * 64;
    const int tid = threadIdx.x;
    const int nn = tid & 63, cc0 = tid >> 6;
#pragma unroll
    for (int i = 0; i < 16; ++i) {
        int cc = cc0 + i * 4;
        T[nn][cc] = f2s(conv[(((b << 8) + c0 + cc) << 12) + n0 + nn]);
    }
    __syncthreads();
    const int rn = tid >> 3, oct = tid & 7;
#pragma unroll
    for (int i = 0; i < 2; ++i) {
        int n = rn + i * 32;
        *(short8*)&convT[(((b << 12) + n0 + n) << 8) + c0 + oct * 8] =
            *(const short8*)&T[n][oct * 8];
    }
}

// ---------------------------------------------------------------------------
// K7: channel gate (gap holds SUMS; scale by 1/4096 here).
// ---------------------------------------------------------------------------
__global__ __launch_bounds__(256) void k_cm(const float* __restrict__ gap,
                                            const float* __restrict__ prm,
                                            float* __restrict__ sigcm) {
    const int b = blockIdx.x;
    const int tid = threadIdx.x;
    __shared__ float gl[256];
    __shared__ float t1[32];
    gl[tid] = gap[(b << 8) + tid] * (1.0f / 4096.0f);
    __syncthreads();
    if (tid < 32) {
        float s = prm[P_CIB1 + tid];
        for (int c = 0; c < 256; ++c) s = fmaf(gl[c], prm[P_CIW1 + c * 32 + tid], s);
        s = (s - prm[P_CIM + tid]) * rsqrtf(prm[P_CIV + tid] + 1e-3f) * prm[P_CIG + tid] + prm[P_CIBT + tid];
        t1[tid] = gelu_exact(s);
    }
    __syncthreads();
    float s = prm[P_CIB2 + tid];
#pragma unroll
    for (int o = 0; o < 32; ++o) s = fmaf(t1[o], prm[P_CIW2 + o * 256 + tid], s);
    sigcm[(b << 8) + tid] = sigmoidf_(s);
}

// ---------------------------------------------------------------------------
// K8: spatial gate from convT (vectorized row reads).
// ---------------------------------------------------------------------------
__global__ __launch_bounds__(256) void k_sm2(const bf16* __restrict__ convT,
                                             const float* __restrict__ prm,
                                             float* __restrict__ sigsm) {
    __shared__ float W1[256][16];
    const int b = blockIdx.y;
    const int tid = threadIdx.x;
    const int n = blockIdx.x * 256 + tid;
    for (int i = tid; i < 4096; i += 256) W1[i >> 4][i & 15] = prm[P_SIW1 + i];
    __syncthreads();
    float acc[16];
#pragma unroll
    for (int o = 0; o < 16; ++o) acc[o] = 0.f;
    const bf16* src = convT + (((b << 12) + n) << 8);
#pragma unroll 4
    for (int g = 0; g < 32; ++g) {
        short8 p = *(const short8*)&src[g * 8];
#pragma unroll
        for (int u = 0; u < 8; ++u) {
            float v = s2f(p[u]);
            int c = g * 8 + u;
#pragma unroll
            for (int o = 0; o < 16; ++o) acc[o] = fmaf(v, W1[c][o], acc[o]);
        }
    }
    float sm = prm[P_SIB2];
#pragma unroll
    for (int o = 0; o < 16; ++o) {
        float t = acc[o] + prm[P_SIB1 + o];
        t = (t - prm[P_SIM + o]) * rsqrtf(prm[P_SIV + o] + 1e-3f) * prm[P_SIG + o] + prm[P_SIBT + o];
        sm = fmaf(gelu_exact(t), prm[P_SIW2 + o], sm);
    }
    sigsm[(b << 12) + n] = sigmoidf_(sm);
}

// ---------------------------------------------------------------------------
// K9: final projection (MFMA, vectorized staging of gated Z).
// ---------------------------------------------------------------------------
__global__ __launch_bounds__(256) void k_proj_m2(const bf16* __restrict__ attT,
                                                 const bf16* __restrict__ convT,
                                                 const float* __restrict__ sigsm,
                                                 const float* __restrict__ sigcm,
                                                 const bf16* __restrict__ wpT,
                                                 const float* __restrict__ prm,
                                                 const unsigned* __restrict__ flag,
                                                 void* __restrict__ out) {
    __shared__ short As[64][72];
    __shared__ short Bs[128][72];
    __shared__ float scs[256];
    const bool isbf = (*flag != 0u);
    const int b = blockIdx.z, j0 = blockIdx.y * 64, n0 = blockIdx.x * 128;
    const int tid = threadIdx.x;
    const int wid = tid >> 6, l = tid & 63;
    const int lm = l & 15, lk = (l >> 4) * 8;
    const int srow = tid >> 3, soct = tid & 7;
    scs[tid] = sigcm[(b << 8) + tid];
    floatx4 acc[8];
#pragma unroll
    for (int i = 0; i < 8; ++i) acc[i] = (floatx4){0.f, 0.f, 0.f, 0.f};

    for (int k0 = 0; k0 < 256; k0 += 64) {
        __syncthreads();
#pragma unroll
        for (int i = 0; i < 2; ++i) {
            int j = srow + i * 32;
            *(short8*)&As[j][soct * 8] =
                *(const short8*)&wpT[((j0 + j) << 8) + k0 + soct * 8];
        }
#pragma unroll
        for (int i = 0; i < 4; ++i) {
            int n = srow + i * 32;
            int rbase = (((b << 12) + n0 + n) << 8) + k0 + soct * 8;
            short8 pa = *(const short8*)&attT[rbase];
            short8 pc = *(const short8*)&convT[rbase];
            float sv = sigsm[(b << 12) + n0 + n];
            short8 pz;
#pragma unroll
            for (int u = 0; u < 8; ++u)
                pz[u] = f2s(s2f(pa[u]) * sv + s2f(pc[u]) * scs[k0 + soct * 8 + u]);
            *(short8*)&Bs[n][soct * 8] = pz;
        }
        __syncthreads();
#pragma unroll
        for (int h = 0; h < 2; ++h) {
            short8 af = *(const short8*)&As[wid * 16 + lm][h * 32 + lk];
#pragma unroll
            for (int nt = 0; nt < 8; ++nt) {
                short8 bfr = *(const short8*)&Bs[nt * 16 + lm][h * 32 + lk];
                acc[nt] = MFMA16(af, bfr, acc[nt]);
            }
        }
    }
    const int jb = j0 + wid * 16 + (l >> 4) * 4;
    float bp[4];
#pragma unroll
    for (int r = 0; r < 4; ++r) bp[r] = prm[P_BPROJ + jb + r];
#pragma unroll
    for (int nt = 0; nt < 8; ++nt) {
        int n = n0 + nt * 16 + lm;
#pragma unroll
        for (int r = 0; r < 4; ++r) {
            int idx = (((b << 8) + jb + r) << 12) + n;
            float val = acc[nt][r] + bp[r];
            if (isbf) ((bf16*)out)[idx] = f2b(val);
            else ((float*)out)[idx] = val;
        }
    }
}

// ---------------------------------------------------------------------------
extern "C" void kernel_launch(void* const* d_in, const int* in_sizes, int n_in,
                              void* d_out, int out_size, void* d_ws, size_t ws_size,
                              hipStream_t stream) {
    char* ws = (char*)d_ws;
    // layout (bytes):
    //   [0,    33.5M) v fp32            -> convT bf16 (after dwconv/attv read v)
    //   [33.5M,50.3M) xT bf16           -> attT bf16 (after qkv reads xT)
    //   [50.3M,67.1M) q bf16            -> conv fp32 [50.3M,83.9M) after k_qk2
    //   [67.1M,83.9M) k bf16
    //   [83.9M, ...)  wqkvT, wprojT, attn, qss, kss, gap, sigcm, sigsm, prm, flag
    float* vb     = (float*)(ws);
    bf16*  convT  = (bf16*) (ws);
    bf16*  xT     = (bf16*) (ws + 33554432);
    bf16*  attT   = (bf16*) (ws + 33554432);
    bf16*  qb     = (bf16*) (ws + 50331648);
    float* conv   = (float*)(ws + 50331648);
    bf16*  kb     = (bf16*) (ws + 67108864);
    bf16*  wqkvT  = (bf16*) (ws + 83886080);
    bf16*  wprojT = (bf16*) (ws + 84279296);
    float* attn   = (float*)(ws + 84410368);
    float* qss    = (float*)(ws + 84672512);
    float* kss    = (float*)(ws + 84680704);
    float* gap    = (float*)(ws + 84688896);
    float* sigcm  = (float*)(ws + 84697088);
    float* sigsm  = (float*)(ws + 84705280);
    float* prm    = (float*)(ws + 84836352);
    unsigned* flag = (unsigned*)(ws + 84936704);

    k_sniff<<<1, 256, 0, stream>>>((const unsigned*)d_in[0], flag);

    CvtArgs a;
    const int map_src[24] = {3, 4, 5, 6, 7, 8, 9, 10, 11, 12, 13, 14, 15, 16, 17,
                             18, 19, 20, 21, 22, 23, 24, 25, 26};
    const int map_dst[24] = {P_BPROJ, P_DWK, P_DWB, P_DWG, P_DWBT, P_DWM, P_DWV,
                             P_CIG, P_CIBT, P_CIM, P_CIV, P_SIG, P_SIBT, P_SIM, P_SIV,
                             P_CIW1, P_CIB1, P_CIW2, P_CIB2, P_SIW1, P_SIB1, P_SIW2,
                             P_SIB2, P_TEMP};
    for (int i = 0; i < 24; ++i) {
        a.src[i] = d_in[map_src[i]];
        a.dst[i] = map_dst[i];
        a.cnt[i] = in_sizes[map_src[i]];
    }
    k_cvt<<<24, 256, 0, stream>>>(a, prm, flag);

    hipMemsetAsync(qss, 0, 24576, stream);   // qss, kss, gap (contiguous)

    k_xt<<<dim3(64, 4, 8), 256, 0, stream>>>(d_in[0], flag, xT);
    k_wt<<<dim3(12, 4), 256, 0, stream>>>(d_in[1], flag, wqkvT, 768);
    k_wt<<<dim3(4, 4), 256, 0, stream>>>(d_in[2], flag, wprojT, 256);

    k_qkv_m2<<<dim3(32, 12, 8), 256, 0, stream>>>(xT, wqkvT, qb, kb, vb, qss, kss);
    k_rsqrt<<<16, 256, 0, stream>>>(qss, kss);
    k_qk2<<<dim3(8, 8), 256, 0, stream>>>(qb, kb, qss, kss, prm, attn);
    k_attv2<<<dim3(16, 8, 8), 256, 0, stream>>>(attn, vb, attT, gap);
    k_dwconv<<<dim3(16, 256, 8), 256, 0, stream>>>(vb, prm, conv);
    k_tr<<<dim3(64, 4, 8), 256, 0, stream>>>(conv, convT);
    k_cm<<<8, 256, 0, stream>>>(gap, prm, sigcm);
    k_sm2<<<dim3(16, 8), 256, 0, stream>>>(convT, prm, sigsm);
    k_proj_m2<<<dim3(32, 4, 8), 256, 0, stream>>>(attT, convT, sigsm, sigcm,
                                                  wprojT, prm, flag, d_out);
}

// Round 6
// 177.981 us; speedup vs baseline: 2.8075x; 1.2484x over previous
//
#include <hip/hip_runtime.h>
#include <hip/hip_bf16.h>
#include <math.h>

typedef __hip_bfloat16 bf16;
typedef __attribute__((ext_vector_type(8))) short short8;
typedef __attribute__((ext_vector_type(4))) short short4v;
typedef __attribute__((ext_vector_type(4))) float floatx4;

__device__ __forceinline__ bf16 f2b(float v) { return __float2bfloat16(v); }
__device__ __forceinline__ short f2s(float v) {
    bf16 h = __float2bfloat16(v);
    return *reinterpret_cast<short*>(&h);
}
__device__ __forceinline__ float s2f(short s) {
    union { unsigned u; float f; } t;
    t.u = ((unsigned)(unsigned short)s) << 16;
    return t.f;
}
__device__ __forceinline__ float gelu_exact(float x) {
    return 0.5f * x * (1.0f + erff(x * 0.70710678118654752440f));
}
__device__ __forceinline__ float sigmoidf_(float x) {
    return 1.0f / (1.0f + __expf(-x));
}
__device__ __forceinline__ float ldin(const void* p, int i, bool isbf) {
    return isbf ? s2f(((const short*)p)[i]) : ((const float*)p)[i];
}
#define MFMA16(a, b, c) __builtin_amdgcn_mfma_f32_16x16x32_bf16(a, b, c, 0, 0, 0)

// fp32 params block layout (offsets in floats)
#define P_DWK    0
#define P_DWB    2304
#define P_DWG    2560
#define P_DWBT   2816
#define P_DWM    3072
#define P_DWV    3328
#define P_CIW1   3584
#define P_CIB1   11776
#define P_CIG    11808
#define P_CIBT   11840
#define P_CIM    11872
#define P_CIV    11904
#define P_CIW2   11936
#define P_CIB2   20128
#define P_SIW1   20384
#define P_SIB1   24480
#define P_SIG    24496
#define P_SIBT   24512
#define P_SIM    24528
#define P_SIV    24544
#define P_SIW2   24560
#define P_SIB2   24576
#define P_TEMP   24577
#define P_BPROJ  24585

// ---------------------------------------------------------------------------
// K0: dtype sniffer (bf16-packed vs fp32 input buffers).
// ---------------------------------------------------------------------------
__global__ __launch_bounds__(256) void k_sniff(const unsigned* __restrict__ x,
                                               unsigned* __restrict__ flag) {
    int cnt = 0;
    for (int i = threadIdx.x; i < 4096; i += 256) {
        unsigned lo = x[i] & 0xFFFFu;
        unsigned e = (lo >> 7) & 0xFFu;
        cnt += (e >= 0x66u && e <= 0x8Au) ? 1 : 0;
    }
    __shared__ int red[256];
    red[threadIdx.x] = cnt;
    __syncthreads();
    for (int o = 128; o > 0; o >>= 1) {
        if (threadIdx.x < o) red[threadIdx.x] += red[threadIdx.x + o];
        __syncthreads();
    }
    if (threadIdx.x == 0) *flag = (red[0] > 2048) ? 1u : 0u;
}

// ---------------------------------------------------------------------------
// K0b: convert all small params to fp32 block.
// ---------------------------------------------------------------------------
struct CvtArgs { const void* src[24]; int dst[24]; int cnt[24]; };

__global__ __launch_bounds__(256) void k_cvt(CvtArgs a, float* __restrict__ prm,
                                             const unsigned* __restrict__ flag) {
    const bool isbf = (*flag != 0u);
    const int e = blockIdx.x;
    const void* s = a.src[e];
    float* d = prm + a.dst[e];
    const int n = a.cnt[e];
    for (int i = threadIdx.x; i < n; i += 256) d[i] = ldin(s, i, isbf);
}

// ===========================================================================
// Swizzled 64x64 transpose tile helpers.
// T row stride = 72 shorts (144B). Column-groups XOR-swizzled by (row&7):
// write elem (row, col): T[row][(((col>>3) ^ (row&7)) << 3) + (col&7)]
// read 8 elems (row, oct): *(short8*)&T[row][((oct ^ (row&7)) << 3)]
// (bijective per row: slot g^(row&7) holds col-group g)
// ===========================================================================

// ---------------------------------------------------------------------------
// K_xt2: x [b][c][n] (fp32 or bf16) -> xT bf16 [b][n][c]. Vectorized loads.
// ---------------------------------------------------------------------------
__global__ __launch_bounds__(256) void k_xt2(const void* __restrict__ x,
                                             const unsigned* __restrict__ flag,
                                             bf16* __restrict__ xT) {
    __shared__ short T[64][72];
    const bool isbf = (*flag != 0u);
    const int b = blockIdx.z, c0 = blockIdx.y * 64, n0 = blockIdx.x * 64;
    const int tid = threadIdx.x;
    const int cc = tid >> 3, oct = tid & 7;
#pragma unroll
    for (int i = 0; i < 2; ++i) {
        int col = cc + i * 32;                 // c within tile
        long gbase = ((long)(b * 256 + c0 + col) << 12) + n0 + oct * 8;
        short v[8];
        if (isbf) {
            short8 p = *(const short8*)((const short*)x + gbase);
#pragma unroll
            for (int u = 0; u < 8; ++u) v[u] = p[u];
        } else {
            floatx4 q0 = *(const floatx4*)((const float*)x + gbase);
            floatx4 q1 = *(const floatx4*)((const float*)x + gbase + 4);
#pragma unroll
            for (int u = 0; u < 4; ++u) { v[u] = f2s(q0[u]); v[4 + u] = f2s(q1[u]); }
        }
        int row0 = oct * 8;                    // n within tile
#pragma unroll
        for (int u = 0; u < 8; ++u) {
            int row = row0 + u;
            T[row][(((col >> 3) ^ (row & 7)) << 3) + (col & 7)] = v[u];
        }
    }
    __syncthreads();
    const int rn = tid >> 3;
#pragma unroll
    for (int i = 0; i < 2; ++i) {
        int n = rn + i * 32;
        short8 p = *(const short8*)&T[n][((oct ^ (n & 7)) << 3)];
        *(short8*)&xT[(((b << 12) + n0 + n) << 8) + c0 + oct * 8] = p;
    }
}

// ---------------------------------------------------------------------------
// K_wt2: w [c][j] (256 x ncols) -> wT bf16 [j][c]. Vectorized loads.
// ---------------------------------------------------------------------------
__global__ __launch_bounds__(256) void k_wt2(const void* __restrict__ src,
                                             const unsigned* __restrict__ flag,
                                             bf16* __restrict__ dst, int ncols) {
    __shared__ short T[64][72];
    const bool isbf = (*flag != 0u);
    const int j0 = blockIdx.x * 64, c0 = blockIdx.y * 64;
    const int tid = threadIdx.x;
    const int cc = tid >> 3, oct = tid & 7;
#pragma unroll
    for (int i = 0; i < 2; ++i) {
        int col = cc + i * 32;                 // c within tile
        long gbase = (long)(c0 + col) * ncols + j0 + oct * 8;
        short v[8];
        if (isbf) {
            short8 p = *(const short8*)((const short*)src + gbase);
#pragma unroll
            for (int u = 0; u < 8; ++u) v[u] = p[u];
        } else {
            floatx4 q0 = *(const floatx4*)((const float*)src + gbase);
            floatx4 q1 = *(const floatx4*)((const float*)src + gbase + 4);
#pragma unroll
            for (int u = 0; u < 4; ++u) { v[u] = f2s(q0[u]); v[4 + u] = f2s(q1[u]); }
        }
        int row0 = oct * 8;                    // j within tile
#pragma unroll
        for (int u = 0; u < 8; ++u) {
            int row = row0 + u;
            T[row][(((col >> 3) ^ (row & 7)) << 3) + (col & 7)] = v[u];
        }
    }
    __syncthreads();
    const int rj = tid >> 3;
#pragma unroll
    for (int i = 0; i < 2; ++i) {
        int j = rj + i * 32;
        short8 p = *(const short8*)&T[j][((oct ^ (j & 7)) << 3)];
        *(short8*)&dst[((j0 + j) << 8) + c0 + oct * 8] = p;
    }
}

// ---------------------------------------------------------------------------
// K1: qkv GEMM (MFMA, vectorized staging).
// ---------------------------------------------------------------------------
__global__ __launch_bounds__(256) void k_qkv_m2(const bf16* __restrict__ xT,
                                                const bf16* __restrict__ wT,
                                                bf16* __restrict__ qb,
                                                bf16* __restrict__ kb,
                                                float* __restrict__ vb,
                                                float* __restrict__ qss,
                                                float* __restrict__ kss) {
    __shared__ short As[64][72];
    __shared__ short Bs[128][72];
    const int b = blockIdx.z, j0 = blockIdx.y * 64, n0 = blockIdx.x * 128;
    const int tid = threadIdx.x;
    const int wid = tid >> 6, l = tid & 63;
    const int lm = l & 15, lk = (l >> 4) * 8;
    const int srow = tid >> 3, soct = tid & 7;
    floatx4 acc[8];
#pragma unroll
    for (int i = 0; i < 8; ++i) acc[i] = (floatx4){0.f, 0.f, 0.f, 0.f};

    for (int k0 = 0; k0 < 256; k0 += 64) {
        __syncthreads();
#pragma unroll
        for (int i = 0; i < 2; ++i) {
            int j = srow + i * 32;
            *(short8*)&As[j][soct * 8] =
                *(const short8*)&wT[((j0 + j) << 8) + k0 + soct * 8];
        }
#pragma unroll
        for (int i = 0; i < 4; ++i) {
            int n = srow + i * 32;
            *(short8*)&Bs[n][soct * 8] =
                *(const short8*)&xT[(((b << 12) + n0 + n) << 8) + k0 + soct * 8];
        }
        __syncthreads();
#pragma unroll
        for (int h = 0; h < 2; ++h) {
            short8 af = *(const short8*)&As[wid * 16 + lm][h * 32 + lk];
#pragma unroll
            for (int nt = 0; nt < 8; ++nt) {
                short8 bfr = *(const short8*)&Bs[nt * 16 + lm][h * 32 + lk];
                acc[nt] = MFMA16(af, bfr, acc[nt]);
            }
        }
    }
    const int y = blockIdx.y;
    const int jloc = (y & 3) * 64 + wid * 16 + (l >> 4) * 4;
    float sq[4] = {0.f, 0.f, 0.f, 0.f};
    if (y < 4) {
#pragma unroll
        for (int nt = 0; nt < 8; ++nt) {
            int n = n0 + nt * 16 + lm;
#pragma unroll
            for (int r = 0; r < 4; ++r) {
                float vf = acc[nt][r];
                qb[(((b << 8) + jloc + r) << 12) + n] = f2b(vf);
                sq[r] = fmaf(vf, vf, sq[r]);
            }
        }
    } else if (y < 8) {
#pragma unroll
        for (int nt = 0; nt < 8; ++nt) {
            int n = n0 + nt * 16 + lm;
#pragma unroll
            for (int r = 0; r < 4; ++r) {
                float vf = acc[nt][r];
                kb[(((b << 8) + jloc + r) << 12) + n] = f2b(vf);
                sq[r] = fmaf(vf, vf, sq[r]);
            }
        }
    } else {
#pragma unroll
        for (int nt = 0; nt < 8; ++nt) {
            int n = n0 + nt * 16 + lm;
#pragma unroll
            for (int r = 0; r < 4; ++r)
                vb[(((b << 8) + jloc + r) << 12) + n] = acc[nt][r];
        }
    }
    if (y < 8) {
        __syncthreads();
        float* red = (float*)&As[0][0];
        const int rbase = wid * 16 + (l >> 4) * 4;
#pragma unroll
        for (int r = 0; r < 4; ++r) red[(rbase + r) * 16 + lm] = sq[r];
        __syncthreads();
        if (tid < 64) {
            float s = 0.f;
#pragma unroll
            for (int i = 0; i < 16; ++i) s += red[tid * 16 + i];
            float* dst = (y < 4) ? qss : kss;
            atomicAdd(&dst[(b << 8) + (y & 3) * 64 + tid], s);
        }
    }
}

// ---------------------------------------------------------------------------
// K3: QK^T partials (MFMA over n), 4 n-chunks of 1024 -> attn_part[chunk].
// ---------------------------------------------------------------------------
__global__ __launch_bounds__(256) void k_qk2p(const bf16* __restrict__ qb,
                                              const bf16* __restrict__ kb,
                                              float* __restrict__ attn_part) {
    __shared__ float AS[32][32];
    const int h = blockIdx.x, b = blockIdx.y, nc = blockIdx.z;
    const int tid = threadIdx.x;
    const int wid = tid >> 6, l = tid & 63;
    const int lm = l & 15, lk = (l >> 4) * 8;
    floatx4 acc[2][2];
#pragma unroll
    for (int i = 0; i < 2; ++i)
#pragma unroll
        for (int j = 0; j < 2; ++j) acc[i][j] = (floatx4){0.f, 0.f, 0.f, 0.f};
    const int cbase = (b << 8) + h * 32;
    for (int it = 0; it < 8; ++it) {
        int n = nc * 1024 + wid * 256 + it * 32 + lk;
        short8 a0 = *(const short8*)&qb[((cbase + lm) << 12) + n];
        short8 a1 = *(const short8*)&qb[((cbase + 16 + lm) << 12) + n];
        short8 b0 = *(const short8*)&kb[((cbase + lm) << 12) + n];
        short8 b1 = *(const short8*)&kb[((cbase + 16 + lm) << 12) + n];
        acc[0][0] = MFMA16(a0, b0, acc[0][0]);
        acc[0][1] = MFMA16(a0, b1, acc[0][1]);
        acc[1][0] = MFMA16(a1, b0, acc[1][0]);
        acc[1][1] = MFMA16(a1, b1, acc[1][1]);
    }
    for (int i = tid; i < 1024; i += 256) ((float*)AS)[i] = 0.f;
    __syncthreads();
#pragma unroll
    for (int mt = 0; mt < 2; ++mt)
#pragma unroll
        for (int nt = 0; nt < 2; ++nt)
#pragma unroll
            for (int r = 0; r < 4; ++r)
                atomicAdd(&AS[mt * 16 + (l >> 4) * 4 + r][nt * 16 + lm], acc[mt][nt][r]);
    __syncthreads();
    float* dst = attn_part + (((nc * 64) + (b * 8 + h)) << 10);
    for (int i = tid; i < 1024; i += 256) dst[i] = ((float*)AS)[i];
}

// ---------------------------------------------------------------------------
// K3b: sum 4 partials + l2 scales (rsqrt of raw sums) + temp + softmax.
// ---------------------------------------------------------------------------
__global__ __launch_bounds__(64) void k_softmax2(const float* __restrict__ attn_part,
                                                 const float* __restrict__ qss,
                                                 const float* __restrict__ kss,
                                                 const float* __restrict__ prm,
                                                 float* __restrict__ attn) {
    __shared__ float A[32][32];
    const int h = blockIdx.x, b = blockIdx.y;
    const int tid = threadIdx.x;
    const int page = (b * 8 + h) << 10;
    for (int i = tid; i < 1024; i += 64) {
        float s = attn_part[page + i] + attn_part[(64 << 10) + page + i] +
                  attn_part[(128 << 10) + page + i] + attn_part[(192 << 10) + page + i];
        ((float*)A)[i] = s;
    }
    __syncthreads();
    if (tid < 32) {
        const int c = tid;
        const int cbase = (b << 8) + h * 32;
        float qsc = rsqrtf(fmaxf(qss[cbase + c], 1e-12f)) * prm[P_TEMP + h];
        float row[32];
        float m = -1e30f;
#pragma unroll
        for (int d = 0; d < 32; ++d) {
            row[d] = A[c][d] * qsc * rsqrtf(fmaxf(kss[cbase + d], 1e-12f));
            m = fmaxf(m, row[d]);
        }
        float s = 0.f;
#pragma unroll
        for (int d = 0; d < 32; ++d) {
            row[d] = __expf(row[d] - m);
            s += row[d];
        }
        float inv = 1.0f / s;
        float* dst = attn + page + c * 32;
#pragma unroll
        for (int d = 0; d < 32; ++d) dst[d] = row[d] * inv;
    }
}

// ---------------------------------------------------------------------------
// K4: att = attn @ v; writes attT bf16 [b][n][c]; fused gap (sum) atomics.
// ---------------------------------------------------------------------------
__global__ __launch_bounds__(256) void k_attv2(const float* __restrict__ attn,
                                               const float* __restrict__ vb,
                                               bf16* __restrict__ attT,
                                               float* __restrict__ gap) {
    __shared__ float A[32][32];
    __shared__ float G[256][32];
    const int b = blockIdx.z, h = blockIdx.y;
    const int tid = threadIdx.x;
    const int n = blockIdx.x * 256 + tid;
    for (int i = tid; i < 1024; i += 256) ((float*)A)[i] = attn[((b * 8 + h) << 10) + i];
    __syncthreads();
    const int base = ((b * 256 + h * 32) << 12) + n;
    float vv[32];
#pragma unroll
    for (int d = 0; d < 32; ++d) vv[d] = vb[base + (d << 12)];
    float av[32];
#pragma unroll
    for (int c = 0; c < 32; ++c) {
        float s = 0.f;
#pragma unroll
        for (int d = 0; d < 32; ++d) s = fmaf(A[c][d], vv[d], s);
        av[c] = s;
        G[tid][c] = s;
    }
    const int obase = (((b << 12) + n) << 8) + h * 32;
#pragma unroll
    for (int g = 0; g < 4; ++g) {
        short8 p;
#pragma unroll
        for (int u = 0; u < 8; ++u) p[u] = f2s(av[g * 8 + u]);
        *(short8*)&attT[obase + g * 8] = p;
    }
    __syncthreads();
    if (tid < 32) {
        float s = 0.f;
        for (int t = 0; t < 256; ++t) s += G[t][tid];
        atomicAdd(&gap[(b << 8) + h * 32 + tid], s);
    }
}

// ---------------------------------------------------------------------------
// K5: depthwise 3x3 + bias + BN + GELU, LDS-staged, bf16 output [c][n].
// ---------------------------------------------------------------------------
__global__ __launch_bounds__(256) void k_dwconv2(const float* __restrict__ vb,
                                                 const float* __restrict__ prm,
                                                 bf16* __restrict__ convb) {
    __shared__ float S[18][66];
    const int b = blockIdx.z, c = blockIdx.y, y0 = blockIdx.x * 16;
    const int tid = threadIdx.x;
    const float* src = vb + (((b << 8) + c) << 12);
    for (int idx = tid; idx < 18 * 66; idx += 256) {
        int r = idx / 66, xcol = idx % 66;
        int gy = y0 + r - 1, gx = xcol - 1;
        float v = 0.f;
        if (gy >= 0 && gy < 64 && gx >= 0 && gx < 64) v = src[gy * 64 + gx];
        S[r][xcol] = v;
    }
    float w[9];
#pragma unroll
    for (int i = 0; i < 9; ++i) w[i] = prm[P_DWK + c * 9 + i];
    const float bias = prm[P_DWB + c];
    const float scale = rsqrtf(prm[P_DWV + c] + 1e-3f) * prm[P_DWG + c];
    const float shift = prm[P_DWBT + c] - prm[P_DWM + c] * scale;
    __syncthreads();
    const int row = tid >> 4, xq = (tid & 15) * 4;
    short4v o;
#pragma unroll
    for (int u = 0; u < 4; ++u) {
        int x = xq + u;
        float acc = bias;
#pragma unroll
        for (int ky = 0; ky < 3; ++ky)
#pragma unroll
            for (int kx = 0; kx < 3; ++kx)
                acc = fmaf(S[row + ky][x + kx], w[ky * 3 + kx], acc);
        acc = acc * scale + shift;
        o[u] = f2s(gelu_exact(acc));
    }
    *(short4v*)&convb[(((b << 8) + c) << 12) + (y0 + row) * 64 + xq] = o;
}

// ---------------------------------------------------------------------------
// K6: conv bf16 [c][n] -> convT bf16 [n][c] (swizzled-tile transpose).
// ---------------------------------------------------------------------------
__global__ __launch_bounds__(256) void k_tr2(const bf16* __restrict__ convb,
                                             bf16* __restrict__ convT) {
    __shared__ short T[64][72];
    const int b = blockIdx.z, c0 = blockIdx.y * 64, n0 = blockIdx.x * 64;
    const int tid = threadIdx.x;
    const int cc = tid >> 3, oct = tid & 7;
#pragma unroll
    for (int i = 0; i < 2; ++i) {
        int col = cc + i * 32;
        short8 p = *(const short8*)((const short*)convb +
                                    (((long)((b << 8) + c0 + col)) << 12) + n0 + oct * 8);
        int row0 = oct * 8;
#pragma unroll
        for (int u = 0; u < 8; ++u) {
            int row = row0 + u;
            T[row][(((col >> 3) ^ (row & 7)) << 3) + (col & 7)] = p[u];
        }
    }
    __syncthreads();
    const int rn = tid >> 3;
#pragma unroll
    for (int i = 0; i < 2; ++i) {
        int n = rn + i * 32;
        short8 p = *(const short8*)&T[n][((oct ^ (n & 7)) << 3)];
        *(short8*)&convT[(((b << 12) + n0 + n) << 8) + c0 + oct * 8] = p;
    }
}

// ---------------------------------------------------------------------------
// K7: channel gate (gap holds SUMS; scale by 1/4096 here).
// ---------------------------------------------------------------------------
__global__ __launch_bounds__(256) void k_cm(const float* __restrict__ gap,
                                            const float* __restrict__ prm,
                                            float* __restrict__ sigcm) {
    const int b = blockIdx.x;
    const int tid = threadIdx.x;
    __shared__ float gl[256];
    __shared__ float t1[32];
    gl[tid] = gap[(b << 8) + tid] * (1.0f / 4096.0f);
    __syncthreads();
    if (tid < 32) {
        float s = prm[P_CIB1 + tid];
        for (int c = 0; c < 256; ++c) s = fmaf(gl[c], prm[P_CIW1 + c * 32 + tid], s);
        s = (s - prm[P_CIM + tid]) * rsqrtf(prm[P_CIV + tid] + 1e-3f) * prm[P_CIG + tid] + prm[P_CIBT + tid];
        t1[tid] = gelu_exact(s);
    }
    __syncthreads();
    float s = prm[P_CIB2 + tid];
#pragma unroll
    for (int o = 0; o < 32; ++o) s = fmaf(t1[o], prm[P_CIW2 + o * 256 + tid], s);
    sigcm[(b << 8) + tid] = sigmoidf_(s);
}

// ---------------------------------------------------------------------------
// K8: spatial gate from convT (vectorized row reads).
// ---------------------------------------------------------------------------
__global__ __launch_bounds__(256) void k_sm2(const bf16* __restrict__ convT,
                                             const float* __restrict__ prm,
                                             float* __restrict__ sigsm) {
    __shared__ float W1[256][16];
    const int b = blockIdx.y;
    const int tid = threadIdx.x;
    const int n = blockIdx.x * 256 + tid;
    for (int i = tid; i < 4096; i += 256) W1[i >> 4][i & 15] = prm[P_SIW1 + i];
    __syncthreads();
    float acc[16];
#pragma unroll
    for (int o = 0; o < 16; ++o) acc[o] = 0.f;
    const bf16* src = convT + (((b << 12) + n) << 8);
#pragma unroll 4
    for (int g = 0; g < 32; ++g) {
        short8 p = *(const short8*)&src[g * 8];
#pragma unroll
        for (int u = 0; u < 8; ++u) {
            float v = s2f(p[u]);
            int c = g * 8 + u;
#pragma unroll
            for (int o = 0; o < 16; ++o) acc[o] = fmaf(v, W1[c][o], acc[o]);
        }
    }
    float sm = prm[P_SIB2];
#pragma unroll
    for (int o = 0; o < 16; ++o) {
        float t = acc[o] + prm[P_SIB1 + o];
        t = (t - prm[P_SIM + o]) * rsqrtf(prm[P_SIV + o] + 1e-3f) * prm[P_SIG + o] + prm[P_SIBT + o];
        sm = fmaf(gelu_exact(t), prm[P_SIW2 + o], sm);
    }
    sigsm[(b << 12) + n] = sigmoidf_(sm);
}

// ---------------------------------------------------------------------------
// K9: final projection (MFMA, vectorized staging of gated Z).
// ---------------------------------------------------------------------------
__global__ __launch_bounds__(256) void k_proj_m2(const bf16* __restrict__ attT,
                                                 const bf16* __restrict__ convT,
                                                 const float* __restrict__ sigsm,
                                                 const float* __restrict__ sigcm,
                                                 const bf16* __restrict__ wpT,
                                                 const float* __restrict__ prm,
                                                 const unsigned* __restrict__ flag,
                                                 void* __restrict__ out) {
    __shared__ short As[64][72];
    __shared__ short Bs[128][72];
    __shared__ float scs[256];
    const bool isbf = (*flag != 0u);
    const int b = blockIdx.z, j0 = blockIdx.y * 64, n0 = blockIdx.x * 128;
    const int tid = threadIdx.x;
    const int wid = tid >> 6, l = tid & 63;
    const int lm = l & 15, lk = (l >> 4) * 8;
    const int srow = tid >> 3, soct = tid & 7;
    scs[tid] = sigcm[(b << 8) + tid];
    floatx4 acc[8];
#pragma unroll
    for (int i = 0; i < 8; ++i) acc[i] = (floatx4){0.f, 0.f, 0.f, 0.f};

    for (int k0 = 0; k0 < 256; k0 += 64) {
        __syncthreads();
#pragma unroll
        for (int i = 0; i < 2; ++i) {
            int j = srow + i * 32;
            *(short8*)&As[j][soct * 8] =
                *(const short8*)&wpT[((j0 + j) << 8) + k0 + soct * 8];
        }
#pragma unroll
        for (int i = 0; i < 4; ++i) {
            int n = srow + i * 32;
            int rbase = (((b << 12) + n0 + n) << 8) + k0 + soct * 8;
            short8 pa = *(const short8*)&attT[rbase];
            short8 pc = *(const short8*)&convT[rbase];
            float sv = sigsm[(b << 12) + n0 + n];
            short8 pz;
#pragma unroll
            for (int u = 0; u < 8; ++u)
                pz[u] = f2s(s2f(pa[u]) * sv + s2f(pc[u]) * scs[k0 + soct * 8 + u]);
            *(short8*)&Bs[n][soct * 8] = pz;
        }
        __syncthreads();
#pragma unroll
        for (int h = 0; h < 2; ++h) {
            short8 af = *(const short8*)&As[wid * 16 + lm][h * 32 + lk];
#pragma unroll
            for (int nt = 0; nt < 8; ++nt) {
                short8 bfr = *(const short8*)&Bs[nt * 16 + lm][h * 32 + lk];
                acc[nt] = MFMA16(af, bfr, acc[nt]);
            }
        }
    }
    const int jb = j0 + wid * 16 + (l >> 4) * 4;
    float bp[4];
#pragma unroll
    for (int r = 0; r < 4; ++r) bp[r] = prm[P_BPROJ + jb + r];
#pragma unroll
    for (int nt = 0; nt < 8; ++nt) {
        int n = n0 + nt * 16 + lm;
#pragma unroll
        for (int r = 0; r < 4; ++r) {
            int idx = (((b << 8) + jb + r) << 12) + n;
            float val = acc[nt][r] + bp[r];
            if (isbf) ((bf16*)out)[idx] = f2b(val);
            else ((float*)out)[idx] = val;
        }
    }
}

// ---------------------------------------------------------------------------
extern "C" void kernel_launch(void* const* d_in, const int* in_sizes, int n_in,
                              void* d_out, int out_size, void* d_ws, size_t ws_size,
                              hipStream_t stream) {
    char* ws = (char*)d_ws;
    float* vb     = (float*)(ws);
    bf16*  xT     = (bf16*) (ws + 33554432);
    bf16*  attT   = (bf16*) (ws + 33554432);
    bf16*  qb     = (bf16*) (ws + 50331648);
    bf16*  convb  = (bf16*) (ws + 50331648);
    bf16*  kb     = (bf16*) (ws + 67108864);
    bf16*  convT  = (bf16*) (ws + 67108864);
    bf16*  wqkvT  = (bf16*) (ws + 83886080);
    bf16*  wprojT = (bf16*) (ws + 84279296);
    float* attn   = (float*)(ws + 84410368);
    float* attn_p = (float*)(ws + 84672512);
    float* qss    = (float*)(ws + 85721088);
    float* kss    = (float*)(ws + 85729280);
    float* gap    = (float*)(ws + 85737472);
    float* sigcm  = (float*)(ws + 85745664);
    float* sigsm  = (float*)(ws + 85753856);
    float* prm    = (float*)(ws + 85884928);
    unsigned* flag = (unsigned*)(ws + 85985280);

    k_sniff<<<1, 256, 0, stream>>>((const unsigned*)d_in[0], flag);

    CvtArgs a;
    const int map_src[24] = {3, 4, 5, 6, 7, 8, 9, 10, 11, 12, 13, 14, 15, 16, 17,
                             18, 19, 20, 21, 22, 23, 24, 25, 26};
    const int map_dst[24] = {P_BPROJ, P_DWK, P_DWB, P_DWG, P_DWBT, P_DWM, P_DWV,
                             P_CIG, P_CIBT, P_CIM, P_CIV, P_SIG, P_SIBT, P_SIM, P_SIV,
                             P_CIW1, P_CIB1, P_CIW2, P_CIB2, P_SIW1, P_SIB1, P_SIW2,
                             P_SIB2, P_TEMP};
    for (int i = 0; i < 24; ++i) {
        a.src[i] = d_in[map_src[i]];
        a.dst[i] = map_dst[i];
        a.cnt[i] = in_sizes[map_src[i]];
    }
    k_cvt<<<24, 256, 0, stream>>>(a, prm, flag);

    hipMemsetAsync(qss, 0, 24576, stream);   // qss, kss, gap (contiguous)

    k_xt2<<<dim3(64, 4, 8), 256, 0, stream>>>(d_in[0], flag, xT);
    k_wt2<<<dim3(12, 4), 256, 0, stream>>>(d_in[1], flag, wqkvT, 768);
    k_wt2<<<dim3(4, 4), 256, 0, stream>>>(d_in[2], flag, wprojT, 256);

    k_qkv_m2<<<dim3(32, 12, 8), 256, 0, stream>>>(xT, wqkvT, qb, kb, vb, qss, kss);
    k_qk2p<<<dim3(8, 8, 4), 256, 0, stream>>>(qb, kb, attn_p);
    k_softmax2<<<dim3(8, 8), 64, 0, stream>>>(attn_p, qss, kss, prm, attn);
    k_attv2<<<dim3(16, 8, 8), 256, 0, stream>>>(attn, vb, attT, gap);
    k_dwconv2<<<dim3(4, 256, 8), 256, 0, stream>>>(vb, prm, convb);
    k_tr2<<<dim3(64, 4, 8), 256, 0, stream>>>(convb, convT);
    k_cm<<<8, 256, 0, stream>>>(gap, prm, sigcm);
    k_sm2<<<dim3(16, 8), 256, 0, stream>>>(convT, prm, sigsm);
    k_proj_m2<<<dim3(32, 4, 8), 256, 0, stream>>>(attT, convT, sigsm, sigcm,
                                                  wprojT, prm, flag, d_out);
}

// Round 7
// 174.758 us; speedup vs baseline: 2.8593x; 1.0184x over previous
//
#include <hip/hip_runtime.h>
#include <hip/hip_bf16.h>
#include <math.h>

typedef __hip_bfloat16 bf16;
typedef __attribute__((ext_vector_type(8))) short short8;
typedef __attribute__((ext_vector_type(4))) short short4v;
typedef __attribute__((ext_vector_type(4))) float floatx4;

__device__ __forceinline__ bf16 f2b(float v) { return __float2bfloat16(v); }
__device__ __forceinline__ short f2s(float v) {
    bf16 h = __float2bfloat16(v);
    return *reinterpret_cast<short*>(&h);
}
__device__ __forceinline__ float s2f(short s) {
    union { unsigned u; float f; } t;
    t.u = ((unsigned)(unsigned short)s) << 16;
    return t.f;
}
__device__ __forceinline__ float gelu_exact(float x) {
    return 0.5f * x * (1.0f + erff(x * 0.70710678118654752440f));
}
__device__ __forceinline__ float sigmoidf_(float x) {
    return 1.0f / (1.0f + __expf(-x));
}
__device__ __forceinline__ float ldin(const void* p, int i, bool isbf) {
    return isbf ? s2f(((const short*)p)[i]) : ((const float*)p)[i];
}
#define MFMA16(a, b, c) __builtin_amdgcn_mfma_f32_16x16x32_bf16(a, b, c, 0, 0, 0)

// fp32 params block layout (offsets in floats)
#define P_DWK    0
#define P_DWB    2304
#define P_DWG    2560
#define P_DWBT   2816
#define P_DWM    3072
#define P_DWV    3328
#define P_CIW1   3584
#define P_CIB1   11776
#define P_CIG    11808
#define P_CIBT   11840
#define P_CIM    11872
#define P_CIV    11904
#define P_CIW2   11936
#define P_CIB2   20128
#define P_SIW1   20384
#define P_SIB1   24480
#define P_SIG    24496
#define P_SIBT   24512
#define P_SIM    24528
#define P_SIV    24544
#define P_SIW2   24560
#define P_SIB2   24576
#define P_TEMP   24577
#define P_BPROJ  24585

// ---------------------------------------------------------------------------
// K0: dtype sniffer + zero the atomic accumulators (qss|kss|gap, 6144 floats).
// Replaces the in-graph hipMemsetAsync (fillBufferAligned cost ~40us/replay).
// ---------------------------------------------------------------------------
__global__ __launch_bounds__(256) void k_sniff(const unsigned* __restrict__ x,
                                               unsigned* __restrict__ flag,
                                               float* __restrict__ accbuf) {
    for (int i = threadIdx.x; i < 6144; i += 256) accbuf[i] = 0.f;
    int cnt = 0;
    for (int i = threadIdx.x; i < 4096; i += 256) {
        unsigned lo = x[i] & 0xFFFFu;
        unsigned e = (lo >> 7) & 0xFFu;
        cnt += (e >= 0x66u && e <= 0x8Au) ? 1 : 0;
    }
    __shared__ int red[256];
    red[threadIdx.x] = cnt;
    __syncthreads();
    for (int o = 128; o > 0; o >>= 1) {
        if (threadIdx.x < o) red[threadIdx.x] += red[threadIdx.x + o];
        __syncthreads();
    }
    if (threadIdx.x == 0) *flag = (red[0] > 2048) ? 1u : 0u;
}

// ---------------------------------------------------------------------------
// K0b: convert all small params to fp32 block.
// ---------------------------------------------------------------------------
struct CvtArgs { const void* src[24]; int dst[24]; int cnt[24]; };

__global__ __launch_bounds__(256) void k_cvt(CvtArgs a, float* __restrict__ prm,
                                             const unsigned* __restrict__ flag) {
    const bool isbf = (*flag != 0u);
    const int e = blockIdx.x;
    const void* s = a.src[e];
    float* d = prm + a.dst[e];
    const int n = a.cnt[e];
    for (int i = threadIdx.x; i < n; i += 256) d[i] = ldin(s, i, isbf);
}

// ===========================================================================
// Swizzled 64x64 transpose tile helpers.
// write elem (row, col): T[row][(((col>>3) ^ (row&7)) << 3) + (col&7)]
// read 8 elems (row, oct): *(short8*)&T[row][((oct ^ (row&7)) << 3)]
// ===========================================================================

// ---------------------------------------------------------------------------
// K_xt2: x [b][c][n] (fp32 or bf16) -> xT bf16 [b][n][c]. Vectorized loads.
// ---------------------------------------------------------------------------
__global__ __launch_bounds__(256) void k_xt2(const void* __restrict__ x,
                                             const unsigned* __restrict__ flag,
                                             bf16* __restrict__ xT) {
    __shared__ short T[64][72];
    const bool isbf = (*flag != 0u);
    const int b = blockIdx.z, c0 = blockIdx.y * 64, n0 = blockIdx.x * 64;
    const int tid = threadIdx.x;
    const int cc = tid >> 3, oct = tid & 7;
#pragma unroll
    for (int i = 0; i < 2; ++i) {
        int col = cc + i * 32;                 // c within tile
        long gbase = ((long)(b * 256 + c0 + col) << 12) + n0 + oct * 8;
        short v[8];
        if (isbf) {
            short8 p = *(const short8*)((const short*)x + gbase);
#pragma unroll
            for (int u = 0; u < 8; ++u) v[u] = p[u];
        } else {
            floatx4 q0 = *(const floatx4*)((const float*)x + gbase);
            floatx4 q1 = *(const floatx4*)((const float*)x + gbase + 4);
#pragma unroll
            for (int u = 0; u < 4; ++u) { v[u] = f2s(q0[u]); v[4 + u] = f2s(q1[u]); }
        }
        int row0 = oct * 8;                    // n within tile
#pragma unroll
        for (int u = 0; u < 8; ++u) {
            int row = row0 + u;
            T[row][(((col >> 3) ^ (row & 7)) << 3) + (col & 7)] = v[u];
        }
    }
    __syncthreads();
    const int rn = tid >> 3;
#pragma unroll
    for (int i = 0; i < 2; ++i) {
        int n = rn + i * 32;
        short8 p = *(const short8*)&T[n][((oct ^ (n & 7)) << 3)];
        *(short8*)&xT[(((b << 12) + n0 + n) << 8) + c0 + oct * 8] = p;
    }
}

// ---------------------------------------------------------------------------
// K_wt2: w [c][j] (256 x ncols) -> wT bf16 [j][c]. Vectorized loads.
// ---------------------------------------------------------------------------
__global__ __launch_bounds__(256) void k_wt2(const void* __restrict__ src,
                                             const unsigned* __restrict__ flag,
                                             bf16* __restrict__ dst, int ncols) {
    __shared__ short T[64][72];
    const bool isbf = (*flag != 0u);
    const int j0 = blockIdx.x * 64, c0 = blockIdx.y * 64;
    const int tid = threadIdx.x;
    const int cc = tid >> 3, oct = tid & 7;
#pragma unroll
    for (int i = 0; i < 2; ++i) {
        int col = cc + i * 32;                 // c within tile
        long gbase = (long)(c0 + col) * ncols + j0 + oct * 8;
        short v[8];
        if (isbf) {
            short8 p = *(const short8*)((const short*)src + gbase);
#pragma unroll
            for (int u = 0; u < 8; ++u) v[u] = p[u];
        } else {
            floatx4 q0 = *(const floatx4*)((const float*)src + gbase);
            floatx4 q1 = *(const floatx4*)((const float*)src + gbase + 4);
#pragma unroll
            for (int u = 0; u < 4; ++u) { v[u] = f2s(q0[u]); v[4 + u] = f2s(q1[u]); }
        }
        int row0 = oct * 8;                    // j within tile
#pragma unroll
        for (int u = 0; u < 8; ++u) {
            int row = row0 + u;
            T[row][(((col >> 3) ^ (row & 7)) << 3) + (col & 7)] = v[u];
        }
    }
    __syncthreads();
    const int rj = tid >> 3;
#pragma unroll
    for (int i = 0; i < 2; ++i) {
        int j = rj + i * 32;
        short8 p = *(const short8*)&T[j][((oct ^ (j & 7)) << 3)];
        *(short8*)&dst[((j0 + j) << 8) + c0 + oct * 8] = p;
    }
}

// ---------------------------------------------------------------------------
// K1: qkv GEMM (MFMA, vectorized staging).
// ---------------------------------------------------------------------------
__global__ __launch_bounds__(256) void k_qkv_m2(const bf16* __restrict__ xT,
                                                const bf16* __restrict__ wT,
                                                bf16* __restrict__ qb,
                                                bf16* __restrict__ kb,
                                                float* __restrict__ vb,
                                                float* __restrict__ qss,
                                                float* __restrict__ kss) {
    __shared__ short As[64][72];
    __shared__ short Bs[128][72];
    const int b = blockIdx.z, j0 = blockIdx.y * 64, n0 = blockIdx.x * 128;
    const int tid = threadIdx.x;
    const int wid = tid >> 6, l = tid & 63;
    const int lm = l & 15, lk = (l >> 4) * 8;
    const int srow = tid >> 3, soct = tid & 7;
    floatx4 acc[8];
#pragma unroll
    for (int i = 0; i < 8; ++i) acc[i] = (floatx4){0.f, 0.f, 0.f, 0.f};

    for (int k0 = 0; k0 < 256; k0 += 64) {
        __syncthreads();
#pragma unroll
        for (int i = 0; i < 2; ++i) {
            int j = srow + i * 32;
            *(short8*)&As[j][soct * 8] =
                *(const short8*)&wT[((j0 + j) << 8) + k0 + soct * 8];
        }
#pragma unroll
        for (int i = 0; i < 4; ++i) {
            int n = srow + i * 32;
            *(short8*)&Bs[n][soct * 8] =
                *(const short8*)&xT[(((b << 12) + n0 + n) << 8) + k0 + soct * 8];
        }
        __syncthreads();
#pragma unroll
        for (int h = 0; h < 2; ++h) {
            short8 af = *(const short8*)&As[wid * 16 + lm][h * 32 + lk];
#pragma unroll
            for (int nt = 0; nt < 8; ++nt) {
                short8 bfr = *(const short8*)&Bs[nt * 16 + lm][h * 32 + lk];
                acc[nt] = MFMA16(af, bfr, acc[nt]);
            }
        }
    }
    const int y = blockIdx.y;
    const int jloc = (y & 3) * 64 + wid * 16 + (l >> 4) * 4;
    float sq[4] = {0.f, 0.f, 0.f, 0.f};
    if (y < 4) {
#pragma unroll
        for (int nt = 0; nt < 8; ++nt) {
            int n = n0 + nt * 16 + lm;
#pragma unroll
            for (int r = 0; r < 4; ++r) {
                float vf = acc[nt][r];
                qb[(((b << 8) + jloc + r) << 12) + n] = f2b(vf);
                sq[r] = fmaf(vf, vf, sq[r]);
            }
        }
    } else if (y < 8) {
#pragma unroll
        for (int nt = 0; nt < 8; ++nt) {
            int n = n0 + nt * 16 + lm;
#pragma unroll
            for (int r = 0; r < 4; ++r) {
                float vf = acc[nt][r];
                kb[(((b << 8) + jloc + r) << 12) + n] = f2b(vf);
                sq[r] = fmaf(vf, vf, sq[r]);
            }
        }
    } else {
#pragma unroll
        for (int nt = 0; nt < 8; ++nt) {
            int n = n0 + nt * 16 + lm;
#pragma unroll
            for (int r = 0; r < 4; ++r)
                vb[(((b << 8) + jloc + r) << 12) + n] = acc[nt][r];
        }
    }
    if (y < 8) {
        __syncthreads();
        float* red = (float*)&As[0][0];
        const int rbase = wid * 16 + (l >> 4) * 4;
#pragma unroll
        for (int r = 0; r < 4; ++r) red[(rbase + r) * 16 + lm] = sq[r];
        __syncthreads();
        if (tid < 64) {
            float s = 0.f;
#pragma unroll
            for (int i = 0; i < 16; ++i) s += red[tid * 16 + i];
            float* dst = (y < 4) ? qss : kss;
            atomicAdd(&dst[(b << 8) + (y & 3) * 64 + tid], s);
        }
    }
}

// ---------------------------------------------------------------------------
// K3: QK^T partials (MFMA over n), 4 n-chunks of 1024 -> attn_part[chunk].
// ---------------------------------------------------------------------------
__global__ __launch_bounds__(256) void k_qk2p(const bf16* __restrict__ qb,
                                              const bf16* __restrict__ kb,
                                              float* __restrict__ attn_part) {
    __shared__ float AS[32][32];
    const int h = blockIdx.x, b = blockIdx.y, nc = blockIdx.z;
    const int tid = threadIdx.x;
    const int wid = tid >> 6, l = tid & 63;
    const int lm = l & 15, lk = (l >> 4) * 8;
    floatx4 acc[2][2];
#pragma unroll
    for (int i = 0; i < 2; ++i)
#pragma unroll
        for (int j = 0; j < 2; ++j) acc[i][j] = (floatx4){0.f, 0.f, 0.f, 0.f};
    const int cbase = (b << 8) + h * 32;
    for (int it = 0; it < 8; ++it) {
        int n = nc * 1024 + wid * 256 + it * 32 + lk;
        short8 a0 = *(const short8*)&qb[((cbase + lm) << 12) + n];
        short8 a1 = *(const short8*)&qb[((cbase + 16 + lm) << 12) + n];
        short8 b0 = *(const short8*)&kb[((cbase + lm) << 12) + n];
        short8 b1 = *(const short8*)&kb[((cbase + 16 + lm) << 12) + n];
        acc[0][0] = MFMA16(a0, b0, acc[0][0]);
        acc[0][1] = MFMA16(a0, b1, acc[0][1]);
        acc[1][0] = MFMA16(a1, b0, acc[1][0]);
        acc[1][1] = MFMA16(a1, b1, acc[1][1]);
    }
    for (int i = tid; i < 1024; i += 256) ((float*)AS)[i] = 0.f;
    __syncthreads();
#pragma unroll
    for (int mt = 0; mt < 2; ++mt)
#pragma unroll
        for (int nt = 0; nt < 2; ++nt)
#pragma unroll
            for (int r = 0; r < 4; ++r)
                atomicAdd(&AS[mt * 16 + (l >> 4) * 4 + r][nt * 16 + lm], acc[mt][nt][r]);
    __syncthreads();
    float* dst = attn_part + (((nc * 64) + (b * 8 + h)) << 10);
    for (int i = tid; i < 1024; i += 256) dst[i] = ((float*)AS)[i];
}

// ---------------------------------------------------------------------------
// K3b: sum 4 partials + l2 scales (rsqrt of raw sums) + temp + softmax.
// ---------------------------------------------------------------------------
__global__ __launch_bounds__(64) void k_softmax2(const float* __restrict__ attn_part,
                                                 const float* __restrict__ qss,
                                                 const float* __restrict__ kss,
                                                 const float* __restrict__ prm,
                                                 float* __restrict__ attn) {
    __shared__ float A[32][32];
    const int h = blockIdx.x, b = blockIdx.y;
    const int tid = threadIdx.x;
    const int page = (b * 8 + h) << 10;
    for (int i = tid; i < 1024; i += 64) {
        float s = attn_part[page + i] + attn_part[(64 << 10) + page + i] +
                  attn_part[(128 << 10) + page + i] + attn_part[(192 << 10) + page + i];
        ((float*)A)[i] = s;
    }
    __syncthreads();
    if (tid < 32) {
        const int c = tid;
        const int cbase = (b << 8) + h * 32;
        float qsc = rsqrtf(fmaxf(qss[cbase + c], 1e-12f)) * prm[P_TEMP + h];
        float row[32];
        float m = -1e30f;
#pragma unroll
        for (int d = 0; d < 32; ++d) {
            row[d] = A[c][d] * qsc * rsqrtf(fmaxf(kss[cbase + d], 1e-12f));
            m = fmaxf(m, row[d]);
        }
        float s = 0.f;
#pragma unroll
        for (int d = 0; d < 32; ++d) {
            row[d] = __expf(row[d] - m);
            s += row[d];
        }
        float inv = 1.0f / s;
        float* dst = attn + page + c * 32;
#pragma unroll
        for (int d = 0; d < 32; ++d) dst[d] = row[d] * inv;
    }
}

// ---------------------------------------------------------------------------
// K4: att = attn @ v; writes attT bf16 [b][n][c]; fused gap (sum) atomics.
// Two-stage parallel LDS reduce for gap (was: 1 wave x 256 serial reads).
// ---------------------------------------------------------------------------
__global__ __launch_bounds__(256) void k_attv2(const float* __restrict__ attn,
                                               const float* __restrict__ vb,
                                               bf16* __restrict__ attT,
                                               float* __restrict__ gap) {
    __shared__ float A[32][32];
    __shared__ float G[256][32];
    const int b = blockIdx.z, h = blockIdx.y;
    const int tid = threadIdx.x;
    const int n = blockIdx.x * 256 + tid;
    for (int i = tid; i < 1024; i += 256) ((float*)A)[i] = attn[((b * 8 + h) << 10) + i];
    __syncthreads();
    const int base = ((b * 256 + h * 32) << 12) + n;
    float vv[32];
#pragma unroll
    for (int d = 0; d < 32; ++d) vv[d] = vb[base + (d << 12)];
    float av[32];
#pragma unroll
    for (int c = 0; c < 32; ++c) {
        float s = 0.f;
#pragma unroll
        for (int d = 0; d < 32; ++d) s = fmaf(A[c][d], vv[d], s);
        av[c] = s;
        G[tid][c] = s;
    }
    const int obase = (((b << 12) + n) << 8) + h * 32;
#pragma unroll
    for (int g = 0; g < 4; ++g) {
        short8 p;
#pragma unroll
        for (int u = 0; u < 8; ++u) p[u] = f2s(av[g * 8 + u]);
        *(short8*)&attT[obase + g * 8] = p;
    }
    __syncthreads();
    // stage 1: thread t sums 32 rows of column (t&31)  (bank-conflict-free)
    {
        const int colc = tid & 31, rg = tid >> 5;   // 8 row-groups
        float s = 0.f;
#pragma unroll
        for (int i = 0; i < 32; ++i) s += G[rg * 32 + i][colc];
        A[rg][colc] = s;        // A reuse: rows 0..7
    }
    __syncthreads();
    if (tid < 32) {
        float s = 0.f;
#pragma unroll
        for (int g = 0; g < 8; ++g) s += A[g][tid];
        atomicAdd(&gap[(b << 8) + h * 32 + tid], s);
    }
}

// ---------------------------------------------------------------------------
// K5: depthwise 3x3 + bias + BN + GELU, LDS-staged, bf16 output [c][n].
// ---------------------------------------------------------------------------
__global__ __launch_bounds__(256) void k_dwconv2(const float* __restrict__ vb,
                                                 const float* __restrict__ prm,
                                                 bf16* __restrict__ convb) {
    __shared__ float S[18][66];
    const int b = blockIdx.z, c = blockIdx.y, y0 = blockIdx.x * 16;
    const int tid = threadIdx.x;
    const float* src = vb + (((b << 8) + c) << 12);
    for (int idx = tid; idx < 18 * 66; idx += 256) {
        int r = idx / 66, xcol = idx % 66;
        int gy = y0 + r - 1, gx = xcol - 1;
        float v = 0.f;
        if (gy >= 0 && gy < 64 && gx >= 0 && gx < 64) v = src[gy * 64 + gx];
        S[r][xcol] = v;
    }
    float w[9];
#pragma unroll
    for (int i = 0; i < 9; ++i) w[i] = prm[P_DWK + c * 9 + i];
    const float bias = prm[P_DWB + c];
    const float scale = rsqrtf(prm[P_DWV + c] + 1e-3f) * prm[P_DWG + c];
    const float shift = prm[P_DWBT + c] - prm[P_DWM + c] * scale;
    __syncthreads();
    const int row = tid >> 4, xq = (tid & 15) * 4;
    short4v o;
#pragma unroll
    for (int u = 0; u < 4; ++u) {
        int x = xq + u;
        float acc = bias;
#pragma unroll
        for (int ky = 0; ky < 3; ++ky)
#pragma unroll
            for (int kx = 0; kx < 3; ++kx)
                acc = fmaf(S[row + ky][x + kx], w[ky * 3 + kx], acc);
        acc = acc * scale + shift;
        o[u] = f2s(gelu_exact(acc));
    }
    *(short4v*)&convb[(((b << 8) + c) << 12) + (y0 + row) * 64 + xq] = o;
}

// ---------------------------------------------------------------------------
// K6: conv bf16 [c][n] -> convT bf16 [n][c] (swizzled-tile transpose).
// ---------------------------------------------------------------------------
__global__ __launch_bounds__(256) void k_tr2(const bf16* __restrict__ convb,
                                             bf16* __restrict__ convT) {
    __shared__ short T[64][72];
    const int b = blockIdx.z, c0 = blockIdx.y * 64, n0 = blockIdx.x * 64;
    const int tid = threadIdx.x;
    const int cc = tid >> 3, oct = tid & 7;
#pragma unroll
    for (int i = 0; i < 2; ++i) {
        int col = cc + i * 32;
        short8 p = *(const short8*)((const short*)convb +
                                    (((long)((b << 8) + c0 + col)) << 12) + n0 + oct * 8);
        int row0 = oct * 8;
#pragma unroll
        for (int u = 0; u < 8; ++u) {
            int row = row0 + u;
            T[row][(((col >> 3) ^ (row & 7)) << 3) + (col & 7)] = p[u];
        }
    }
    __syncthreads();
    const int rn = tid >> 3;
#pragma unroll
    for (int i = 0; i < 2; ++i) {
        int n = rn + i * 32;
        short8 p = *(const short8*)&T[n][((oct ^ (n & 7)) << 3)];
        *(short8*)&convT[(((b << 12) + n0 + n) << 8) + c0 + oct * 8] = p;
    }
}

// ---------------------------------------------------------------------------
// K7: channel gate (gap holds SUMS; scale by 1/4096 here).
// ---------------------------------------------------------------------------
__global__ __launch_bounds__(256) void k_cm(const float* __restrict__ gap,
                                            const float* __restrict__ prm,
                                            float* __restrict__ sigcm) {
    const int b = blockIdx.x;
    const int tid = threadIdx.x;
    __shared__ float gl[256];
    __shared__ float t1[32];
    gl[tid] = gap[(b << 8) + tid] * (1.0f / 4096.0f);
    __syncthreads();
    if (tid < 32) {
        float s = prm[P_CIB1 + tid];
        for (int c = 0; c < 256; ++c) s = fmaf(gl[c], prm[P_CIW1 + c * 32 + tid], s);
        s = (s - prm[P_CIM + tid]) * rsqrtf(prm[P_CIV + tid] + 1e-3f) * prm[P_CIG + tid] + prm[P_CIBT + tid];
        t1[tid] = gelu_exact(s);
    }
    __syncthreads();
    float s = prm[P_CIB2 + tid];
#pragma unroll
    for (int o = 0; o < 32; ++o) s = fmaf(t1[o], prm[P_CIW2 + o * 256 + tid], s);
    sigcm[(b << 8) + tid] = sigmoidf_(s);
}

// ---------------------------------------------------------------------------
// K8: spatial gate from convT (vectorized row reads).
// ---------------------------------------------------------------------------
__global__ __launch_bounds__(256) void k_sm2(const bf16* __restrict__ convT,
                                             const float* __restrict__ prm,
                                             float* __restrict__ sigsm) {
    __shared__ float W1[256][16];
    const int b = blockIdx.y;
    const int tid = threadIdx.x;
    const int n = blockIdx.x * 256 + tid;
    for (int i = tid; i < 4096; i += 256) W1[i >> 4][i & 15] = prm[P_SIW1 + i];
    __syncthreads();
    float acc[16];
#pragma unroll
    for (int o = 0; o < 16; ++o) acc[o] = 0.f;
    const bf16* src = convT + (((b << 12) + n) << 8);
#pragma unroll 4
    for (int g = 0; g < 32; ++g) {
        short8 p = *(const short8*)&src[g * 8];
#pragma unroll
        for (int u = 0; u < 8; ++u) {
            float v = s2f(p[u]);
            int c = g * 8 + u;
#pragma unroll
            for (int o = 0; o < 16; ++o) acc[o] = fmaf(v, W1[c][o], acc[o]);
        }
    }
    float sm = prm[P_SIB2];
#pragma unroll
    for (int o = 0; o < 16; ++o) {
        float t = acc[o] + prm[P_SIB1 + o];
        t = (t - prm[P_SIM + o]) * rsqrtf(prm[P_SIV + o] + 1e-3f) * prm[P_SIG + o] + prm[P_SIBT + o];
        sm = fmaf(gelu_exact(t), prm[P_SIW2 + o], sm);
    }
    sigsm[(b << 12) + n] = sigmoidf_(sm);
}

// ---------------------------------------------------------------------------
// K9: final projection (MFMA, vectorized staging of gated Z).
// ---------------------------------------------------------------------------
__global__ __launch_bounds__(256) void k_proj_m2(const bf16* __restrict__ attT,
                                                 const bf16* __restrict__ convT,
                                                 const float* __restrict__ sigsm,
                                                 const float* __restrict__ sigcm,
                                                 const bf16* __restrict__ wpT,
                                                 const float* __restrict__ prm,
                                                 const unsigned* __restrict__ flag,
                                                 void* __restrict__ out) {
    __shared__ short As[64][72];
    __shared__ short Bs[128][72];
    __shared__ float scs[256];
    const bool isbf = (*flag != 0u);
    const int b = blockIdx.z, j0 = blockIdx.y * 64, n0 = blockIdx.x * 128;
    const int tid = threadIdx.x;
    const int wid = tid >> 6, l = tid & 63;
    const int lm = l & 15, lk = (l >> 4) * 8;
    const int srow = tid >> 3, soct = tid & 7;
    scs[tid] = sigcm[(b << 8) + tid];
    floatx4 acc[8];
#pragma unroll
    for (int i = 0; i < 8; ++i) acc[i] = (floatx4){0.f, 0.f, 0.f, 0.f};

    for (int k0 = 0; k0 < 256; k0 += 64) {
        __syncthreads();
#pragma unroll
        for (int i = 0; i < 2; ++i) {
            int j = srow + i * 32;
            *(short8*)&As[j][soct * 8] =
                *(const short8*)&wpT[((j0 + j) << 8) + k0 + soct * 8];
        }
#pragma unroll
        for (int i = 0; i < 4; ++i) {
            int n = srow + i * 32;
            int rbase = (((b << 12) + n0 + n) << 8) + k0 + soct * 8;
            short8 pa = *(const short8*)&attT[rbase];
            short8 pc = *(const short8*)&convT[rbase];
            float sv = sigsm[(b << 12) + n0 + n];
            short8 pz;
#pragma unroll
            for (int u = 0; u < 8; ++u)
                pz[u] = f2s(s2f(pa[u]) * sv + s2f(pc[u]) * scs[k0 + soct * 8 + u]);
            *(short8*)&Bs[n][soct * 8] = pz;
        }
        __syncthreads();
#pragma unroll
        for (int h = 0; h < 2; ++h) {
            short8 af = *(const short8*)&As[wid * 16 + lm][h * 32 + lk];
#pragma unroll
            for (int nt = 0; nt < 8; ++nt) {
                short8 bfr = *(const short8*)&Bs[nt * 16 + lm][h * 32 + lk];
                acc[nt] = MFMA16(af, bfr, acc[nt]);
            }
        }
    }
    const int jb = j0 + wid * 16 + (l >> 4) * 4;
    float bp[4];
#pragma unroll
    for (int r = 0; r < 4; ++r) bp[r] = prm[P_BPROJ + jb + r];
#pragma unroll
    for (int nt = 0; nt < 8; ++nt) {
        int n = n0 + nt * 16 + lm;
#pragma unroll
        for (int r = 0; r < 4; ++r) {
            int idx = (((b << 8) + jb + r) << 12) + n;
            float val = acc[nt][r] + bp[r];
            if (isbf) ((bf16*)out)[idx] = f2b(val);
            else ((float*)out)[idx] = val;
        }
    }
}

// ---------------------------------------------------------------------------
extern "C" void kernel_launch(void* const* d_in, const int* in_sizes, int n_in,
                              void* d_out, int out_size, void* d_ws, size_t ws_size,
                              hipStream_t stream) {
    char* ws = (char*)d_ws;
    float* vb     = (float*)(ws);
    bf16*  xT     = (bf16*) (ws + 33554432);
    bf16*  attT   = (bf16*) (ws + 33554432);
    bf16*  qb     = (bf16*) (ws + 50331648);
    bf16*  convb  = (bf16*) (ws + 50331648);
    bf16*  kb     = (bf16*) (ws + 67108864);
    bf16*  convT  = (bf16*) (ws + 67108864);
    bf16*  wqkvT  = (bf16*) (ws + 83886080);
    bf16*  wprojT = (bf16*) (ws + 84279296);
    float* attn   = (float*)(ws + 84410368);
    float* attn_p = (float*)(ws + 84672512);
    float* qss    = (float*)(ws + 85721088);   // qss|kss|gap contiguous 24576B
    float* kss    = (float*)(ws + 85729280);
    float* gap    = (float*)(ws + 85737472);
    float* sigcm  = (float*)(ws + 85745664);
    float* sigsm  = (float*)(ws + 85753856);
    float* prm    = (float*)(ws + 85884928);
    unsigned* flag = (unsigned*)(ws + 85985280);

    // k_sniff also zeros qss|kss|gap (replaces the 40us-in-graph memset node)
    k_sniff<<<1, 256, 0, stream>>>((const unsigned*)d_in[0], flag, qss);

    CvtArgs a;
    const int map_src[24] = {3, 4, 5, 6, 7, 8, 9, 10, 11, 12, 13, 14, 15, 16, 17,
                             18, 19, 20, 21, 22, 23, 24, 25, 26};
    const int map_dst[24] = {P_BPROJ, P_DWK, P_DWB, P_DWG, P_DWBT, P_DWM, P_DWV,
                             P_CIG, P_CIBT, P_CIM, P_CIV, P_SIG, P_SIBT, P_SIM, P_SIV,
                             P_CIW1, P_CIB1, P_CIW2, P_CIB2, P_SIW1, P_SIB1, P_SIW2,
                             P_SIB2, P_TEMP};
    for (int i = 0; i < 24; ++i) {
        a.src[i] = d_in[map_src[i]];
        a.dst[i] = map_dst[i];
        a.cnt[i] = in_sizes[map_src[i]];
    }
    k_cvt<<<24, 256, 0, stream>>>(a, prm, flag);

    k_xt2<<<dim3(64, 4, 8), 256, 0, stream>>>(d_in[0], flag, xT);
    k_wt2<<<dim3(12, 4), 256, 0, stream>>>(d_in[1], flag, wqkvT, 768);
    k_wt2<<<dim3(4, 4), 256, 0, stream>>>(d_in[2], flag, wprojT, 256);

    k_qkv_m2<<<dim3(32, 12, 8), 256, 0, stream>>>(xT, wqkvT, qb, kb, vb, qss, kss);
    k_qk2p<<<dim3(8, 8, 4), 256, 0, stream>>>(qb, kb, attn_p);
    k_softmax2<<<dim3(8, 8), 64, 0, stream>>>(attn_p, qss, kss, prm, attn);
    k_attv2<<<dim3(16, 8, 8), 256, 0, stream>>>(attn, vb, attT, gap);
    k_dwconv2<<<dim3(4, 256, 8), 256, 0, stream>>>(vb, prm, convb);
    k_tr2<<<dim3(64, 4, 8), 256, 0, stream>>>(convb, convT);
    k_cm<<<8, 256, 0, stream>>>(gap, prm, sigcm);
    k_sm2<<<dim3(16, 8), 256, 0, stream>>>(convT, prm, sigsm);
    k_proj_m2<<<dim3(32, 4, 8), 256, 0, stream>>>(attT, convT, sigsm, sigcm,
                                                  wprojT, prm, flag, d_out);
}

// Round 8
// 167.706 us; speedup vs baseline: 2.9795x; 1.0420x over previous
//
#include <hip/hip_runtime.h>
#include <hip/hip_bf16.h>
#include <math.h>

typedef __hip_bfloat16 bf16;
typedef __attribute__((ext_vector_type(8))) short short8;
typedef __attribute__((ext_vector_type(4))) short short4v;
typedef __attribute__((ext_vector_type(4))) float floatx4;

__device__ __forceinline__ bf16 f2b(float v) { return __float2bfloat16(v); }
__device__ __forceinline__ short f2s(float v) {
    bf16 h = __float2bfloat16(v);
    return *reinterpret_cast<short*>(&h);
}
__device__ __forceinline__ float s2f(short s) {
    union { unsigned u; float f; } t;
    t.u = ((unsigned)(unsigned short)s) << 16;
    return t.f;
}
__device__ __forceinline__ float gelu_exact(float x) {
    return 0.5f * x * (1.0f + erff(x * 0.70710678118654752440f));
}
__device__ __forceinline__ float sigmoidf_(float x) {
    return 1.0f / (1.0f + __expf(-x));
}
__device__ __forceinline__ float ldin(const void* p, int i, bool isbf) {
    return isbf ? s2f(((const short*)p)[i]) : ((const float*)p)[i];
}
#define MFMA16(a, b, c) __builtin_amdgcn_mfma_f32_16x16x32_bf16(a, b, c, 0, 0, 0)

// fp32 params block layout (offsets in floats)
#define P_DWK    0
#define P_DWB    2304
#define P_DWG    2560
#define P_DWBT   2816
#define P_DWM    3072
#define P_DWV    3328
#define P_CIW1   3584
#define P_CIB1   11776
#define P_CIG    11808
#define P_CIBT   11840
#define P_CIM    11872
#define P_CIV    11904
#define P_CIW2   11936
#define P_CIB2   20128
#define P_SIW1   20384
#define P_SIB1   24480
#define P_SIG    24496
#define P_SIBT   24512
#define P_SIM    24528
#define P_SIV    24544
#define P_SIW2   24560
#define P_SIB2   24576
#define P_TEMP   24577
#define P_BPROJ  24585

// ---------------------------------------------------------------------------
// K0: dtype sniffer + zero the atomic accumulators (qss|kss|gap, 6144 floats).
// ---------------------------------------------------------------------------
__global__ __launch_bounds__(256) void k_sniff(const unsigned* __restrict__ x,
                                               unsigned* __restrict__ flag,
                                               float* __restrict__ accbuf) {
    for (int i = threadIdx.x; i < 6144; i += 256) accbuf[i] = 0.f;
    int cnt = 0;
    for (int i = threadIdx.x; i < 4096; i += 256) {
        unsigned lo = x[i] & 0xFFFFu;
        unsigned e = (lo >> 7) & 0xFFu;
        cnt += (e >= 0x66u && e <= 0x8Au) ? 1 : 0;
    }
    __shared__ int red[256];
    red[threadIdx.x] = cnt;
    __syncthreads();
    for (int o = 128; o > 0; o >>= 1) {
        if (threadIdx.x < o) red[threadIdx.x] += red[threadIdx.x + o];
        __syncthreads();
    }
    if (threadIdx.x == 0) *flag = (red[0] > 2048) ? 1u : 0u;
}

// ---------------------------------------------------------------------------
// K0b: convert all small params to fp32 block.
// ---------------------------------------------------------------------------
struct CvtArgs { const void* src[24]; int dst[24]; int cnt[24]; };

__global__ __launch_bounds__(256) void k_cvt(CvtArgs a, float* __restrict__ prm,
                                             const unsigned* __restrict__ flag) {
    const bool isbf = (*flag != 0u);
    const int e = blockIdx.x;
    const void* s = a.src[e];
    float* d = prm + a.dst[e];
    const int n = a.cnt[e];
    for (int i = threadIdx.x; i < n; i += 256) d[i] = ldin(s, i, isbf);
}

// ===========================================================================
// Swizzled 64x64 transpose tile helpers.
// write elem (row, col): T[row][(((col>>3) ^ (row&7)) << 3) + (col&7)]
// read 8 elems (row, oct): *(short8*)&T[row][((oct ^ (row&7)) << 3)]
// ===========================================================================

// ---------------------------------------------------------------------------
// K_xt2: x [b][c][n] (fp32 or bf16) -> xT bf16 [b][n][c]. Vectorized loads.
// ---------------------------------------------------------------------------
__global__ __launch_bounds__(256) void k_xt2(const void* __restrict__ x,
                                             const unsigned* __restrict__ flag,
                                             bf16* __restrict__ xT) {
    __shared__ short T[64][72];
    const bool isbf = (*flag != 0u);
    const int b = blockIdx.z, c0 = blockIdx.y * 64, n0 = blockIdx.x * 64;
    const int tid = threadIdx.x;
    const int cc = tid >> 3, oct = tid & 7;
#pragma unroll
    for (int i = 0; i < 2; ++i) {
        int col = cc + i * 32;                 // c within tile
        long gbase = ((long)(b * 256 + c0 + col) << 12) + n0 + oct * 8;
        short v[8];
        if (isbf) {
            short8 p = *(const short8*)((const short*)x + gbase);
#pragma unroll
            for (int u = 0; u < 8; ++u) v[u] = p[u];
        } else {
            floatx4 q0 = *(const floatx4*)((const float*)x + gbase);
            floatx4 q1 = *(const floatx4*)((const float*)x + gbase + 4);
#pragma unroll
            for (int u = 0; u < 4; ++u) { v[u] = f2s(q0[u]); v[4 + u] = f2s(q1[u]); }
        }
        int row0 = oct * 8;                    // n within tile
#pragma unroll
        for (int u = 0; u < 8; ++u) {
            int row = row0 + u;
            T[row][(((col >> 3) ^ (row & 7)) << 3) + (col & 7)] = v[u];
        }
    }
    __syncthreads();
    const int rn = tid >> 3;
#pragma unroll
    for (int i = 0; i < 2; ++i) {
        int n = rn + i * 32;
        short8 p = *(const short8*)&T[n][((oct ^ (n & 7)) << 3)];
        *(short8*)&xT[(((b << 12) + n0 + n) << 8) + c0 + oct * 8] = p;
    }
}

// ---------------------------------------------------------------------------
// K_wt2: w [c][j] (256 x ncols) -> wT bf16 [j][c]. Vectorized loads.
// ---------------------------------------------------------------------------
__global__ __launch_bounds__(256) void k_wt2(const void* __restrict__ src,
                                             const unsigned* __restrict__ flag,
                                             bf16* __restrict__ dst, int ncols) {
    __shared__ short T[64][72];
    const bool isbf = (*flag != 0u);
    const int j0 = blockIdx.x * 64, c0 = blockIdx.y * 64;
    const int tid = threadIdx.x;
    const int cc = tid >> 3, oct = tid & 7;
#pragma unroll
    for (int i = 0; i < 2; ++i) {
        int col = cc + i * 32;                 // c within tile
        long gbase = (long)(c0 + col) * ncols + j0 + oct * 8;
        short v[8];
        if (isbf) {
            short8 p = *(const short8*)((const short*)src + gbase);
#pragma unroll
            for (int u = 0; u < 8; ++u) v[u] = p[u];
        } else {
            floatx4 q0 = *(const floatx4*)((const float*)src + gbase);
            floatx4 q1 = *(const floatx4*)((const float*)src + gbase + 4);
#pragma unroll
            for (int u = 0; u < 4; ++u) { v[u] = f2s(q0[u]); v[4 + u] = f2s(q1[u]); }
        }
        int row0 = oct * 8;                    // j within tile
#pragma unroll
        for (int u = 0; u < 8; ++u) {
            int row = row0 + u;
            T[row][(((col >> 3) ^ (row & 7)) << 3) + (col & 7)] = v[u];
        }
    }
    __syncthreads();
    const int rj = tid >> 3;
#pragma unroll
    for (int i = 0; i < 2; ++i) {
        int j = rj + i * 32;
        short8 p = *(const short8*)&T[j][((oct ^ (j & 7)) << 3)];
        *(short8*)&dst[((j0 + j) << 8) + c0 + oct * 8] = p;
    }
}

// ---------------------------------------------------------------------------
// K1: qkv GEMM (MFMA). 1D grid 3072 with XCD-chunk swizzle: each XCD owns one
// batch b; j varies fastest so 12 j-tiles reuse the same xT slice in L2.
// v output now bf16.
// ---------------------------------------------------------------------------
__global__ __launch_bounds__(256) void k_qkv_m2(const bf16* __restrict__ xT,
                                                const bf16* __restrict__ wT,
                                                bf16* __restrict__ qb,
                                                bf16* __restrict__ kb,
                                                bf16* __restrict__ vbb,
                                                float* __restrict__ qss,
                                                float* __restrict__ kss) {
    __shared__ short As[64][72];
    __shared__ short Bs[128][72];
    const int id = blockIdx.x;                 // 3072 = 8 XCD * 384
    const int swz = (id & 7) * 384 + (id >> 3);
    const int y = swz % 12;
    const int rest = swz / 12;                 // 0..255
    const int n0 = (rest & 31) * 128;
    const int b = rest >> 5;
    const int j0 = y * 64;
    const int tid = threadIdx.x;
    const int wid = tid >> 6, l = tid & 63;
    const int lm = l & 15, lk = (l >> 4) * 8;
    const int srow = tid >> 3, soct = tid & 7;
    floatx4 acc[8];
#pragma unroll
    for (int i = 0; i < 8; ++i) acc[i] = (floatx4){0.f, 0.f, 0.f, 0.f};

    for (int k0 = 0; k0 < 256; k0 += 64) {
        __syncthreads();
#pragma unroll
        for (int i = 0; i < 2; ++i) {
            int j = srow + i * 32;
            *(short8*)&As[j][soct * 8] =
                *(const short8*)&wT[((j0 + j) << 8) + k0 + soct * 8];
        }
#pragma unroll
        for (int i = 0; i < 4; ++i) {
            int n = srow + i * 32;
            *(short8*)&Bs[n][soct * 8] =
                *(const short8*)&xT[(((b << 12) + n0 + n) << 8) + k0 + soct * 8];
        }
        __syncthreads();
#pragma unroll
        for (int h = 0; h < 2; ++h) {
            short8 af = *(const short8*)&As[wid * 16 + lm][h * 32 + lk];
#pragma unroll
            for (int nt = 0; nt < 8; ++nt) {
                short8 bfr = *(const short8*)&Bs[nt * 16 + lm][h * 32 + lk];
                acc[nt] = MFMA16(af, bfr, acc[nt]);
            }
        }
    }
    const int jloc = (y & 3) * 64 + wid * 16 + (l >> 4) * 4;
    float sq[4] = {0.f, 0.f, 0.f, 0.f};
    if (y < 4) {
#pragma unroll
        for (int nt = 0; nt < 8; ++nt) {
            int n = n0 + nt * 16 + lm;
#pragma unroll
            for (int r = 0; r < 4; ++r) {
                float vf = acc[nt][r];
                qb[(((b << 8) + jloc + r) << 12) + n] = f2b(vf);
                sq[r] = fmaf(vf, vf, sq[r]);
            }
        }
    } else if (y < 8) {
#pragma unroll
        for (int nt = 0; nt < 8; ++nt) {
            int n = n0 + nt * 16 + lm;
#pragma unroll
            for (int r = 0; r < 4; ++r) {
                float vf = acc[nt][r];
                kb[(((b << 8) + jloc + r) << 12) + n] = f2b(vf);
                sq[r] = fmaf(vf, vf, sq[r]);
            }
        }
    } else {
#pragma unroll
        for (int nt = 0; nt < 8; ++nt) {
            int n = n0 + nt * 16 + lm;
#pragma unroll
            for (int r = 0; r < 4; ++r)
                vbb[(((b << 8) + jloc + r) << 12) + n] = f2b(acc[nt][r]);
        }
    }
    if (y < 8) {
        __syncthreads();
        float* red = (float*)&As[0][0];
        const int rbase = wid * 16 + (l >> 4) * 4;
#pragma unroll
        for (int r = 0; r < 4; ++r) red[(rbase + r) * 16 + lm] = sq[r];
        __syncthreads();
        if (tid < 64) {
            float s = 0.f;
#pragma unroll
            for (int i = 0; i < 16; ++i) s += red[tid * 16 + i];
            float* dst = (y < 4) ? qss : kss;
            atomicAdd(&dst[(b << 8) + (y & 3) * 64 + tid], s);
        }
    }
}

// ---------------------------------------------------------------------------
// K3: QK^T partials (MFMA over n), 4 n-chunks of 1024 -> attn_part[chunk].
// ---------------------------------------------------------------------------
__global__ __launch_bounds__(256) void k_qk2p(const bf16* __restrict__ qb,
                                              const bf16* __restrict__ kb,
                                              float* __restrict__ attn_part) {
    __shared__ float AS[32][32];
    const int h = blockIdx.x, b = blockIdx.y, nc = blockIdx.z;
    const int tid = threadIdx.x;
    const int wid = tid >> 6, l = tid & 63;
    const int lm = l & 15, lk = (l >> 4) * 8;
    floatx4 acc[2][2];
#pragma unroll
    for (int i = 0; i < 2; ++i)
#pragma unroll
        for (int j = 0; j < 2; ++j) acc[i][j] = (floatx4){0.f, 0.f, 0.f, 0.f};
    const int cbase = (b << 8) + h * 32;
    for (int it = 0; it < 8; ++it) {
        int n = nc * 1024 + wid * 256 + it * 32 + lk;
        short8 a0 = *(const short8*)&qb[((cbase + lm) << 12) + n];
        short8 a1 = *(const short8*)&qb[((cbase + 16 + lm) << 12) + n];
        short8 b0 = *(const short8*)&kb[((cbase + lm) << 12) + n];
        short8 b1 = *(const short8*)&kb[((cbase + 16 + lm) << 12) + n];
        acc[0][0] = MFMA16(a0, b0, acc[0][0]);
        acc[0][1] = MFMA16(a0, b1, acc[0][1]);
        acc[1][0] = MFMA16(a1, b0, acc[1][0]);
        acc[1][1] = MFMA16(a1, b1, acc[1][1]);
    }
    for (int i = tid; i < 1024; i += 256) ((float*)AS)[i] = 0.f;
    __syncthreads();
#pragma unroll
    for (int mt = 0; mt < 2; ++mt)
#pragma unroll
        for (int nt = 0; nt < 2; ++nt)
#pragma unroll
            for (int r = 0; r < 4; ++r)
                atomicAdd(&AS[mt * 16 + (l >> 4) * 4 + r][nt * 16 + lm], acc[mt][nt][r]);
    __syncthreads();
    float* dst = attn_part + (((nc * 64) + (b * 8 + h)) << 10);
    for (int i = tid; i < 1024; i += 256) dst[i] = ((float*)AS)[i];
}

// ---------------------------------------------------------------------------
// K3b: sum 4 partials + l2 scales (rsqrt of raw sums) + temp + softmax.
// ---------------------------------------------------------------------------
__global__ __launch_bounds__(64) void k_softmax2(const float* __restrict__ attn_part,
                                                 const float* __restrict__ qss,
                                                 const float* __restrict__ kss,
                                                 const float* __restrict__ prm,
                                                 float* __restrict__ attn) {
    __shared__ float A[32][32];
    const int h = blockIdx.x, b = blockIdx.y;
    const int tid = threadIdx.x;
    const int page = (b * 8 + h) << 10;
    for (int i = tid; i < 1024; i += 64) {
        float s = attn_part[page + i] + attn_part[(64 << 10) + page + i] +
                  attn_part[(128 << 10) + page + i] + attn_part[(192 << 10) + page + i];
        ((float*)A)[i] = s;
    }
    __syncthreads();
    if (tid < 32) {
        const int c = tid;
        const int cbase = (b << 8) + h * 32;
        float qsc = rsqrtf(fmaxf(qss[cbase + c], 1e-12f)) * prm[P_TEMP + h];
        float row[32];
        float m = -1e30f;
#pragma unroll
        for (int d = 0; d < 32; ++d) {
            row[d] = A[c][d] * qsc * rsqrtf(fmaxf(kss[cbase + d], 1e-12f));
            m = fmaxf(m, row[d]);
        }
        float s = 0.f;
#pragma unroll
        for (int d = 0; d < 32; ++d) {
            row[d] = __expf(row[d] - m);
            s += row[d];
        }
        float inv = 1.0f / s;
        float* dst = attn + page + c * 32;
#pragma unroll
        for (int d = 0; d < 32; ++d) dst[d] = row[d] * inv;
    }
}

// ---------------------------------------------------------------------------
// K4: att = attn @ v (bf16); writes attT bf16 [b][n][c]; fused gap atomics.
// ---------------------------------------------------------------------------
__global__ __launch_bounds__(256) void k_attv2(const float* __restrict__ attn,
                                               const bf16* __restrict__ vbb,
                                               bf16* __restrict__ attT,
                                               float* __restrict__ gap) {
    __shared__ float A[32][32];
    __shared__ float G[256][32];
    const int b = blockIdx.z, h = blockIdx.y;
    const int tid = threadIdx.x;
    const int n = blockIdx.x * 256 + tid;
    for (int i = tid; i < 1024; i += 256) ((float*)A)[i] = attn[((b * 8 + h) << 10) + i];
    __syncthreads();
    const int base = ((b * 256 + h * 32) << 12) + n;
    float vv[32];
#pragma unroll
    for (int d = 0; d < 32; ++d) vv[d] = s2f(((const short*)vbb)[base + (d << 12)]);
    float av[32];
#pragma unroll
    for (int c = 0; c < 32; ++c) {
        float s = 0.f;
#pragma unroll
        for (int d = 0; d < 32; ++d) s = fmaf(A[c][d], vv[d], s);
        av[c] = s;
        G[tid][c] = s;
    }
    const int obase = (((b << 12) + n) << 8) + h * 32;
#pragma unroll
    for (int g = 0; g < 4; ++g) {
        short8 p;
#pragma unroll
        for (int u = 0; u < 8; ++u) p[u] = f2s(av[g * 8 + u]);
        *(short8*)&attT[obase + g * 8] = p;
    }
    __syncthreads();
    {
        const int colc = tid & 31, rg = tid >> 5;
        float s = 0.f;
#pragma unroll
        for (int i = 0; i < 32; ++i) s += G[rg * 32 + i][colc];
        A[rg][colc] = s;
    }
    __syncthreads();
    if (tid < 32) {
        float s = 0.f;
#pragma unroll
        for (int g = 0; g < 8; ++g) s += A[g][tid];
        atomicAdd(&gap[(b << 8) + h * 32 + tid], s);
    }
}

// ---------------------------------------------------------------------------
// K5: fused depthwise 3x3 + bias + BN + GELU + transpose.
// Block = (16-row tile, 8-channel group, batch); writes convT[n][c0..c0+7]
// directly as short8 (replaces k_dwconv2 + k_tr2). BN scale folded into w.
// ---------------------------------------------------------------------------
__global__ __launch_bounds__(256) void k_dwconv3(const bf16* __restrict__ vbb,
                                                 const float* __restrict__ prm,
                                                 bf16* __restrict__ convT) {
    __shared__ float S[8][18][66];   // 38016 B
    __shared__ float Wl[8][11];      // 9 scaled w, (unused), shift
    const int b = blockIdx.z, c0 = blockIdx.y * 8, y0 = blockIdx.x * 16;
    const int tid = threadIdx.x;
    if (tid < 144) {
        int ch = tid / 18, r = tid - ch * 18;
        int gy = y0 + r - 1;
        float* drow = &S[ch][r][0];
        if (gy < 0 || gy > 63) {
            for (int i = 0; i < 66; ++i) drow[i] = 0.f;
        } else {
            const short* src = (const short*)vbb + ((((b << 8) + c0 + ch) << 12) + gy * 64);
            drow[0] = 0.f;
            drow[65] = 0.f;
#pragma unroll
            for (int g = 0; g < 8; ++g) {
                short8 p = *(const short8*)(src + g * 8);
#pragma unroll
                for (int u = 0; u < 8; ++u) drow[1 + g * 8 + u] = s2f(p[u]);
            }
        }
    } else if (tid >= 248) {
        int ch = tid - 248;                    // 0..7
        int c = c0 + ch;
        float scale = rsqrtf(prm[P_DWV + c] + 1e-3f) * prm[P_DWG + c];
#pragma unroll
        for (int e = 0; e < 9; ++e) Wl[ch][e] = prm[P_DWK + c * 9 + e] * scale;
        Wl[ch][10] = (prm[P_DWB + c] - prm[P_DWM + c]) * scale + prm[P_DWBT + c];
    }
    __syncthreads();
    const int row = tid >> 4, xl = tid & 15;
#pragma unroll
    for (int u = 0; u < 4; ++u) {
        int x = xl + u * 16;
        short8 o;
#pragma unroll
        for (int ch = 0; ch < 8; ++ch) {
            float acc = Wl[ch][10];
#pragma unroll
            for (int ky = 0; ky < 3; ++ky)
#pragma unroll
                for (int kx = 0; kx < 3; ++kx)
                    acc = fmaf(S[ch][row + ky][x + kx], Wl[ch][ky * 3 + kx], acc);
            o[ch] = f2s(gelu_exact(acc));
        }
        *(short8*)&((short*)convT)[(((b << 12) + (y0 + row) * 64 + x) << 8) + c0] = o;
    }
}

// ---------------------------------------------------------------------------
// K7: channel gate (gap holds SUMS; scale by 1/4096 here).
// ---------------------------------------------------------------------------
__global__ __launch_bounds__(256) void k_cm(const float* __restrict__ gap,
                                            const float* __restrict__ prm,
                                            float* __restrict__ sigcm) {
    const int b = blockIdx.x;
    const int tid = threadIdx.x;
    __shared__ float gl[256];
    __shared__ float t1[32];
    gl[tid] = gap[(b << 8) + tid] * (1.0f / 4096.0f);
    __syncthreads();
    if (tid < 32) {
        float s = prm[P_CIB1 + tid];
        for (int c = 0; c < 256; ++c) s = fmaf(gl[c], prm[P_CIW1 + c * 32 + tid], s);
        s = (s - prm[P_CIM + tid]) * rsqrtf(prm[P_CIV + tid] + 1e-3f) * prm[P_CIG + tid] + prm[P_CIBT + tid];
        t1[tid] = gelu_exact(s);
    }
    __syncthreads();
    float s = prm[P_CIB2 + tid];
#pragma unroll
    for (int o = 0; o < 32; ++o) s = fmaf(t1[o], prm[P_CIW2 + o * 256 + tid], s);
    sigcm[(b << 8) + tid] = sigmoidf_(s);
}

// ---------------------------------------------------------------------------
// K8: spatial gate from convT (vectorized row reads).
// ---------------------------------------------------------------------------
__global__ __launch_bounds__(256) void k_sm2(const bf16* __restrict__ convT,
                                             const float* __restrict__ prm,
                                             float* __restrict__ sigsm) {
    __shared__ float W1[256][16];
    const int b = blockIdx.y;
    const int tid = threadIdx.x;
    const int n = blockIdx.x * 256 + tid;
    for (int i = tid; i < 4096; i += 256) W1[i >> 4][i & 15] = prm[P_SIW1 + i];
    __syncthreads();
    float acc[16];
#pragma unroll
    for (int o = 0; o < 16; ++o) acc[o] = 0.f;
    const bf16* src = convT + (((b << 12) + n) << 8);
#pragma unroll 4
    for (int g = 0; g < 32; ++g) {
        short8 p = *(const short8*)&src[g * 8];
#pragma unroll
        for (int u = 0; u < 8; ++u) {
            float v = s2f(p[u]);
            int c = g * 8 + u;
#pragma unroll
            for (int o = 0; o < 16; ++o) acc[o] = fmaf(v, W1[c][o], acc[o]);
        }
    }
    float sm = prm[P_SIB2];
#pragma unroll
    for (int o = 0; o < 16; ++o) {
        float t = acc[o] + prm[P_SIB1 + o];
        t = (t - prm[P_SIM + o]) * rsqrtf(prm[P_SIV + o] + 1e-3f) * prm[P_SIG + o] + prm[P_SIBT + o];
        sm = fmaf(gelu_exact(t), prm[P_SIW2 + o], sm);
    }
    sigsm[(b << 12) + n] = sigmoidf_(sm);
}

// ---------------------------------------------------------------------------
// K9: final projection (MFMA). 1D grid 1024 with XCD-chunk swizzle (b per XCD,
// j fastest for attT/convT L2 reuse).
// ---------------------------------------------------------------------------
__global__ __launch_bounds__(256) void k_proj_m2(const bf16* __restrict__ attT,
                                                 const bf16* __restrict__ convT,
                                                 const float* __restrict__ sigsm,
                                                 const float* __restrict__ sigcm,
                                                 const bf16* __restrict__ wpT,
                                                 const float* __restrict__ prm,
                                                 const unsigned* __restrict__ flag,
                                                 void* __restrict__ out) {
    __shared__ short As[64][72];
    __shared__ short Bs[128][72];
    __shared__ float scs[256];
    const bool isbf = (*flag != 0u);
    const int id = blockIdx.x;                 // 1024 = 8 XCD * 128
    const int swz = (id & 7) * 128 + (id >> 3);
    const int j0 = (swz & 3) * 64;
    const int rest = swz >> 2;                 // 0..255
    const int n0 = (rest & 31) * 128;
    const int b = rest >> 5;
    const int tid = threadIdx.x;
    const int wid = tid >> 6, l = tid & 63;
    const int lm = l & 15, lk = (l >> 4) * 8;
    const int srow = tid >> 3, soct = tid & 7;
    scs[tid] = sigcm[(b << 8) + tid];
    floatx4 acc[8];
#pragma unroll
    for (int i = 0; i < 8; ++i) acc[i] = (floatx4){0.f, 0.f, 0.f, 0.f};

    for (int k0 = 0; k0 < 256; k0 += 64) {
        __syncthreads();
#pragma unroll
        for (int i = 0; i < 2; ++i) {
            int j = srow + i * 32;
            *(short8*)&As[j][soct * 8] =
                *(const short8*)&wpT[((j0 + j) << 8) + k0 + soct * 8];
        }
#pragma unroll
        for (int i = 0; i < 4; ++i) {
            int n = srow + i * 32;
            int rbase = (((b << 12) + n0 + n) << 8) + k0 + soct * 8;
            short8 pa = *(const short8*)&attT[rbase];
            short8 pc = *(const short8*)&convT[rbase];
            float sv = sigsm[(b << 12) + n0 + n];
            short8 pz;
#pragma unroll
            for (int u = 0; u < 8; ++u)
                pz[u] = f2s(s2f(pa[u]) * sv + s2f(pc[u]) * scs[k0 + soct * 8 + u]);
            *(short8*)&Bs[n][soct * 8] = pz;
        }
        __syncthreads();
#pragma unroll
        for (int h = 0; h < 2; ++h) {
            short8 af = *(const short8*)&As[wid * 16 + lm][h * 32 + lk];
#pragma unroll
            for (int nt = 0; nt < 8; ++nt) {
                short8 bfr = *(const short8*)&Bs[nt * 16 + lm][h * 32 + lk];
                acc[nt] = MFMA16(af, bfr, acc[nt]);
            }
        }
    }
    const int jb = j0 + wid * 16 + (l >> 4) * 4;
    float bp[4];
#pragma unroll
    for (int r = 0; r < 4; ++r) bp[r] = prm[P_BPROJ + jb + r];
#pragma unroll
    for (int nt = 0; nt < 8; ++nt) {
        int n = n0 + nt * 16 + lm;
#pragma unroll
        for (int r = 0; r < 4; ++r) {
            int idx = (((b << 8) + jb + r) << 12) + n;
            float val = acc[nt][r] + bp[r];
            if (isbf) ((bf16*)out)[idx] = f2b(val);
            else ((float*)out)[idx] = val;
        }
    }
}

// ---------------------------------------------------------------------------
extern "C" void kernel_launch(void* const* d_in, const int* in_sizes, int n_in,
                              void* d_out, int out_size, void* d_ws, size_t ws_size,
                              hipStream_t stream) {
    char* ws = (char*)d_ws;
    // layout (bytes):
    //   [0,      17M)  vbb bf16 [c][n]
    //   [32M,    48M)  xT bf16   -> attT bf16 alias (after k_qkv_m2 reads xT)
    //   [48M,    64M)  qb bf16
    //   [64M,    80M)  kb bf16   -> convT bf16 alias (after k_qk2p reads kb)
    //   [80M+ )  wqkvT, wprojT, attn, attn_part[4], qss|kss|gap, sigcm,
    //            sigsm, prm, flag
    bf16*  vbb    = (bf16*) (ws);
    bf16*  xT     = (bf16*) (ws + 33554432);
    bf16*  attT   = (bf16*) (ws + 33554432);
    bf16*  qb     = (bf16*) (ws + 50331648);
    bf16*  kb     = (bf16*) (ws + 67108864);
    bf16*  convT  = (bf16*) (ws + 67108864);
    bf16*  wqkvT  = (bf16*) (ws + 83886080);
    bf16*  wprojT = (bf16*) (ws + 84279296);
    float* attn   = (float*)(ws + 84410368);
    float* attn_p = (float*)(ws + 84672512);
    float* qss    = (float*)(ws + 85721088);   // qss|kss|gap contiguous 24576B
    float* kss    = (float*)(ws + 85729280);
    float* gap    = (float*)(ws + 85737472);
    float* sigcm  = (float*)(ws + 85745664);
    float* sigsm  = (float*)(ws + 85753856);
    float* prm    = (float*)(ws + 85884928);
    unsigned* flag = (unsigned*)(ws + 85985280);

    k_sniff<<<1, 256, 0, stream>>>((const unsigned*)d_in[0], flag, qss);

    CvtArgs a;
    const int map_src[24] = {3, 4, 5, 6, 7, 8, 9, 10, 11, 12, 13, 14, 15, 16, 17,
                             18, 19, 20, 21, 22, 23, 24, 25, 26};
    const int map_dst[24] = {P_BPROJ, P_DWK, P_DWB, P_DWG, P_DWBT, P_DWM, P_DWV,
                             P_CIG, P_CIBT, P_CIM, P_CIV, P_SIG, P_SIBT, P_SIM, P_SIV,
                             P_CIW1, P_CIB1, P_CIW2, P_CIB2, P_SIW1, P_SIB1, P_SIW2,
                             P_SIB2, P_TEMP};
    for (int i = 0; i < 24; ++i) {
        a.src[i] = d_in[map_src[i]];
        a.dst[i] = map_dst[i];
        a.cnt[i] = in_sizes[map_src[i]];
    }
    k_cvt<<<24, 256, 0, stream>>>(a, prm, flag);

    k_xt2<<<dim3(64, 4, 8), 256, 0, stream>>>(d_in[0], flag, xT);
    k_wt2<<<dim3(12, 4), 256, 0, stream>>>(d_in[1], flag, wqkvT, 768);
    k_wt2<<<dim3(4, 4), 256, 0, stream>>>(d_in[2], flag, wprojT, 256);

    k_qkv_m2<<<3072, 256, 0, stream>>>(xT, wqkvT, qb, kb, vbb, qss, kss);
    k_qk2p<<<dim3(8, 8, 4), 256, 0, stream>>>(qb, kb, attn_p);
    k_softmax2<<<dim3(8, 8), 64, 0, stream>>>(attn_p, qss, kss, prm, attn);
    k_attv2<<<dim3(16, 8, 8), 256, 0, stream>>>(attn, vbb, attT, gap);
    k_dwconv3<<<dim3(4, 32, 8), 256, 0, stream>>>(vbb, prm, convT);
    k_cm<<<8, 256, 0, stream>>>(gap, prm, sigcm);
    k_sm2<<<dim3(16, 8), 256, 0, stream>>>(convT, prm, sigsm);
    k_proj_m2<<<1024, 256, 0, stream>>>(attT, convT, sigsm, sigcm,
                                        wprojT, prm, flag, d_out);
}

// Round 10
// 166.787 us; speedup vs baseline: 2.9960x; 1.0055x over previous
//
#include <hip/hip_runtime.h>
#include <hip/hip_bf16.h>
#include <math.h>

typedef __hip_bfloat16 bf16;
typedef __attribute__((ext_vector_type(8))) short short8;
typedef __attribute__((ext_vector_type(4))) short short4v;
typedef __attribute__((ext_vector_type(4))) float floatx4;

__device__ __forceinline__ bf16 f2b(float v) { return __float2bfloat16(v); }
__device__ __forceinline__ short f2s(float v) {
    bf16 h = __float2bfloat16(v);
    return *reinterpret_cast<short*>(&h);
}
__device__ __forceinline__ float s2f(short s) {
    union { unsigned u; float f; } t;
    t.u = ((unsigned)(unsigned short)s) << 16;
    return t.f;
}
__device__ __forceinline__ float gelu_exact(float x) {
    return 0.5f * x * (1.0f + erff(x * 0.70710678118654752440f));
}
__device__ __forceinline__ float sigmoidf_(float x) {
    return 1.0f / (1.0f + __expf(-x));
}
__device__ __forceinline__ float ldin(const void* p, int i, bool isbf) {
    return isbf ? s2f(((const short*)p)[i]) : ((const float*)p)[i];
}
#define MFMA16(a, b, c) __builtin_amdgcn_mfma_f32_16x16x32_bf16(a, b, c, 0, 0, 0)

// fp32 params block layout (offsets in floats)
#define P_DWK    0
#define P_DWB    2304
#define P_DWG    2560
#define P_DWBT   2816
#define P_DWM    3072
#define P_DWV    3328
#define P_CIW1   3584
#define P_CIB1   11776
#define P_CIG    11808
#define P_CIBT   11840
#define P_CIM    11872
#define P_CIV    11904
#define P_CIW2   11936
#define P_CIB2   20128
#define P_SIW1   20384
#define P_SIB1   24480
#define P_SIG    24496
#define P_SIBT   24512
#define P_SIM    24528
#define P_SIV    24544
#define P_SIW2   24560
#define P_SIB2   24576
#define P_TEMP   24577
#define P_BPROJ  24585

// ---------------------------------------------------------------------------
// K0: dtype sniffer + zero the atomic accumulators (qss|kss|gap, 6144 floats).
// ---------------------------------------------------------------------------
__global__ __launch_bounds__(256) void k_sniff(const unsigned* __restrict__ x,
                                               unsigned* __restrict__ flag,
                                               float* __restrict__ accbuf) {
    for (int i = threadIdx.x; i < 6144; i += 256) accbuf[i] = 0.f;
    int cnt = 0;
    for (int i = threadIdx.x; i < 4096; i += 256) {
        unsigned lo = x[i] & 0xFFFFu;
        unsigned e = (lo >> 7) & 0xFFu;
        cnt += (e >= 0x66u && e <= 0x8Au) ? 1 : 0;
    }
    __shared__ int red[256];
    red[threadIdx.x] = cnt;
    __syncthreads();
    for (int o = 128; o > 0; o >>= 1) {
        if (threadIdx.x < o) red[threadIdx.x] += red[threadIdx.x + o];
        __syncthreads();
    }
    if (threadIdx.x == 0) *flag = (red[0] > 2048) ? 1u : 0u;
}

// ---------------------------------------------------------------------------
// K0b: convert all small params to fp32 block.
// ---------------------------------------------------------------------------
struct CvtArgs { const void* src[24]; int dst[24]; int cnt[24]; };

__global__ __launch_bounds__(256) void k_cvt(CvtArgs a, float* __restrict__ prm,
                                             const unsigned* __restrict__ flag) {
    const bool isbf = (*flag != 0u);
    const int e = blockIdx.x;
    const void* s = a.src[e];
    float* d = prm + a.dst[e];
    const int n = a.cnt[e];
    for (int i = threadIdx.x; i < n; i += 256) d[i] = ldin(s, i, isbf);
}

// ===========================================================================
// Swizzled 64x64 transpose tile helpers (bijective; see round 6 notes).
// ===========================================================================

// ---------------------------------------------------------------------------
// K_xt2: x [b][c][n] (fp32 or bf16) -> xT bf16 [b][n][c].
// ---------------------------------------------------------------------------
__global__ __launch_bounds__(256) void k_xt2(const void* __restrict__ x,
                                             const unsigned* __restrict__ flag,
                                             bf16* __restrict__ xT) {
    __shared__ short T[64][72];
    const bool isbf = (*flag != 0u);
    const int b = blockIdx.z, c0 = blockIdx.y * 64, n0 = blockIdx.x * 64;
    const int tid = threadIdx.x;
    const int cc = tid >> 3, oct = tid & 7;
#pragma unroll
    for (int i = 0; i < 2; ++i) {
        int col = cc + i * 32;
        long gbase = ((long)(b * 256 + c0 + col) << 12) + n0 + oct * 8;
        short v[8];
        if (isbf) {
            short8 p = *(const short8*)((const short*)x + gbase);
#pragma unroll
            for (int u = 0; u < 8; ++u) v[u] = p[u];
        } else {
            floatx4 q0 = *(const floatx4*)((const float*)x + gbase);
            floatx4 q1 = *(const floatx4*)((const float*)x + gbase + 4);
#pragma unroll
            for (int u = 0; u < 4; ++u) { v[u] = f2s(q0[u]); v[4 + u] = f2s(q1[u]); }
        }
        int row0 = oct * 8;
#pragma unroll
        for (int u = 0; u < 8; ++u) {
            int row = row0 + u;
            T[row][(((col >> 3) ^ (row & 7)) << 3) + (col & 7)] = v[u];
        }
    }
    __syncthreads();
    const int rn = tid >> 3;
#pragma unroll
    for (int i = 0; i < 2; ++i) {
        int n = rn + i * 32;
        short8 p = *(const short8*)&T[n][((oct ^ (n & 7)) << 3)];
        *(short8*)&xT[(((b << 12) + n0 + n) << 8) + c0 + oct * 8] = p;
    }
}

// ---------------------------------------------------------------------------
// K_wt2: w [c][j] (256 x ncols) -> wT bf16 [j][c].
// ---------------------------------------------------------------------------
__global__ __launch_bounds__(256) void k_wt2(const void* __restrict__ src,
                                             const unsigned* __restrict__ flag,
                                             bf16* __restrict__ dst, int ncols) {
    __shared__ short T[64][72];
    const bool isbf = (*flag != 0u);
    const int j0 = blockIdx.x * 64, c0 = blockIdx.y * 64;
    const int tid = threadIdx.x;
    const int cc = tid >> 3, oct = tid & 7;
#pragma unroll
    for (int i = 0; i < 2; ++i) {
        int col = cc + i * 32;
        long gbase = (long)(c0 + col) * ncols + j0 + oct * 8;
        short v[8];
        if (isbf) {
            short8 p = *(const short8*)((const short*)src + gbase);
#pragma unroll
            for (int u = 0; u < 8; ++u) v[u] = p[u];
        } else {
            floatx4 q0 = *(const floatx4*)((const float*)src + gbase);
            floatx4 q1 = *(const floatx4*)((const float*)src + gbase + 4);
#pragma unroll
            for (int u = 0; u < 4; ++u) { v[u] = f2s(q0[u]); v[4 + u] = f2s(q1[u]); }
        }
        int row0 = oct * 8;
#pragma unroll
        for (int u = 0; u < 8; ++u) {
            int row = row0 + u;
            T[row][(((col >> 3) ^ (row & 7)) << 3) + (col & 7)] = v[u];
        }
    }
    __syncthreads();
    const int rj = tid >> 3;
#pragma unroll
    for (int i = 0; i < 2; ++i) {
        int j = rj + i * 32;
        short8 p = *(const short8*)&T[j][((oct ^ (j & 7)) << 3)];
        *(short8*)&dst[((j0 + j) << 8) + c0 + oct * 8] = p;
    }
}

// ---------------------------------------------------------------------------
// K1: qkv GEMM (MFMA), 128x128 tile, 4 waves each owning a 64x64 quadrant.
// Grid 1536 = 8 XCD * 192 (bijective swizzle; each XCD owns one batch).
// j-tile y: 0,1 -> q; 2,3 -> k; 4,5 -> v. q/k get fused sum-of-squares.
// ---------------------------------------------------------------------------
__global__ __launch_bounds__(256) void k_qkv_m3(const bf16* __restrict__ xT,
                                                const bf16* __restrict__ wT,
                                                bf16* __restrict__ qb,
                                                bf16* __restrict__ kb,
                                                bf16* __restrict__ vbb,
                                                float* __restrict__ qss,
                                                float* __restrict__ kss) {
    __shared__ short As[128][72];
    __shared__ short Bs[128][72];
    const int id = blockIdx.x;                 // 1536 = 8 * 192
    const int swz = (id & 7) * 192 + (id >> 3);
    const int y = swz % 6;                     // j-tile (fastest -> L2 reuse of xT)
    const int rest = swz / 6;                  // 0..255 ; b = rest>>5 = XCD id
    const int n0 = (rest & 31) * 128;
    const int b = rest >> 5;
    const int j0 = y * 128;
    const int tid = threadIdx.x;
    const int wid = tid >> 6, l = tid & 63;
    const int wr = wid >> 1, wc = wid & 1;
    const int lm = l & 15, lk = (l >> 4) * 8;
    const int srow = tid >> 3, soct = tid & 7;
    floatx4 acc[4][4];
#pragma unroll
    for (int i = 0; i < 4; ++i)
#pragma unroll
        for (int j = 0; j < 4; ++j) acc[i][j] = (floatx4){0.f, 0.f, 0.f, 0.f};

    for (int k0 = 0; k0 < 256; k0 += 64) {
        __syncthreads();
#pragma unroll
        for (int i = 0; i < 4; ++i) {
            int row = srow + i * 32;
            *(short8*)&As[row][soct * 8] =
                *(const short8*)&wT[((j0 + row) << 8) + k0 + soct * 8];
            *(short8*)&Bs[row][soct * 8] =
                *(const short8*)&xT[(((b << 12) + n0 + row) << 8) + k0 + soct * 8];
        }
        __syncthreads();
#pragma unroll
        for (int h = 0; h < 2; ++h) {
            short8 af[4], bfv[4];
#pragma unroll
            for (int mt = 0; mt < 4; ++mt)
                af[mt] = *(const short8*)&As[wr * 64 + mt * 16 + lm][h * 32 + lk];
#pragma unroll
            for (int nt = 0; nt < 4; ++nt)
                bfv[nt] = *(const short8*)&Bs[wc * 64 + nt * 16 + lm][h * 32 + lk];
#pragma unroll
            for (int mt = 0; mt < 4; ++mt)
#pragma unroll
                for (int nt = 0; nt < 4; ++nt)
                    acc[mt][nt] = MFMA16(af[mt], bfv[nt], acc[mt][nt]);
        }
    }
    const int jbase = wr * 64 + (l >> 4) * 4;  // + mt*16 + r  (local 0..127)
    const int jq = (y & 1) * 128;              // j-tile offset within q/k/v
    if (y < 4) {
        bf16* dst = (y < 2) ? qb : kb;
#pragma unroll
        for (int mt = 0; mt < 4; ++mt)
#pragma unroll
            for (int nt = 0; nt < 4; ++nt) {
                int n = n0 + wc * 64 + nt * 16 + lm;
#pragma unroll
                for (int r = 0; r < 4; ++r)
                    dst[(((b << 8) + jq + jbase + mt * 16 + r) << 12) + n] =
                        f2b(acc[mt][nt][r]);
            }
        __syncthreads();
        float* red = (float*)&As[0][0];        // 128*32 floats = 16 KB
#pragma unroll
        for (int mt = 0; mt < 4; ++mt)
#pragma unroll
            for (int r = 0; r < 4; ++r) {
                float s = 0.f;
#pragma unroll
                for (int nt = 0; nt < 4; ++nt) {
                    float v = acc[mt][nt][r];
                    s = fmaf(v, v, s);
                }
                red[(jbase + mt * 16 + r) * 32 + wc * 16 + lm] = s;
            }
        __syncthreads();
        if (tid < 128) {
            float s = 0.f;
#pragma unroll
            for (int i = 0; i < 32; ++i)
                s += red[tid * 32 + ((i + tid) & 31)];   // rotated: no bank serial
            float* dsts = (y < 2) ? qss : kss;
            atomicAdd(&dsts[(b << 8) + jq + tid], s);
        }
    } else {
        // BUGFIX (round 9): v channels need the jq offset too (y=5 -> +128)
#pragma unroll
        for (int mt = 0; mt < 4; ++mt)
#pragma unroll
            for (int nt = 0; nt < 4; ++nt) {
                int n = n0 + wc * 64 + nt * 16 + lm;
#pragma unroll
                for (int r = 0; r < 4; ++r)
                    vbb[(((b << 8) + jq + jbase + mt * 16 + r) << 12) + n] =
                        f2b(acc[mt][nt][r]);
            }
    }
}

// ---------------------------------------------------------------------------
// K3: fused QK^T (MFMA over n) + l2 scales + temperature + softmax.
// ---------------------------------------------------------------------------
__global__ __launch_bounds__(256) void k_qk3(const bf16* __restrict__ qb,
                                             const bf16* __restrict__ kb,
                                             const float* __restrict__ qss,
                                             const float* __restrict__ kss,
                                             const float* __restrict__ prm,
                                             float* __restrict__ attn) {
    __shared__ float AS[32][32];
    const int h = blockIdx.x, b = blockIdx.y;
    const int tid = threadIdx.x;
    const int wid = tid >> 6, l = tid & 63;
    const int lm = l & 15, lk = (l >> 4) * 8;
    floatx4 acc[2][2];
#pragma unroll
    for (int i = 0; i < 2; ++i)
#pragma unroll
        for (int j = 0; j < 2; ++j) acc[i][j] = (floatx4){0.f, 0.f, 0.f, 0.f};
    const int cbase = (b << 8) + h * 32;
    for (int it = 0; it < 32; ++it) {
        int n = wid * 1024 + it * 32 + lk;
        short8 a0 = *(const short8*)&qb[((cbase + lm) << 12) + n];
        short8 a1 = *(const short8*)&qb[((cbase + 16 + lm) << 12) + n];
        short8 b0 = *(const short8*)&kb[((cbase + lm) << 12) + n];
        short8 b1 = *(const short8*)&kb[((cbase + 16 + lm) << 12) + n];
        acc[0][0] = MFMA16(a0, b0, acc[0][0]);
        acc[0][1] = MFMA16(a0, b1, acc[0][1]);
        acc[1][0] = MFMA16(a1, b0, acc[1][0]);
        acc[1][1] = MFMA16(a1, b1, acc[1][1]);
    }
    for (int i = tid; i < 1024; i += 256) ((float*)AS)[i] = 0.f;
    __syncthreads();
#pragma unroll
    for (int mt = 0; mt < 2; ++mt)
#pragma unroll
        for (int nt = 0; nt < 2; ++nt)
#pragma unroll
            for (int r = 0; r < 4; ++r)
                atomicAdd(&AS[mt * 16 + (l >> 4) * 4 + r][nt * 16 + lm], acc[mt][nt][r]);
    __syncthreads();
    if (tid < 32) {
        const int c = tid;
        float qsc = rsqrtf(fmaxf(qss[cbase + c], 1e-12f)) * prm[P_TEMP + h];
        float row[32];
        float m = -1e30f;
#pragma unroll
        for (int d = 0; d < 32; ++d) {
            row[d] = AS[c][d] * qsc * rsqrtf(fmaxf(kss[cbase + d], 1e-12f));
            m = fmaxf(m, row[d]);
        }
        float s = 0.f;
#pragma unroll
        for (int d = 0; d < 32; ++d) {
            row[d] = __expf(row[d] - m);
            s += row[d];
        }
        float inv = 1.0f / s;
        float* dst = attn + ((b * 8 + h) << 10) + c * 32;
#pragma unroll
        for (int d = 0; d < 32; ++d) dst[d] = row[d] * inv;
    }
}

// ---------------------------------------------------------------------------
// K4: att = attn @ v (bf16); writes attT bf16 [b][n][c]; fused gap atomics.
// ---------------------------------------------------------------------------
__global__ __launch_bounds__(256) void k_attv2(const float* __restrict__ attn,
                                               const bf16* __restrict__ vbb,
                                               bf16* __restrict__ attT,
                                               float* __restrict__ gap) {
    __shared__ float A[32][32];
    __shared__ float G[256][32];
    const int b = blockIdx.z, h = blockIdx.y;
    const int tid = threadIdx.x;
    const int n = blockIdx.x * 256 + tid;
    for (int i = tid; i < 1024; i += 256) ((float*)A)[i] = attn[((b * 8 + h) << 10) + i];
    __syncthreads();
    const int base = ((b * 256 + h * 32) << 12) + n;
    float vv[32];
#pragma unroll
    for (int d = 0; d < 32; ++d) vv[d] = s2f(((const short*)vbb)[base + (d << 12)]);
    float av[32];
#pragma unroll
    for (int c = 0; c < 32; ++c) {
        float s = 0.f;
#pragma unroll
        for (int d = 0; d < 32; ++d) s = fmaf(A[c][d], vv[d], s);
        av[c] = s;
        G[tid][c] = s;
    }
    const int obase = (((b << 12) + n) << 8) + h * 32;
#pragma unroll
    for (int g = 0; g < 4; ++g) {
        short8 p;
#pragma unroll
        for (int u = 0; u < 8; ++u) p[u] = f2s(av[g * 8 + u]);
        *(short8*)&attT[obase + g * 8] = p;
    }
    __syncthreads();
    {
        const int colc = tid & 31, rg = tid >> 5;
        float s = 0.f;
#pragma unroll
        for (int i = 0; i < 32; ++i) s += G[rg * 32 + i][colc];
        A[rg][colc] = s;
    }
    __syncthreads();
    if (tid < 32) {
        float s = 0.f;
#pragma unroll
        for (int g = 0; g < 8; ++g) s += A[g][tid];
        atomicAdd(&gap[(b << 8) + h * 32 + tid], s);
    }
}

// ---------------------------------------------------------------------------
// K5: fused depthwise 3x3 + bias + BN + GELU + transpose (writes convT).
// ---------------------------------------------------------------------------
__global__ __launch_bounds__(256) void k_dwconv3(const bf16* __restrict__ vbb,
                                                 const float* __restrict__ prm,
                                                 bf16* __restrict__ convT) {
    __shared__ float S[8][18][66];
    __shared__ float Wl[8][11];
    const int b = blockIdx.z, c0 = blockIdx.y * 8, y0 = blockIdx.x * 16;
    const int tid = threadIdx.x;
    if (tid < 144) {
        int ch = tid / 18, r = tid - ch * 18;
        int gy = y0 + r - 1;
        float* drow = &S[ch][r][0];
        if (gy < 0 || gy > 63) {
            for (int i = 0; i < 66; ++i) drow[i] = 0.f;
        } else {
            const short* src = (const short*)vbb + ((((b << 8) + c0 + ch) << 12) + gy * 64);
            drow[0] = 0.f;
            drow[65] = 0.f;
#pragma unroll
            for (int g = 0; g < 8; ++g) {
                short8 p = *(const short8*)(src + g * 8);
#pragma unroll
                for (int u = 0; u < 8; ++u) drow[1 + g * 8 + u] = s2f(p[u]);
            }
        }
    } else if (tid >= 248) {
        int ch = tid - 248;
        int c = c0 + ch;
        float scale = rsqrtf(prm[P_DWV + c] + 1e-3f) * prm[P_DWG + c];
#pragma unroll
        for (int e = 0; e < 9; ++e) Wl[ch][e] = prm[P_DWK + c * 9 + e] * scale;
        Wl[ch][10] = (prm[P_DWB + c] - prm[P_DWM + c]) * scale + prm[P_DWBT + c];
    }
    __syncthreads();
    const int row = tid >> 4, xl = tid & 15;
#pragma unroll
    for (int u = 0; u < 4; ++u) {
        int x = xl + u * 16;
        short8 o;
#pragma unroll
        for (int ch = 0; ch < 8; ++ch) {
            float acc = Wl[ch][10];
#pragma unroll
            for (int ky = 0; ky < 3; ++ky)
#pragma unroll
                for (int kx = 0; kx < 3; ++kx)
                    acc = fmaf(S[ch][row + ky][x + kx], Wl[ch][ky * 3 + kx], acc);
            o[ch] = f2s(gelu_exact(acc));
        }
        *(short8*)&((short*)convT)[(((b << 12) + (y0 + row) * 64 + x) << 8) + c0] = o;
    }
}

// ---------------------------------------------------------------------------
// K7: channel gate (gap holds SUMS; scale by 1/4096 here).
// ---------------------------------------------------------------------------
__global__ __launch_bounds__(256) void k_cm(const float* __restrict__ gap,
                                            const float* __restrict__ prm,
                                            float* __restrict__ sigcm) {
    const int b = blockIdx.x;
    const int tid = threadIdx.x;
    __shared__ float gl[256];
    __shared__ float t1[32];
    gl[tid] = gap[(b << 8) + tid] * (1.0f / 4096.0f);
    __syncthreads();
    if (tid < 32) {
        float s = prm[P_CIB1 + tid];
        for (int c = 0; c < 256; ++c) s = fmaf(gl[c], prm[P_CIW1 + c * 32 + tid], s);
        s = (s - prm[P_CIM + tid]) * rsqrtf(prm[P_CIV + tid] + 1e-3f) * prm[P_CIG + tid] + prm[P_CIBT + tid];
        t1[tid] = gelu_exact(s);
    }
    __syncthreads();
    float s = prm[P_CIB2 + tid];
#pragma unroll
    for (int o = 0; o < 32; ++o) s = fmaf(t1[o], prm[P_CIW2 + o * 256 + tid], s);
    sigcm[(b << 8) + tid] = sigmoidf_(s);
}

// ---------------------------------------------------------------------------
// K8: spatial gate from convT (vectorized row reads).
// ---------------------------------------------------------------------------
__global__ __launch_bounds__(256) void k_sm2(const bf16* __restrict__ convT,
                                             const float* __restrict__ prm,
                                             float* __restrict__ sigsm) {
    __shared__ float W1[256][16];
    const int b = blockIdx.y;
    const int tid = threadIdx.x;
    const int n = blockIdx.x * 256 + tid;
    for (int i = tid; i < 4096; i += 256) W1[i >> 4][i & 15] = prm[P_SIW1 + i];
    __syncthreads();
    float acc[16];
#pragma unroll
    for (int o = 0; o < 16; ++o) acc[o] = 0.f;
    const bf16* src = convT + (((b << 12) + n) << 8);
#pragma unroll 4
    for (int g = 0; g < 32; ++g) {
        short8 p = *(const short8*)&src[g * 8];
#pragma unroll
        for (int u = 0; u < 8; ++u) {
            float v = s2f(p[u]);
            int c = g * 8 + u;
#pragma unroll
            for (int o = 0; o < 16; ++o) acc[o] = fmaf(v, W1[c][o], acc[o]);
        }
    }
    float sm = prm[P_SIB2];
#pragma unroll
    for (int o = 0; o < 16; ++o) {
        float t = acc[o] + prm[P_SIB1 + o];
        t = (t - prm[P_SIM + o]) * rsqrtf(prm[P_SIV + o] + 1e-3f) * prm[P_SIG + o] + prm[P_SIBT + o];
        sm = fmaf(gelu_exact(t), prm[P_SIW2 + o], sm);
    }
    sigsm[(b << 12) + n] = sigmoidf_(sm);
}

// ---------------------------------------------------------------------------
// K9: final projection (MFMA), 128x128 tile, 4 waves. Grid 512 = 8 XCD * 64.
// ---------------------------------------------------------------------------
__global__ __launch_bounds__(256) void k_proj_m3(const bf16* __restrict__ attT,
                                                 const bf16* __restrict__ convT,
                                                 const float* __restrict__ sigsm,
                                                 const float* __restrict__ sigcm,
                                                 const bf16* __restrict__ wpT,
                                                 const float* __restrict__ prm,
                                                 const unsigned* __restrict__ flag,
                                                 void* __restrict__ out) {
    __shared__ short As[128][72];
    __shared__ short Bs[128][72];
    __shared__ float scs[256];
    const bool isbf = (*flag != 0u);
    const int id = blockIdx.x;                 // 512 = 8 * 64
    const int swz = (id & 7) * 64 + (id >> 3);
    const int j0 = (swz & 1) * 128;
    const int rest = swz >> 1;                 // 0..255 ; b = rest>>5 = XCD id
    const int n0 = (rest & 31) * 128;
    const int b = rest >> 5;
    const int tid = threadIdx.x;
    const int wid = tid >> 6, l = tid & 63;
    const int wr = wid >> 1, wc = wid & 1;
    const int lm = l & 15, lk = (l >> 4) * 8;
    const int srow = tid >> 3, soct = tid & 7;
    scs[tid] = sigcm[(b << 8) + tid];
    floatx4 acc[4][4];
#pragma unroll
    for (int i = 0; i < 4; ++i)
#pragma unroll
        for (int j = 0; j < 4; ++j) acc[i][j] = (floatx4){0.f, 0.f, 0.f, 0.f};

    for (int k0 = 0; k0 < 256; k0 += 64) {
        __syncthreads();
#pragma unroll
        for (int i = 0; i < 4; ++i) {
            int row = srow + i * 32;
            *(short8*)&As[row][soct * 8] =
                *(const short8*)&wpT[((j0 + row) << 8) + k0 + soct * 8];
            int rbase = (((b << 12) + n0 + row) << 8) + k0 + soct * 8;
            short8 pa = *(const short8*)&attT[rbase];
            short8 pc = *(const short8*)&convT[rbase];
            float sv = sigsm[(b << 12) + n0 + row];
            short8 pz;
#pragma unroll
            for (int u = 0; u < 8; ++u)
                pz[u] = f2s(s2f(pa[u]) * sv + s2f(pc[u]) * scs[k0 + soct * 8 + u]);
            *(short8*)&Bs[row][soct * 8] = pz;
        }
        __syncthreads();
#pragma unroll
        for (int h = 0; h < 2; ++h) {
            short8 af[4], bfv[4];
#pragma unroll
            for (int mt = 0; mt < 4; ++mt)
                af[mt] = *(const short8*)&As[wr * 64 + mt * 16 + lm][h * 32 + lk];
#pragma unroll
            for (int nt = 0; nt < 4; ++nt)
                bfv[nt] = *(const short8*)&Bs[wc * 64 + nt * 16 + lm][h * 32 + lk];
#pragma unroll
            for (int mt = 0; mt < 4; ++mt)
#pragma unroll
                for (int nt = 0; nt < 4; ++nt)
                    acc[mt][nt] = MFMA16(af[mt], bfv[nt], acc[mt][nt]);
        }
    }
    const int jbase = j0 + wr * 64 + (l >> 4) * 4;
#pragma unroll
    for (int mt = 0; mt < 4; ++mt) {
        float bp[4];
#pragma unroll
        for (int r = 0; r < 4; ++r) bp[r] = prm[P_BPROJ + jbase + mt * 16 + r];
#pragma unroll
        for (int nt = 0; nt < 4; ++nt) {
            int n = n0 + wc * 64 + nt * 16 + lm;
#pragma unroll
            for (int r = 0; r < 4; ++r) {
                int idx = (((b << 8) + jbase + mt * 16 + r) << 12) + n;
                float val = acc[mt][nt][r] + bp[r];
                if (isbf) ((bf16*)out)[idx] = f2b(val);
                else ((float*)out)[idx] = val;
            }
        }
    }
}

// ---------------------------------------------------------------------------
extern "C" void kernel_launch(void* const* d_in, const int* in_sizes, int n_in,
                              void* d_out, int out_size, void* d_ws, size_t ws_size,
                              hipStream_t stream) {
    char* ws = (char*)d_ws;
    bf16*  vbb    = (bf16*) (ws);
    bf16*  xT     = (bf16*) (ws + 33554432);
    bf16*  attT   = (bf16*) (ws + 33554432);
    bf16*  qb     = (bf16*) (ws + 50331648);
    bf16*  kb     = (bf16*) (ws + 67108864);
    bf16*  convT  = (bf16*) (ws + 67108864);
    bf16*  wqkvT  = (bf16*) (ws + 83886080);
    bf16*  wprojT = (bf16*) (ws + 84279296);
    float* attn   = (float*)(ws + 84410368);
    float* qss    = (float*)(ws + 85721088);   // qss|kss|gap contiguous 24576B
    float* kss    = (float*)(ws + 85729280);
    float* gap    = (float*)(ws + 85737472);
    float* sigcm  = (float*)(ws + 85745664);
    float* sigsm  = (float*)(ws + 85753856);
    float* prm    = (float*)(ws + 85884928);
    unsigned* flag = (unsigned*)(ws + 85985280);

    k_sniff<<<1, 256, 0, stream>>>((const unsigned*)d_in[0], flag, qss);

    CvtArgs a;
    const int map_src[24] = {3, 4, 5, 6, 7, 8, 9, 10, 11, 12, 13, 14, 15, 16, 17,
                             18, 19, 20, 21, 22, 23, 24, 25, 26};
    const int map_dst[24] = {P_BPROJ, P_DWK, P_DWB, P_DWG, P_DWBT, P_DWM, P_DWV,
                             P_CIG, P_CIBT, P_CIM, P_CIV, P_SIG, P_SIBT, P_SIM, P_SIV,
                             P_CIW1, P_CIB1, P_CIW2, P_CIB2, P_SIW1, P_SIB1, P_SIW2,
                             P_SIB2, P_TEMP};
    for (int i = 0; i < 24; ++i) {
        a.src[i] = d_in[map_src[i]];
        a.dst[i] = map_dst[i];
        a.cnt[i] = in_sizes[map_src[i]];
    }
    k_cvt<<<24, 256, 0, stream>>>(a, prm, flag);

    k_xt2<<<dim3(64, 4, 8), 256, 0, stream>>>(d_in[0], flag, xT);
    k_wt2<<<dim3(12, 4), 256, 0, stream>>>(d_in[1], flag, wqkvT, 768);
    k_wt2<<<dim3(4, 4), 256, 0, stream>>>(d_in[2], flag, wprojT, 256);

    k_qkv_m3<<<1536, 256, 0, stream>>>(xT, wqkvT, qb, kb, vbb, qss, kss);
    k_qk3<<<dim3(8, 8), 256, 0, stream>>>(qb, kb, qss, kss, prm, attn);
    k_attv2<<<dim3(16, 8, 8), 256, 0, stream>>>(attn, vbb, attT, gap);
    k_dwconv3<<<dim3(4, 32, 8), 256, 0, stream>>>(vbb, prm, convT);
    k_cm<<<8, 256, 0, stream>>>(gap, prm, sigcm);
    k_sm2<<<dim3(16, 8), 256, 0, stream>>>(convT, prm, sigsm);
    k_proj_m3<<<512, 256, 0, stream>>>(attT, convT, sigsm, sigcm,
                                       wprojT, prm, flag, d_out);
}

// Round 12
// 137.089 us; speedup vs baseline: 3.6450x; 1.2166x over previous
//
#include <hip/hip_runtime.h>
#include <hip/hip_bf16.h>
#include <math.h>

typedef __hip_bfloat16 bf16;
typedef __attribute__((ext_vector_type(8))) short short8;
typedef __attribute__((ext_vector_type(4))) short short4v;
typedef __attribute__((ext_vector_type(4))) float floatx4;

__device__ __forceinline__ bf16 f2b(float v) { return __float2bfloat16(v); }
__device__ __forceinline__ short f2s(float v) {
    bf16 h = __float2bfloat16(v);
    return *reinterpret_cast<short*>(&h);
}
__device__ __forceinline__ float s2f(short s) {
    union { unsigned u; float f; } t;
    t.u = ((unsigned)(unsigned short)s) << 16;
    return t.f;
}
__device__ __forceinline__ float gelu_exact(float x) {
    return 0.5f * x * (1.0f + erff(x * 0.70710678118654752440f));
}
__device__ __forceinline__ float sigmoidf_(float x) {
    return 1.0f / (1.0f + __expf(-x));
}
__device__ __forceinline__ float ldin(const void* p, int i, bool isbf) {
    return isbf ? s2f(((const short*)p)[i]) : ((const float*)p)[i];
}
#define MFMA16(a, b, c) __builtin_amdgcn_mfma_f32_16x16x32_bf16(a, b, c, 0, 0, 0)

// fp32 params block layout (offsets in floats)
#define P_DWK    0
#define P_DWB    2304
#define P_DWG    2560
#define P_DWBT   2816
#define P_DWM    3072
#define P_DWV    3328
#define P_CIW1   3584
#define P_CIB1   11776
#define P_CIG    11808
#define P_CIBT   11840
#define P_CIM    11872
#define P_CIV    11904
#define P_CIW2   11936
#define P_CIB2   20128
#define P_SIW1   20384
#define P_SIB1   24480
#define P_SIG    24496
#define P_SIBT   24512
#define P_SIM    24528
#define P_SIV    24544
#define P_SIW2   24560
#define P_SIB2   24576
#define P_TEMP   24577
#define P_BPROJ  24585

// ---------------------------------------------------------------------------
// helper: per-block dtype sniff of x's first 4096 words (cheap, L2-hot).
// ---------------------------------------------------------------------------
__device__ __forceinline__ bool block_sniff(const unsigned* __restrict__ x) {
    int cnt = 0;
    for (int i = threadIdx.x; i < 4096; i += 256) {
        unsigned lo = x[i] & 0xFFFFu;
        unsigned e = (lo >> 7) & 0xFFu;
        cnt += (e >= 0x66u && e <= 0x8Au) ? 1 : 0;
    }
    __shared__ int red[256];
    red[threadIdx.x] = cnt;
    __syncthreads();
    for (int o = 128; o > 0; o >>= 1) {
        if (threadIdx.x < o) red[threadIdx.x] += red[threadIdx.x + o];
        __syncthreads();
    }
    return red[0] > 2048;
}

// ---------------------------------------------------------------------------
// K_prep (node 1): blocks 0..23 convert params (self-sniffed dtype);
// block 24 zeros qss|kss|gap and publishes the flag for later kernels.
// ---------------------------------------------------------------------------
struct CvtArgs { const void* src[24]; int dst[24]; int cnt[24]; };

__global__ __launch_bounds__(256) void k_prep(CvtArgs a, float* __restrict__ prm,
                                              const unsigned* __restrict__ x,
                                              unsigned* __restrict__ flag,
                                              float* __restrict__ accbuf) {
    const bool isbf = block_sniff(x);
    const int e = blockIdx.x;
    if (e < 24) {
        const void* s = a.src[e];
        float* d = prm + a.dst[e];
        const int n = a.cnt[e];
        for (int i = threadIdx.x; i < n; i += 256) d[i] = ldin(s, i, isbf);
    } else {
        for (int i = threadIdx.x; i < 6144; i += 256) accbuf[i] = 0.f;
        if (threadIdx.x == 0) *flag = isbf ? 1u : 0u;
    }
}

// ---------------------------------------------------------------------------
// K_trans (node 2): all three transposes in one kernel.
//  id < 2048        : x [b][c][n] -> xT bf16 [b][n][c]
//  2048 <= id < 2096: w_qkv -> wqkvT [j][c]   (ncols 768)
//  2096 <= id < 2112: w_proj -> wprojT [j][c] (ncols 256)
// Swizzled 64x64 tile (bijective):
//  write (row,col): T[row][(((col>>3) ^ (row&7)) << 3) + (col&7)]
//  read  (row,oct): *(short8*)&T[row][((oct ^ (row&7)) << 3)]
// ---------------------------------------------------------------------------
__global__ __launch_bounds__(256) void k_trans(const void* __restrict__ x,
                                               const void* __restrict__ wqkv,
                                               const void* __restrict__ wproj,
                                               const unsigned* __restrict__ flag,
                                               bf16* __restrict__ xT,
                                               bf16* __restrict__ wqkvT,
                                               bf16* __restrict__ wprojT) {
    __shared__ short T[64][72];
    const bool isbf = (*flag != 0u);
    const int id = blockIdx.x;
    const int tid = threadIdx.x;
    const int cc = tid >> 3, oct = tid & 7;

    const void* src;
    bf16* dst;
    long row_stride;
    long src_off;
    int c0;
    long out_row_off;
    if (id < 2048) {
        int nx = id & 63, cy = (id >> 6) & 3, b = id >> 8;
        c0 = cy * 64;
        int n0 = nx * 64;
        src = x;
        dst = xT;
        row_stride = 4096;
        src_off = ((long)(b * 256 + c0) << 12) + n0;
        out_row_off = ((long)(b << 12) + n0) << 8;
    } else if (id < 2096) {
        int id2 = id - 2048;
        int jx = id2 % 12, cy = id2 / 12;
        c0 = cy * 64;
        int j0 = jx * 64;
        src = wqkv;
        dst = wqkvT;
        row_stride = 768;
        src_off = (long)c0 * 768 + j0;
        out_row_off = (long)j0 << 8;
    } else {
        int id3 = id - 2096;
        int jx = id3 & 3, cy = id3 >> 2;
        c0 = cy * 64;
        int j0 = jx * 64;
        src = wproj;
        dst = wprojT;
        row_stride = 256;
        src_off = (long)c0 * 256 + j0;
        out_row_off = (long)j0 << 8;
    }

#pragma unroll
    for (int i = 0; i < 2; ++i) {
        int col = cc + i * 32;
        long gbase = src_off + (long)col * row_stride + oct * 8;
        short v[8];
        if (isbf) {
            short8 p = *(const short8*)((const short*)src + gbase);
#pragma unroll
            for (int u = 0; u < 8; ++u) v[u] = p[u];
        } else {
            floatx4 q0 = *(const floatx4*)((const float*)src + gbase);
            floatx4 q1 = *(const floatx4*)((const float*)src + gbase + 4);
#pragma unroll
            for (int u = 0; u < 4; ++u) { v[u] = f2s(q0[u]); v[4 + u] = f2s(q1[u]); }
        }
        int row0 = oct * 8;
#pragma unroll
        for (int u = 0; u < 8; ++u) {
            int row = row0 + u;
            T[row][(((col >> 3) ^ (row & 7)) << 3) + (col & 7)] = v[u];
        }
    }
    __syncthreads();
    const int rr = tid >> 3;
#pragma unroll
    for (int i = 0; i < 2; ++i) {
        int row = rr + i * 32;
        short8 p = *(const short8*)&T[row][((oct ^ (row & 7)) << 3)];
        *(short8*)&dst[out_row_off + ((long)row << 8) + c0 + oct * 8] = p;
    }
}

// ---------------------------------------------------------------------------
// K1 (node 3): qkv GEMM (MFMA), 128x128 tile, 4 waves (64x64 quadrants).
// Grid 1536 = 8 XCD * 192 (bijective swizzle; each XCD owns one batch).
// ---------------------------------------------------------------------------
__global__ __launch_bounds__(256) void k_qkv_m3(const bf16* __restrict__ xT,
                                                const bf16* __restrict__ wT,
                                                bf16* __restrict__ qb,
                                                bf16* __restrict__ kb,
                                                bf16* __restrict__ vbb,
                                                float* __restrict__ qss,
                                                float* __restrict__ kss) {
    __shared__ short As[128][72];
    __shared__ short Bs[128][72];
    const int id = blockIdx.x;                 // 1536 = 8 * 192
    const int swz = (id & 7) * 192 + (id >> 3);
    const int y = swz % 6;
    const int rest = swz / 6;
    const int n0 = (rest & 31) * 128;
    const int b = rest >> 5;
    const int j0 = y * 128;
    const int tid = threadIdx.x;
    const int wid = tid >> 6, l = tid & 63;
    const int wr = wid >> 1, wc = wid & 1;
    const int lm = l & 15, lk = (l >> 4) * 8;
    const int srow = tid >> 3, soct = tid & 7;
    floatx4 acc[4][4];
#pragma unroll
    for (int i = 0; i < 4; ++i)
#pragma unroll
        for (int j = 0; j < 4; ++j) acc[i][j] = (floatx4){0.f, 0.f, 0.f, 0.f};

    for (int k0 = 0; k0 < 256; k0 += 64) {
        __syncthreads();
#pragma unroll
        for (int i = 0; i < 4; ++i) {
            int row = srow + i * 32;
            *(short8*)&As[row][soct * 8] =
                *(const short8*)&wT[((j0 + row) << 8) + k0 + soct * 8];
            *(short8*)&Bs[row][soct * 8] =
                *(const short8*)&xT[(((b << 12) + n0 + row) << 8) + k0 + soct * 8];
        }
        __syncthreads();
#pragma unroll
        for (int h = 0; h < 2; ++h) {
            short8 af[4], bfv[4];
#pragma unroll
            for (int mt = 0; mt < 4; ++mt)
                af[mt] = *(const short8*)&As[wr * 64 + mt * 16 + lm][h * 32 + lk];
#pragma unroll
            for (int nt = 0; nt < 4; ++nt)
                bfv[nt] = *(const short8*)&Bs[wc * 64 + nt * 16 + lm][h * 32 + lk];
#pragma unroll
            for (int mt = 0; mt < 4; ++mt)
#pragma unroll
                for (int nt = 0; nt < 4; ++nt)
                    acc[mt][nt] = MFMA16(af[mt], bfv[nt], acc[mt][nt]);
        }
    }
    const int jbase = wr * 64 + (l >> 4) * 4;
    const int jq = (y & 1) * 128;
    if (y < 4) {
        bf16* dst = (y < 2) ? qb : kb;
#pragma unroll
        for (int mt = 0; mt < 4; ++mt)
#pragma unroll
            for (int nt = 0; nt < 4; ++nt) {
                int n = n0 + wc * 64 + nt * 16 + lm;
#pragma unroll
                for (int r = 0; r < 4; ++r)
                    dst[(((b << 8) + jq + jbase + mt * 16 + r) << 12) + n] =
                        f2b(acc[mt][nt][r]);
            }
        __syncthreads();
        float* red = (float*)&As[0][0];
#pragma unroll
        for (int mt = 0; mt < 4; ++mt)
#pragma unroll
            for (int r = 0; r < 4; ++r) {
                float s = 0.f;
#pragma unroll
                for (int nt = 0; nt < 4; ++nt) {
                    float v = acc[mt][nt][r];
                    s = fmaf(v, v, s);
                }
                red[(jbase + mt * 16 + r) * 32 + wc * 16 + lm] = s;
            }
        __syncthreads();
        if (tid < 128) {
            float s = 0.f;
#pragma unroll
            for (int i = 0; i < 32; ++i)
                s += red[tid * 32 + ((i + tid) & 31)];
            float* dsts = (y < 2) ? qss : kss;
            atomicAdd(&dsts[(b << 8) + jq + tid], s);
        }
    } else {
#pragma unroll
        for (int mt = 0; mt < 4; ++mt)
#pragma unroll
            for (int nt = 0; nt < 4; ++nt) {
                int n = n0 + wc * 64 + nt * 16 + lm;
#pragma unroll
                for (int r = 0; r < 4; ++r)
                    vbb[(((b << 8) + jq + jbase + mt * 16 + r) << 12) + n] =
                        f2b(acc[mt][nt][r]);
            }
    }
}

// ---------------------------------------------------------------------------
// K_qkdw (node 4): id<64 -> fused QK^T+softmax (per (h,b));
//                  id>=64 -> depthwise conv + BN + GELU + transpose.
// NOTE: convT must NOT alias qb/kb (qk3 blocks read them concurrently).
// ---------------------------------------------------------------------------
__global__ __launch_bounds__(256) void k_qkdw(const bf16* __restrict__ qb,
                                              const bf16* __restrict__ kb,
                                              const float* __restrict__ qss,
                                              const float* __restrict__ kss,
                                              const bf16* __restrict__ vbb,
                                              const float* __restrict__ prm,
                                              float* __restrict__ attn,
                                              bf16* __restrict__ convT) {
    __shared__ __align__(16) char smem[38368];
    const int id = blockIdx.x;
    const int tid = threadIdx.x;
    if (id < 64) {
        float (*AS)[32] = (float(*)[32])smem;
        const int h = id & 7, b = id >> 3;
        const int wid = tid >> 6, l = tid & 63;
        const int lm = l & 15, lk = (l >> 4) * 8;
        floatx4 acc[2][2];
#pragma unroll
        for (int i = 0; i < 2; ++i)
#pragma unroll
            for (int j = 0; j < 2; ++j) acc[i][j] = (floatx4){0.f, 0.f, 0.f, 0.f};
        const int cbase = (b << 8) + h * 32;
        for (int it = 0; it < 32; ++it) {
            int n = wid * 1024 + it * 32 + lk;
            short8 a0 = *(const short8*)&qb[((cbase + lm) << 12) + n];
            short8 a1 = *(const short8*)&qb[((cbase + 16 + lm) << 12) + n];
            short8 b0 = *(const short8*)&kb[((cbase + lm) << 12) + n];
            short8 b1 = *(const short8*)&kb[((cbase + 16 + lm) << 12) + n];
            acc[0][0] = MFMA16(a0, b0, acc[0][0]);
            acc[0][1] = MFMA16(a0, b1, acc[0][1]);
            acc[1][0] = MFMA16(a1, b0, acc[1][0]);
            acc[1][1] = MFMA16(a1, b1, acc[1][1]);
        }
        for (int i = tid; i < 1024; i += 256) ((float*)AS)[i] = 0.f;
        __syncthreads();
#pragma unroll
        for (int mt = 0; mt < 2; ++mt)
#pragma unroll
            for (int nt = 0; nt < 2; ++nt)
#pragma unroll
                for (int r = 0; r < 4; ++r)
                    atomicAdd(&AS[mt * 16 + (l >> 4) * 4 + r][nt * 16 + lm],
                              acc[mt][nt][r]);
        __syncthreads();
        if (tid < 32) {
            const int c = tid;
            float qsc = rsqrtf(fmaxf(qss[cbase + c], 1e-12f)) * prm[P_TEMP + h];
            float row[32];
            float m = -1e30f;
#pragma unroll
            for (int d = 0; d < 32; ++d) {
                row[d] = AS[c][d] * qsc * rsqrtf(fmaxf(kss[cbase + d], 1e-12f));
                m = fmaxf(m, row[d]);
            }
            float s = 0.f;
#pragma unroll
            for (int d = 0; d < 32; ++d) {
                row[d] = __expf(row[d] - m);
                s += row[d];
            }
            float inv = 1.0f / s;
            float* dst = attn + ((b * 8 + h) << 10) + c * 32;
#pragma unroll
            for (int d = 0; d < 32; ++d) dst[d] = row[d] * inv;
        }
    } else {
        float (*S)[18][66] = (float(*)[18][66])smem;
        float (*Wl)[11] = (float(*)[11])(smem + 38016);
        const int id2 = id - 64;
        const int y0 = (id2 & 3) * 16, c0 = ((id2 >> 2) & 31) * 8, b = id2 >> 7;
        if (tid < 144) {
            int ch = tid / 18, r = tid - ch * 18;
            int gy = y0 + r - 1;
            float* drow = &S[ch][r][0];
            if (gy < 0 || gy > 63) {
                for (int i = 0; i < 66; ++i) drow[i] = 0.f;
            } else {
                const short* src = (const short*)vbb +
                                   ((((b << 8) + c0 + ch) << 12) + gy * 64);
                drow[0] = 0.f;
                drow[65] = 0.f;
#pragma unroll
                for (int g = 0; g < 8; ++g) {
                    short8 p = *(const short8*)(src + g * 8);
#pragma unroll
                    for (int u = 0; u < 8; ++u) drow[1 + g * 8 + u] = s2f(p[u]);
                }
            }
        } else if (tid >= 248) {
            int ch = tid - 248;
            int c = c0 + ch;
            float scale = rsqrtf(prm[P_DWV + c] + 1e-3f) * prm[P_DWG + c];
#pragma unroll
            for (int e = 0; e < 9; ++e) Wl[ch][e] = prm[P_DWK + c * 9 + e] * scale;
            Wl[ch][10] = (prm[P_DWB + c] - prm[P_DWM + c]) * scale + prm[P_DWBT + c];
        }
        __syncthreads();
        const int row = tid >> 4, xl = tid & 15;
#pragma unroll
        for (int u = 0; u < 4; ++u) {
            int x = xl + u * 16;
            short8 o;
#pragma unroll
            for (int ch = 0; ch < 8; ++ch) {
                float acc = Wl[ch][10];
#pragma unroll
                for (int ky = 0; ky < 3; ++ky)
#pragma unroll
                    for (int kx = 0; kx < 3; ++kx)
                        acc = fmaf(S[ch][row + ky][x + kx], Wl[ch][ky * 3 + kx], acc);
                o[ch] = f2s(gelu_exact(acc));
            }
            *(short8*)&((short*)convT)[(((b << 12) + (y0 + row) * 64 + x) << 8) + c0] = o;
        }
    }
}

// ---------------------------------------------------------------------------
// K_attv_sm (node 5): id<1024 -> att = attn @ v -> attT + gap atomics;
//                     id>=1024 -> spatial gate sigsm from convT.
// ---------------------------------------------------------------------------
__global__ __launch_bounds__(256) void k_attv_sm(const float* __restrict__ attn,
                                                 const bf16* __restrict__ vbb,
                                                 const bf16* __restrict__ convT,
                                                 const float* __restrict__ prm,
                                                 bf16* __restrict__ attT,
                                                 float* __restrict__ gap,
                                                 float* __restrict__ sigsm) {
    __shared__ __align__(16) char smem[36864];
    const int id = blockIdx.x;
    const int tid = threadIdx.x;
    if (id < 1024) {
        float (*A)[32] = (float(*)[32])smem;
        float (*G)[32] = (float(*)[32])(smem + 4096);
        const int nx = id & 15, h = (id >> 4) & 7, b = id >> 7;
        const int n = nx * 256 + tid;
        for (int i = tid; i < 1024; i += 256)
            ((float*)A)[i] = attn[((b * 8 + h) << 10) + i];
        __syncthreads();
        const int base = ((b * 256 + h * 32) << 12) + n;
        float vv[32];
#pragma unroll
        for (int d = 0; d < 32; ++d) vv[d] = s2f(((const short*)vbb)[base + (d << 12)]);
        float av[32];
#pragma unroll
        for (int c = 0; c < 32; ++c) {
            float s = 0.f;
#pragma unroll
            for (int d = 0; d < 32; ++d) s = fmaf(A[c][d], vv[d], s);
            av[c] = s;
            G[tid][c] = s;
        }
        const int obase = (((b << 12) + n) << 8) + h * 32;
#pragma unroll
        for (int g = 0; g < 4; ++g) {
            short8 p;
#pragma unroll
            for (int u = 0; u < 8; ++u) p[u] = f2s(av[g * 8 + u]);
            *(short8*)&attT[obase + g * 8] = p;
        }
        __syncthreads();
        {
            const int colc = tid & 31, rg = tid >> 5;
            float s = 0.f;
#pragma unroll
            for (int i = 0; i < 32; ++i) s += G[rg * 32 + i][colc];
            A[rg][colc] = s;
        }
        __syncthreads();
        if (tid < 32) {
            float s = 0.f;
#pragma unroll
            for (int g = 0; g < 8; ++g) s += A[g][tid];
            atomicAdd(&gap[(b << 8) + h * 32 + tid], s);
        }
    } else {
        float (*W1)[16] = (float(*)[16])smem;
        const int id2 = id - 1024;
        const int nx = id2 & 15, b = id2 >> 4;
        const int n = nx * 256 + tid;
        for (int i = tid; i < 4096; i += 256) W1[i >> 4][i & 15] = prm[P_SIW1 + i];
        __syncthreads();
        float acc[16];
#pragma unroll
        for (int o = 0; o < 16; ++o) acc[o] = 0.f;
        const bf16* src = convT + (((b << 12) + n) << 8);
#pragma unroll 4
        for (int g = 0; g < 32; ++g) {
            short8 p = *(const short8*)&src[g * 8];
#pragma unroll
            for (int u = 0; u < 8; ++u) {
                float v = s2f(p[u]);
                int c = g * 8 + u;
#pragma unroll
                for (int o = 0; o < 16; ++o) acc[o] = fmaf(v, W1[c][o], acc[o]);
            }
        }
        float sm = prm[P_SIB2];
#pragma unroll
        for (int o = 0; o < 16; ++o) {
            float t = acc[o] + prm[P_SIB1 + o];
            t = (t - prm[P_SIM + o]) * rsqrtf(prm[P_SIV + o] + 1e-3f) * prm[P_SIG + o] +
                prm[P_SIBT + o];
            sm = fmaf(gelu_exact(t), prm[P_SIW2 + o], sm);
        }
        sigsm[(b << 12) + n] = sigmoidf_(sm);
    }
}

// ---------------------------------------------------------------------------
// K9 (node 6): final projection (MFMA), 128x128 tile; channel gate (cm)
// computed INLINE per block (parallel 2-stage matvec) -> scs[256].
// ---------------------------------------------------------------------------
__global__ __launch_bounds__(256) void k_proj_m3(const bf16* __restrict__ attT,
                                                 const bf16* __restrict__ convT,
                                                 const float* __restrict__ sigsm,
                                                 const float* __restrict__ gap,
                                                 const bf16* __restrict__ wpT,
                                                 const float* __restrict__ prm,
                                                 const unsigned* __restrict__ flag,
                                                 void* __restrict__ out) {
    __shared__ short As[128][72];
    __shared__ short Bs[128][72];
    __shared__ float scs[256];
    const bool isbf = (*flag != 0u);
    const int id = blockIdx.x;                 // 512 = 8 * 64
    const int swz = (id & 7) * 64 + (id >> 3);
    const int j0 = (swz & 1) * 128;
    const int rest = swz >> 1;
    const int n0 = (rest & 31) * 128;
    const int b = rest >> 5;
    const int tid = threadIdx.x;
    const int wid = tid >> 6, l = tid & 63;
    const int wr = wid >> 1, wc = wid & 1;
    const int lm = l & 15, lk = (l >> 4) * 8;
    const int srow = tid >> 3, soct = tid & 7;

    // inline channel gate: scs[j] = sigmoid(gelu(bn(gap/4096 @ w1)) @ w2 + b2)
    {
        float* gl = (float*)&As[0][0];         // 256 f
        float* rd = gl + 256;                  // 256 f
        float* t1 = rd + 256;                  // 32 f
        gl[tid] = gap[(b << 8) + tid] * (1.0f / 4096.0f);
        __syncthreads();
        const int o = tid >> 3, g = tid & 7;
        float s1 = 0.f;
#pragma unroll
        for (int i = 0; i < 32; ++i) {
            int c = g * 32 + i;
            s1 = fmaf(gl[c], prm[P_CIW1 + c * 32 + o], s1);
        }
        rd[o * 8 + g] = s1;
        __syncthreads();
        if (tid < 32) {
            float s = prm[P_CIB1 + tid];
#pragma unroll
            for (int g2 = 0; g2 < 8; ++g2) s += rd[tid * 8 + g2];
            s = (s - prm[P_CIM + tid]) * rsqrtf(prm[P_CIV + tid] + 1e-3f) *
                    prm[P_CIG + tid] + prm[P_CIBT + tid];
            t1[tid] = gelu_exact(s);
        }
        __syncthreads();
        float s = prm[P_CIB2 + tid];
#pragma unroll
        for (int o2 = 0; o2 < 32; ++o2)
            s = fmaf(t1[o2], prm[P_CIW2 + o2 * 256 + tid], s);
        scs[tid] = sigmoidf_(s);
    }

    floatx4 acc[4][4];
#pragma unroll
    for (int i = 0; i < 4; ++i)
#pragma unroll
        for (int j = 0; j < 4; ++j) acc[i][j] = (floatx4){0.f, 0.f, 0.f, 0.f};

    for (int k0 = 0; k0 < 256; k0 += 64) {
        __syncthreads();
#pragma unroll
        for (int i = 0; i < 4; ++i) {
            int row = srow + i * 32;
            *(short8*)&As[row][soct * 8] =
                *(const short8*)&wpT[((j0 + row) << 8) + k0 + soct * 8];
            int rbase = (((b << 12) + n0 + row) << 8) + k0 + soct * 8;
            short8 pa = *(const short8*)&attT[rbase];
            short8 pc = *(const short8*)&convT[rbase];
            float sv = sigsm[(b << 12) + n0 + row];
            short8 pz;
#pragma unroll
            for (int u = 0; u < 8; ++u)
                pz[u] = f2s(s2f(pa[u]) * sv + s2f(pc[u]) * scs[k0 + soct * 8 + u]);
            *(short8*)&Bs[row][soct * 8] = pz;
        }
        __syncthreads();
#pragma unroll
        for (int h = 0; h < 2; ++h) {
            short8 af[4], bfv[4];
#pragma unroll
            for (int mt = 0; mt < 4; ++mt)
                af[mt] = *(const short8*)&As[wr * 64 + mt * 16 + lm][h * 32 + lk];
#pragma unroll
            for (int nt = 0; nt < 4; ++nt)
                bfv[nt] = *(const short8*)&Bs[wc * 64 + nt * 16 + lm][h * 32 + lk];
#pragma unroll
            for (int mt = 0; mt < 4; ++mt)
#pragma unroll
                for (int nt = 0; nt < 4; ++nt)
                    acc[mt][nt] = MFMA16(af[mt], bfv[nt], acc[mt][nt]);
        }
    }
    const int jbase = j0 + wr * 64 + (l >> 4) * 4;
#pragma unroll
    for (int mt = 0; mt < 4; ++mt) {
        float bp[4];
#pragma unroll
        for (int r = 0; r < 4; ++r) bp[r] = prm[P_BPROJ + jbase + mt * 16 + r];
#pragma unroll
        for (int nt = 0; nt < 4; ++nt) {
            int n = n0 + wc * 64 + nt * 16 + lm;
#pragma unroll
            for (int r = 0; r < 4; ++r) {
                int idx = (((b << 8) + jbase + mt * 16 + r) << 12) + n;
                float val = acc[mt][nt][r] + bp[r];
                if (isbf) ((bf16*)out)[idx] = f2b(val);
                else ((float*)out)[idx] = val;
            }
        }
    }
}

// ---------------------------------------------------------------------------
extern "C" void kernel_launch(void* const* d_in, const int* in_sizes, int n_in,
                              void* d_out, int out_size, void* d_ws, size_t ws_size,
                              hipStream_t stream) {
    char* ws = (char*)d_ws;
    // layout (bytes):
    //   [0,    17M)  vbb bf16 [c][n]
    //   [32M,  48M)  xT bf16    -> attT alias (xT dead after node 3)
    //   [48M,  64M)  qb bf16
    //   [64M,  80M)  kb bf16    (NOT aliased by convT: node-4 race, round 11)
    //   [80M,  86M)  wqkvT, wprojT, attn, qss|kss|gap, sigsm, prm, flag
    //   [96M, 113M)  convT bf16 (own region)
    bf16*  vbb    = (bf16*) (ws);
    bf16*  xT     = (bf16*) (ws + 33554432);
    bf16*  attT   = (bf16*) (ws + 33554432);   // alias xT (dead after qkv)
    bf16*  qb     = (bf16*) (ws + 50331648);
    bf16*  kb     = (bf16*) (ws + 67108864);
    bf16*  wqkvT  = (bf16*) (ws + 83886080);
    bf16*  wprojT = (bf16*) (ws + 84279296);
    float* attn   = (float*)(ws + 84410368);
    float* qss    = (float*)(ws + 85721088);   // qss|kss|gap contiguous 24576B
    float* kss    = (float*)(ws + 85729280);
    float* gap    = (float*)(ws + 85737472);
    float* sigsm  = (float*)(ws + 85753856);
    float* prm    = (float*)(ws + 85884928);
    unsigned* flag = (unsigned*)(ws + 85985280);
    bf16*  convT  = (bf16*) (ws + 100663296);  // 96M, no alias

    CvtArgs a;
    const int map_src[24] = {3, 4, 5, 6, 7, 8, 9, 10, 11, 12, 13, 14, 15, 16, 17,
                             18, 19, 20, 21, 22, 23, 24, 25, 26};
    const int map_dst[24] = {P_BPROJ, P_DWK, P_DWB, P_DWG, P_DWBT, P_DWM, P_DWV,
                             P_CIG, P_CIBT, P_CIM, P_CIV, P_SIG, P_SIBT, P_SIM, P_SIV,
                             P_CIW1, P_CIB1, P_CIW2, P_CIB2, P_SIW1, P_SIB1, P_SIW2,
                             P_SIB2, P_TEMP};
    for (int i = 0; i < 24; ++i) {
        a.src[i] = d_in[map_src[i]];
        a.dst[i] = map_dst[i];
        a.cnt[i] = in_sizes[map_src[i]];
    }

    k_prep<<<25, 256, 0, stream>>>(a, prm, (const unsigned*)d_in[0], flag, qss);
    k_trans<<<2112, 256, 0, stream>>>(d_in[0], d_in[1], d_in[2], flag,
                                      xT, wqkvT, wprojT);
    k_qkv_m3<<<1536, 256, 0, stream>>>(xT, wqkvT, qb, kb, vbb, qss, kss);
    k_qkdw<<<1088, 256, 0, stream>>>(qb, kb, qss, kss, vbb, prm, attn, convT);
    k_attv_sm<<<1152, 256, 0, stream>>>(attn, vbb, convT, prm, attT, gap, sigsm);
    k_proj_m3<<<512, 256, 0, stream>>>(attT, convT, sigsm, gap,
                                       wprojT, prm, flag, d_out);
}

// Round 13
// 134.004 us; speedup vs baseline: 3.7289x; 1.0230x over previous
//
#include <hip/hip_runtime.h>
#include <hip/hip_bf16.h>
#include <math.h>

typedef __hip_bfloat16 bf16;
typedef __attribute__((ext_vector_type(8))) short short8;
typedef __attribute__((ext_vector_type(4))) short short4v;
typedef __attribute__((ext_vector_type(4))) float floatx4;

__device__ __forceinline__ bf16 f2b(float v) { return __float2bfloat16(v); }
__device__ __forceinline__ short f2s(float v) {
    bf16 h = __float2bfloat16(v);
    return *reinterpret_cast<short*>(&h);
}
__device__ __forceinline__ float s2f(short s) {
    union { unsigned u; float f; } t;
    t.u = ((unsigned)(unsigned short)s) << 16;
    return t.f;
}
__device__ __forceinline__ float gelu_exact(float x) {
    return 0.5f * x * (1.0f + erff(x * 0.70710678118654752440f));
}
__device__ __forceinline__ float sigmoidf_(float x) {
    return 1.0f / (1.0f + __expf(-x));
}
__device__ __forceinline__ float ldin(const void* p, int i, bool isbf) {
    return isbf ? s2f(((const short*)p)[i]) : ((const float*)p)[i];
}
#define MFMA16(a, b, c) __builtin_amdgcn_mfma_f32_16x16x32_bf16(a, b, c, 0, 0, 0)

// fp32 params block layout (offsets in floats)
#define P_DWK    0
#define P_DWB    2304
#define P_DWG    2560
#define P_DWBT   2816
#define P_DWM    3072
#define P_DWV    3328
#define P_CIW1   3584
#define P_CIB1   11776
#define P_CIG    11808
#define P_CIBT   11840
#define P_CIM    11872
#define P_CIV    11904
#define P_CIW2   11936
#define P_CIB2   20128
#define P_SIW1   20384
#define P_SIB1   24480
#define P_SIG    24496
#define P_SIBT   24512
#define P_SIM    24528
#define P_SIV    24544
#define P_SIW2   24560
#define P_SIB2   24576
#define P_TEMP   24577
#define P_BPROJ  24585

// ---------------------------------------------------------------------------
// helper: per-block dtype sniff of x's first 4096 words (cheap, L2-hot).
// ---------------------------------------------------------------------------
__device__ __forceinline__ bool block_sniff(const unsigned* __restrict__ x) {
    int cnt = 0;
    for (int i = threadIdx.x; i < 4096; i += 256) {
        unsigned lo = x[i] & 0xFFFFu;
        unsigned e = (lo >> 7) & 0xFFu;
        cnt += (e >= 0x66u && e <= 0x8Au) ? 1 : 0;
    }
    __shared__ int red[256];
    red[threadIdx.x] = cnt;
    __syncthreads();
    for (int o = 128; o > 0; o >>= 1) {
        if (threadIdx.x < o) red[threadIdx.x] += red[threadIdx.x + o];
        __syncthreads();
    }
    return red[0] > 2048;
}

// ---------------------------------------------------------------------------
// K_prep (node 1): blocks 0..23 convert params (self-sniffed dtype);
// block 24 zeros qss|kss|gap and publishes the flag for later kernels.
// ---------------------------------------------------------------------------
struct CvtArgs { const void* src[24]; int dst[24]; int cnt[24]; };

__global__ __launch_bounds__(256) void k_prep(CvtArgs a, float* __restrict__ prm,
                                              const unsigned* __restrict__ x,
                                              unsigned* __restrict__ flag,
                                              float* __restrict__ accbuf) {
    const bool isbf = block_sniff(x);
    const int e = blockIdx.x;
    if (e < 24) {
        const void* s = a.src[e];
        float* d = prm + a.dst[e];
        const int n = a.cnt[e];
        for (int i = threadIdx.x; i < n; i += 256) d[i] = ldin(s, i, isbf);
    } else {
        for (int i = threadIdx.x; i < 6144; i += 256) accbuf[i] = 0.f;
        if (threadIdx.x == 0) *flag = isbf ? 1u : 0u;
    }
}

// ---------------------------------------------------------------------------
// K_trans (node 2): all three transposes in one kernel.
// ---------------------------------------------------------------------------
__global__ __launch_bounds__(256) void k_trans(const void* __restrict__ x,
                                               const void* __restrict__ wqkv,
                                               const void* __restrict__ wproj,
                                               const unsigned* __restrict__ flag,
                                               bf16* __restrict__ xT,
                                               bf16* __restrict__ wqkvT,
                                               bf16* __restrict__ wprojT) {
    __shared__ short T[64][72];
    const bool isbf = (*flag != 0u);
    const int id = blockIdx.x;
    const int tid = threadIdx.x;
    const int cc = tid >> 3, oct = tid & 7;

    const void* src;
    bf16* dst;
    long row_stride;
    long src_off;
    int c0;
    long out_row_off;
    if (id < 2048) {
        int nx = id & 63, cy = (id >> 6) & 3, b = id >> 8;
        c0 = cy * 64;
        int n0 = nx * 64;
        src = x;
        dst = xT;
        row_stride = 4096;
        src_off = ((long)(b * 256 + c0) << 12) + n0;
        out_row_off = ((long)(b << 12) + n0) << 8;
    } else if (id < 2096) {
        int id2 = id - 2048;
        int jx = id2 % 12, cy = id2 / 12;
        c0 = cy * 64;
        int j0 = jx * 64;
        src = wqkv;
        dst = wqkvT;
        row_stride = 768;
        src_off = (long)c0 * 768 + j0;
        out_row_off = (long)j0 << 8;
    } else {
        int id3 = id - 2096;
        int jx = id3 & 3, cy = id3 >> 2;
        c0 = cy * 64;
        int j0 = jx * 64;
        src = wproj;
        dst = wprojT;
        row_stride = 256;
        src_off = (long)c0 * 256 + j0;
        out_row_off = (long)j0 << 8;
    }

#pragma unroll
    for (int i = 0; i < 2; ++i) {
        int col = cc + i * 32;
        long gbase = src_off + (long)col * row_stride + oct * 8;
        short v[8];
        if (isbf) {
            short8 p = *(const short8*)((const short*)src + gbase);
#pragma unroll
            for (int u = 0; u < 8; ++u) v[u] = p[u];
        } else {
            floatx4 q0 = *(const floatx4*)((const float*)src + gbase);
            floatx4 q1 = *(const floatx4*)((const float*)src + gbase + 4);
#pragma unroll
            for (int u = 0; u < 4; ++u) { v[u] = f2s(q0[u]); v[4 + u] = f2s(q1[u]); }
        }
        int row0 = oct * 8;
#pragma unroll
        for (int u = 0; u < 8; ++u) {
            int row = row0 + u;
            T[row][(((col >> 3) ^ (row & 7)) << 3) + (col & 7)] = v[u];
        }
    }
    __syncthreads();
    const int rr = tid >> 3;
#pragma unroll
    for (int i = 0; i < 2; ++i) {
        int row = rr + i * 32;
        short8 p = *(const short8*)&T[row][((oct ^ (row & 7)) << 3)];
        *(short8*)&dst[out_row_off + ((long)row << 8) + c0 + oct * 8] = p;
    }
}

// ---------------------------------------------------------------------------
// K1 (node 3): qkv GEMM (MFMA), 128x128 tile, 4 waves (64x64 quadrants).
// ---------------------------------------------------------------------------
__global__ __launch_bounds__(256) void k_qkv_m3(const bf16* __restrict__ xT,
                                                const bf16* __restrict__ wT,
                                                bf16* __restrict__ qb,
                                                bf16* __restrict__ kb,
                                                bf16* __restrict__ vbb,
                                                float* __restrict__ qss,
                                                float* __restrict__ kss) {
    __shared__ short As[128][72];
    __shared__ short Bs[128][72];
    const int id = blockIdx.x;                 // 1536 = 8 * 192
    const int swz = (id & 7) * 192 + (id >> 3);
    const int y = swz % 6;
    const int rest = swz / 6;
    const int n0 = (rest & 31) * 128;
    const int b = rest >> 5;
    const int j0 = y * 128;
    const int tid = threadIdx.x;
    const int wid = tid >> 6, l = tid & 63;
    const int wr = wid >> 1, wc = wid & 1;
    const int lm = l & 15, lk = (l >> 4) * 8;
    const int srow = tid >> 3, soct = tid & 7;
    floatx4 acc[4][4];
#pragma unroll
    for (int i = 0; i < 4; ++i)
#pragma unroll
        for (int j = 0; j < 4; ++j) acc[i][j] = (floatx4){0.f, 0.f, 0.f, 0.f};

    for (int k0 = 0; k0 < 256; k0 += 64) {
        __syncthreads();
#pragma unroll
        for (int i = 0; i < 4; ++i) {
            int row = srow + i * 32;
            *(short8*)&As[row][soct * 8] =
                *(const short8*)&wT[((j0 + row) << 8) + k0 + soct * 8];
            *(short8*)&Bs[row][soct * 8] =
                *(const short8*)&xT[(((b << 12) + n0 + row) << 8) + k0 + soct * 8];
        }
        __syncthreads();
#pragma unroll
        for (int h = 0; h < 2; ++h) {
            short8 af[4], bfv[4];
#pragma unroll
            for (int mt = 0; mt < 4; ++mt)
                af[mt] = *(const short8*)&As[wr * 64 + mt * 16 + lm][h * 32 + lk];
#pragma unroll
            for (int nt = 0; nt < 4; ++nt)
                bfv[nt] = *(const short8*)&Bs[wc * 64 + nt * 16 + lm][h * 32 + lk];
#pragma unroll
            for (int mt = 0; mt < 4; ++mt)
#pragma unroll
                for (int nt = 0; nt < 4; ++nt)
                    acc[mt][nt] = MFMA16(af[mt], bfv[nt], acc[mt][nt]);
        }
    }
    const int jbase = wr * 64 + (l >> 4) * 4;
    const int jq = (y & 1) * 128;
    if (y < 4) {
        bf16* dst = (y < 2) ? qb : kb;
#pragma unroll
        for (int mt = 0; mt < 4; ++mt)
#pragma unroll
            for (int nt = 0; nt < 4; ++nt) {
                int n = n0 + wc * 64 + nt * 16 + lm;
#pragma unroll
                for (int r = 0; r < 4; ++r)
                    dst[(((b << 8) + jq + jbase + mt * 16 + r) << 12) + n] =
                        f2b(acc[mt][nt][r]);
            }
        __syncthreads();
        float* red = (float*)&As[0][0];
#pragma unroll
        for (int mt = 0; mt < 4; ++mt)
#pragma unroll
            for (int r = 0; r < 4; ++r) {
                float s = 0.f;
#pragma unroll
                for (int nt = 0; nt < 4; ++nt) {
                    float v = acc[mt][nt][r];
                    s = fmaf(v, v, s);
                }
                red[(jbase + mt * 16 + r) * 32 + wc * 16 + lm] = s;
            }
        __syncthreads();
        if (tid < 128) {
            float s = 0.f;
#pragma unroll
            for (int i = 0; i < 32; ++i)
                s += red[tid * 32 + ((i + tid) & 31)];
            float* dsts = (y < 2) ? qss : kss;
            atomicAdd(&dsts[(b << 8) + jq + tid], s);
        }
    } else {
#pragma unroll
        for (int mt = 0; mt < 4; ++mt)
#pragma unroll
            for (int nt = 0; nt < 4; ++nt) {
                int n = n0 + wc * 64 + nt * 16 + lm;
#pragma unroll
                for (int r = 0; r < 4; ++r)
                    vbb[(((b << 8) + jq + jbase + mt * 16 + r) << 12) + n] =
                        f2b(acc[mt][nt][r]);
            }
    }
}

// ---------------------------------------------------------------------------
// K_qkdw (node 4): id<64 -> fused QK^T+softmax; id>=64 -> dwconv+BN+GELU+T.
// ---------------------------------------------------------------------------
__global__ __launch_bounds__(256) void k_qkdw(const bf16* __restrict__ qb,
                                              const bf16* __restrict__ kb,
                                              const float* __restrict__ qss,
                                              const float* __restrict__ kss,
                                              const bf16* __restrict__ vbb,
                                              const float* __restrict__ prm,
                                              float* __restrict__ attn,
                                              bf16* __restrict__ convT) {
    __shared__ __align__(16) char smem[38368];
    const int id = blockIdx.x;
    const int tid = threadIdx.x;
    if (id < 64) {
        float (*AS)[32] = (float(*)[32])smem;
        const int h = id & 7, b = id >> 3;
        const int wid = tid >> 6, l = tid & 63;
        const int lm = l & 15, lk = (l >> 4) * 8;
        floatx4 acc[2][2];
#pragma unroll
        for (int i = 0; i < 2; ++i)
#pragma unroll
            for (int j = 0; j < 2; ++j) acc[i][j] = (floatx4){0.f, 0.f, 0.f, 0.f};
        const int cbase = (b << 8) + h * 32;
        for (int it = 0; it < 32; ++it) {
            int n = wid * 1024 + it * 32 + lk;
            short8 a0 = *(const short8*)&qb[((cbase + lm) << 12) + n];
            short8 a1 = *(const short8*)&qb[((cbase + 16 + lm) << 12) + n];
            short8 b0 = *(const short8*)&kb[((cbase + lm) << 12) + n];
            short8 b1 = *(const short8*)&kb[((cbase + 16 + lm) << 12) + n];
            acc[0][0] = MFMA16(a0, b0, acc[0][0]);
            acc[0][1] = MFMA16(a0, b1, acc[0][1]);
            acc[1][0] = MFMA16(a1, b0, acc[1][0]);
            acc[1][1] = MFMA16(a1, b1, acc[1][1]);
        }
        for (int i = tid; i < 1024; i += 256) ((float*)AS)[i] = 0.f;
        __syncthreads();
#pragma unroll
        for (int mt = 0; mt < 2; ++mt)
#pragma unroll
            for (int nt = 0; nt < 2; ++nt)
#pragma unroll
                for (int r = 0; r < 4; ++r)
                    atomicAdd(&AS[mt * 16 + (l >> 4) * 4 + r][nt * 16 + lm],
                              acc[mt][nt][r]);
        __syncthreads();
        if (tid < 32) {
            const int c = tid;
            float qsc = rsqrtf(fmaxf(qss[cbase + c], 1e-12f)) * prm[P_TEMP + h];
            float row[32];
            float m = -1e30f;
#pragma unroll
            for (int d = 0; d < 32; ++d) {
                row[d] = AS[c][d] * qsc * rsqrtf(fmaxf(kss[cbase + d], 1e-12f));
                m = fmaxf(m, row[d]);
            }
            float s = 0.f;
#pragma unroll
            for (int d = 0; d < 32; ++d) {
                row[d] = __expf(row[d] - m);
                s += row[d];
            }
            float inv = 1.0f / s;
            float* dst = attn + ((b * 8 + h) << 10) + c * 32;
#pragma unroll
            for (int d = 0; d < 32; ++d) dst[d] = row[d] * inv;
        }
    } else {
        float (*S)[18][66] = (float(*)[18][66])smem;
        float (*Wl)[11] = (float(*)[11])(smem + 38016);
        const int id2 = id - 64;
        const int y0 = (id2 & 3) * 16, c0 = ((id2 >> 2) & 31) * 8, b = id2 >> 7;
        if (tid < 144) {
            int ch = tid / 18, r = tid - ch * 18;
            int gy = y0 + r - 1;
            float* drow = &S[ch][r][0];
            if (gy < 0 || gy > 63) {
                for (int i = 0; i < 66; ++i) drow[i] = 0.f;
            } else {
                const short* src = (const short*)vbb +
                                   ((((b << 8) + c0 + ch) << 12) + gy * 64);
                drow[0] = 0.f;
                drow[65] = 0.f;
#pragma unroll
                for (int g = 0; g < 8; ++g) {
                    short8 p = *(const short8*)(src + g * 8);
#pragma unroll
                    for (int u = 0; u < 8; ++u) drow[1 + g * 8 + u] = s2f(p[u]);
                }
            }
        } else if (tid >= 248) {
            int ch = tid - 248;
            int c = c0 + ch;
            float scale = rsqrtf(prm[P_DWV + c] + 1e-3f) * prm[P_DWG + c];
#pragma unroll
            for (int e = 0; e < 9; ++e) Wl[ch][e] = prm[P_DWK + c * 9 + e] * scale;
            Wl[ch][10] = (prm[P_DWB + c] - prm[P_DWM + c]) * scale + prm[P_DWBT + c];
        }
        __syncthreads();
        const int row = tid >> 4, xl = tid & 15;
#pragma unroll
        for (int u = 0; u < 4; ++u) {
            int x = xl + u * 16;
            short8 o;
#pragma unroll
            for (int ch = 0; ch < 8; ++ch) {
                float acc = Wl[ch][10];
#pragma unroll
                for (int ky = 0; ky < 3; ++ky)
#pragma unroll
                    for (int kx = 0; kx < 3; ++kx)
                        acc = fmaf(S[ch][row + ky][x + kx], Wl[ch][ky * 3 + kx], acc);
                o[ch] = f2s(gelu_exact(acc));
            }
            *(short8*)&((short*)convT)[(((b << 12) + (y0 + row) * 64 + x) << 8) + c0] = o;
        }
    }
}

// ---------------------------------------------------------------------------
// K_attv_sm (node 5): id<1024 -> att = attn @ v -> attT + gap atomics;
//                     id>=1024 -> spatial gate sigsm from convT.
// ROUND-13 FIX: G column-writes rotated by tid -> bank (c+tid)&31 distinct
// per lane (was: all 64 lanes on bank c = 64-way conflict x 32 writes).
// ---------------------------------------------------------------------------
__global__ __launch_bounds__(256) void k_attv_sm(const float* __restrict__ attn,
                                                 const bf16* __restrict__ vbb,
                                                 const bf16* __restrict__ convT,
                                                 const float* __restrict__ prm,
                                                 bf16* __restrict__ attT,
                                                 float* __restrict__ gap,
                                                 float* __restrict__ sigsm) {
    __shared__ __align__(16) char smem[36864];
    const int id = blockIdx.x;
    const int tid = threadIdx.x;
    if (id < 1024) {
        float (*A)[32] = (float(*)[32])smem;
        float (*G)[32] = (float(*)[32])(smem + 4096);
        const int nx = id & 15, h = (id >> 4) & 7, b = id >> 7;
        const int n = nx * 256 + tid;
        for (int i = tid; i < 1024; i += 256)
            ((float*)A)[i] = attn[((b * 8 + h) << 10) + i];
        __syncthreads();
        const int base = ((b * 256 + h * 32) << 12) + n;
        float vv[32];
#pragma unroll
        for (int d = 0; d < 32; ++d) vv[d] = s2f(((const short*)vbb)[base + (d << 12)]);
        float av[32];
#pragma unroll
        for (int c = 0; c < 32; ++c) {
            float s = 0.f;
#pragma unroll
            for (int d = 0; d < 32; ++d) s = fmaf(A[c][d], vv[d], s);
            av[c] = s;
            G[tid][(c + tid) & 31] = s;        // rotated: conflict-free
        }
        const int obase = (((b << 12) + n) << 8) + h * 32;
#pragma unroll
        for (int g = 0; g < 4; ++g) {
            short8 p;
#pragma unroll
            for (int u = 0; u < 8; ++u) p[u] = f2s(av[g * 8 + u]);
            *(short8*)&attT[obase + g * 8] = p;
        }
        __syncthreads();
        {
            const int colc = tid & 31, rg = tid >> 5;
            float s = 0.f;
#pragma unroll
            for (int i = 0; i < 32; ++i) {
                int row = rg * 32 + i;
                s += G[row][(colc + row) & 31];   // inverse rotation
            }
            A[rg][colc] = s;
        }
        __syncthreads();
        if (tid < 32) {
            float s = 0.f;
#pragma unroll
            for (int g = 0; g < 8; ++g) s += A[g][tid];
            atomicAdd(&gap[(b << 8) + h * 32 + tid], s);
        }
    } else {
        float (*W1)[16] = (float(*)[16])smem;
        const int id2 = id - 1024;
        const int nx = id2 & 15, b = id2 >> 4;
        const int n = nx * 256 + tid;
        for (int i = tid; i < 4096; i += 256) W1[i >> 4][i & 15] = prm[P_SIW1 + i];
        __syncthreads();
        float acc[16];
#pragma unroll
        for (int o = 0; o < 16; ++o) acc[o] = 0.f;
        const bf16* src = convT + (((b << 12) + n) << 8);
#pragma unroll 4
        for (int g = 0; g < 32; ++g) {
            short8 p = *(const short8*)&src[g * 8];
#pragma unroll
            for (int u = 0; u < 8; ++u) {
                float v = s2f(p[u]);
                int c = g * 8 + u;
#pragma unroll
                for (int o = 0; o < 16; ++o) acc[o] = fmaf(v, W1[c][o], acc[o]);
            }
        }
        float sm = prm[P_SIB2];
#pragma unroll
        for (int o = 0; o < 16; ++o) {
            float t = acc[o] + prm[P_SIB1 + o];
            t = (t - prm[P_SIM + o]) * rsqrtf(prm[P_SIV + o] + 1e-3f) * prm[P_SIG + o] +
                prm[P_SIBT + o];
            sm = fmaf(gelu_exact(t), prm[P_SIW2 + o], sm);
        }
        sigsm[(b << 12) + n] = sigmoidf_(sm);
    }
}

// ---------------------------------------------------------------------------
// K9 (node 6): final projection (MFMA), 128x128 tile; inline channel gate.
// ---------------------------------------------------------------------------
__global__ __launch_bounds__(256) void k_proj_m3(const bf16* __restrict__ attT,
                                                 const bf16* __restrict__ convT,
                                                 const float* __restrict__ sigsm,
                                                 const float* __restrict__ gap,
                                                 const bf16* __restrict__ wpT,
                                                 const float* __restrict__ prm,
                                                 const unsigned* __restrict__ flag,
                                                 void* __restrict__ out) {
    __shared__ short As[128][72];
    __shared__ short Bs[128][72];
    __shared__ float scs[256];
    const bool isbf = (*flag != 0u);
    const int id = blockIdx.x;                 // 512 = 8 * 64
    const int swz = (id & 7) * 64 + (id >> 3);
    const int j0 = (swz & 1) * 128;
    const int rest = swz >> 1;
    const int n0 = (rest & 31) * 128;
    const int b = rest >> 5;
    const int tid = threadIdx.x;
    const int wid = tid >> 6, l = tid & 63;
    const int wr = wid >> 1, wc = wid & 1;
    const int lm = l & 15, lk = (l >> 4) * 8;
    const int srow = tid >> 3, soct = tid & 7;

    {
        float* gl = (float*)&As[0][0];
        float* rd = gl + 256;
        float* t1 = rd + 256;
        gl[tid] = gap[(b << 8) + tid] * (1.0f / 4096.0f);
        __syncthreads();
        const int o = tid >> 3, g = tid & 7;
        float s1 = 0.f;
#pragma unroll
        for (int i = 0; i < 32; ++i) {
            int c = g * 32 + i;
            s1 = fmaf(gl[c], prm[P_CIW1 + c * 32 + o], s1);
        }
        rd[o * 8 + g] = s1;
        __syncthreads();
        if (tid < 32) {
            float s = prm[P_CIB1 + tid];
#pragma unroll
            for (int g2 = 0; g2 < 8; ++g2) s += rd[tid * 8 + g2];
            s = (s - prm[P_CIM + tid]) * rsqrtf(prm[P_CIV + tid] + 1e-3f) *
                    prm[P_CIG + tid] + prm[P_CIBT + tid];
            t1[tid] = gelu_exact(s);
        }
        __syncthreads();
        float s = prm[P_CIB2 + tid];
#pragma unroll
        for (int o2 = 0; o2 < 32; ++o2)
            s = fmaf(t1[o2], prm[P_CIW2 + o2 * 256 + tid], s);
        scs[tid] = sigmoidf_(s);
    }

    floatx4 acc[4][4];
#pragma unroll
    for (int i = 0; i < 4; ++i)
#pragma unroll
        for (int j = 0; j < 4; ++j) acc[i][j] = (floatx4){0.f, 0.f, 0.f, 0.f};

    for (int k0 = 0; k0 < 256; k0 += 64) {
        __syncthreads();
#pragma unroll
        for (int i = 0; i < 4; ++i) {
            int row = srow + i * 32;
            *(short8*)&As[row][soct * 8] =
                *(const short8*)&wpT[((j0 + row) << 8) + k0 + soct * 8];
            int rbase = (((b << 12) + n0 + row) << 8) + k0 + soct * 8;
            short8 pa = *(const short8*)&attT[rbase];
            short8 pc = *(const short8*)&convT[rbase];
            float sv = sigsm[(b << 12) + n0 + row];
            short8 pz;
#pragma unroll
            for (int u = 0; u < 8; ++u)
                pz[u] = f2s(s2f(pa[u]) * sv + s2f(pc[u]) * scs[k0 + soct * 8 + u]);
            *(short8*)&Bs[row][soct * 8] = pz;
        }
        __syncthreads();
#pragma unroll
        for (int h = 0; h < 2; ++h) {
            short8 af[4], bfv[4];
#pragma unroll
            for (int mt = 0; mt < 4; ++mt)
                af[mt] = *(const short8*)&As[wr * 64 + mt * 16 + lm][h * 32 + lk];
#pragma unroll
            for (int nt = 0; nt < 4; ++nt)
                bfv[nt] = *(const short8*)&Bs[wc * 64 + nt * 16 + lm][h * 32 + lk];
#pragma unroll
            for (int mt = 0; mt < 4; ++mt)
#pragma unroll
                for (int nt = 0; nt < 4; ++nt)
                    acc[mt][nt] = MFMA16(af[mt], bfv[nt], acc[mt][nt]);
        }
    }
    const int jbase = j0 + wr * 64 + (l >> 4) * 4;
#pragma unroll
    for (int mt = 0; mt < 4; ++mt) {
        float bp[4];
#pragma unroll
        for (int r = 0; r < 4; ++r) bp[r] = prm[P_BPROJ + jbase + mt * 16 + r];
#pragma unroll
        for (int nt = 0; nt < 4; ++nt) {
            int n = n0 + wc * 64 + nt * 16 + lm;
#pragma unroll
            for (int r = 0; r < 4; ++r) {
                int idx = (((b << 8) + jbase + mt * 16 + r) << 12) + n;
                float val = acc[mt][nt][r] + bp[r];
                if (isbf) ((bf16*)out)[idx] = f2b(val);
                else ((float*)out)[idx] = val;
            }
        }
    }
}

// ---------------------------------------------------------------------------
extern "C" void kernel_launch(void* const* d_in, const int* in_sizes, int n_in,
                              void* d_out, int out_size, void* d_ws, size_t ws_size,
                              hipStream_t stream) {
    char* ws = (char*)d_ws;
    bf16*  vbb    = (bf16*) (ws);
    bf16*  xT     = (bf16*) (ws + 33554432);
    bf16*  attT   = (bf16*) (ws + 33554432);   // alias xT (dead after qkv)
    bf16*  qb     = (bf16*) (ws + 50331648);
    bf16*  kb     = (bf16*) (ws + 67108864);
    bf16*  wqkvT  = (bf16*) (ws + 83886080);
    bf16*  wprojT = (bf16*) (ws + 84279296);
    float* attn   = (float*)(ws + 84410368);
    float* qss    = (float*)(ws + 85721088);   // qss|kss|gap contiguous 24576B
    float* kss    = (float*)(ws + 85729280);
    float* gap    = (float*)(ws + 85737472);
    float* sigsm  = (float*)(ws + 85753856);
    float* prm    = (float*)(ws + 85884928);
    unsigned* flag = (unsigned*)(ws + 85985280);
    bf16*  convT  = (bf16*) (ws + 100663296);  // 96M, no alias

    CvtArgs a;
    const int map_src[24] = {3, 4, 5, 6, 7, 8, 9, 10, 11, 12, 13, 14, 15, 16, 17,
                             18, 19, 20, 21, 22, 23, 24, 25, 26};
    const int map_dst[24] = {P_BPROJ, P_DWK, P_DWB, P_DWG, P_DWBT, P_DWM, P_DWV,
                             P_CIG, P_CIBT, P_CIM, P_CIV, P_SIG, P_SIBT, P_SIM, P_SIV,
                             P_CIW1, P_CIB1, P_CIW2, P_CIB2, P_SIW1, P_SIB1, P_SIW2,
                             P_SIB2, P_TEMP};
    for (int i = 0; i < 24; ++i) {
        a.src[i] = d_in[map_src[i]];
        a.dst[i] = map_dst[i];
        a.cnt[i] = in_sizes[map_src[i]];
    }

    k_prep<<<25, 256, 0, stream>>>(a, prm, (const unsigned*)d_in[0], flag, qss);
    k_trans<<<2112, 256, 0, stream>>>(d_in[0], d_in[1], d_in[2], flag,
                                      xT, wqkvT, wprojT);
    k_qkv_m3<<<1536, 256, 0, stream>>>(xT, wqkvT, qb, kb, vbb, qss, kss);
    k_qkdw<<<1088, 256, 0, stream>>>(qb, kb, qss, kss, vbb, prm, attn, convT);
    k_attv_sm<<<1152, 256, 0, stream>>>(attn, vbb, convT, prm, attT, gap, sigsm);
    k_proj_m3<<<512, 256, 0, stream>>>(attT, convT, sigsm, gap,
                                       wprojT, prm, flag, d_out);
}